// Round 13
// baseline (2283.510 us; speedup 1.0000x reference)
//
#include <hip/hip_runtime.h>
#include <hip/hip_bf16.h>

#define DEV __device__ __forceinline__

typedef __attribute__((ext_vector_type(8))) short bf16x8;
typedef __attribute__((ext_vector_type(4))) float f32x4;
typedef __attribute__((ext_vector_type(4))) unsigned short u16x4;

#define MFMA16(a,b,c) __builtin_amdgcn_mfma_f32_16x16x32_bf16(a,b,c,0,0,0)

DEV unsigned short bfbits(float v){ __hip_bfloat16 h = __float2bfloat16(v); return *(unsigned short*)&h; }
DEV float bf2f(unsigned short u){ __hip_bfloat16 h = *(__hip_bfloat16*)&u; return __bfloat162float(h); }
DEV void split3(float v, unsigned short& h, unsigned short& m, unsigned short& l) {
  h = bfbits(v);        float r  = v - bf2f(h);
  m = bfbits(r);        float r2 = r - bf2f(m);
  l = bfbits(r2);
}
DEV uint4 zero4(){ uint4 z; z.x=0; z.y=0; z.z=0; z.w=0; return z; }
DEV void gload_lds16(const void* g, void* l) {
  __builtin_amdgcn_global_load_lds(
      (const __attribute__((address_space(1))) void*)g,
      (__attribute__((address_space(3))) void*)l, 16, 0, 0);
}

// ---------------- fused weight prep (one dispatch, 3066 blocks) ----------------
DEV void prep_deconv_img(int i, int CI, const float* __restrict__ w, unsigned short* __restrict__ w2) {
  const int nch = CI/16;
  int cil = i & 7, s = (i >> 3) & 7, co = (i >> 6) & 127, f = (i >> 13) & 1;
  int rest = i >> 14;
  int ch = rest % nch, e = rest / nch;
  int k = ch*64 + s*8 + cil;
  int ci = (k & 15) | ((k >> 6) << 4);
  int tap = (k >> 4) & 3, a = tap >> 1, b = tap & 1;
  float v = w[ (((long)ci*128 + co)*4 + (2*a+1-e))*4 + (2*b+1-f) ];
  w2[(long)(e*nch + ch)*16384 + ((long)(f*128 + co))*64 + ((s ^ (co&7))*8) + cil] = bfbits(v);
}
__global__ __launch_bounds__(256) void wprep_all(
    const float* __restrict__ c1w, float* __restrict__ w2c1,
    const float* __restrict__ c2w, unsigned short* __restrict__ w2c2,
    const float* __restrict__ c3w, unsigned short* __restrict__ w2c3,
    const float* __restrict__ d1w, unsigned short* __restrict__ w2d1,
    const float* __restrict__ d2w, unsigned short* __restrict__ w2d2,
    const float* __restrict__ d3w, unsigned short* __restrict__ w2d3,
    const float* __restrict__ emb, float* __restrict__ esq) {
  const int bx = blockIdx.x, t = threadIdx.x;
  if (bx < 24) {                         // conv1 transpose: 6144
    int i = bx*256 + t;
    if (i < 6144) {
      int tap = i & 15, ci = (i>>4) % 3, co = i / 48;
      w2c1[((long)ci*16 + tap)*128 + co] = c1w[i];
    }
  } else if (bx < 1048) {                // conv2 prep -> LDS-image layout
    int i = (bx-24)*256 + t;             // 0..262143
    int cil = i & 7, s = (i>>3) & 15, co = (i>>7) & 63;
    int ch = (i>>13) & 15, cog = i >> 17;
    int co_g = cog*64 + co, ci = ch*8 + cil, ky = s >> 2, kx = s & 3;
    float v = c2w[(((long)co_g*128 + ci)*4 + ky)*4 + kx];
    unsigned short h,m,l; split3(v,h,m,l);
    long base = (long)(cog*16 + ch)*24576 + ((long)co*16 + (s ^ (co&15)))*8 + cil;
    w2c2[base] = h; w2c2[base + 8192] = m; w2c2[base + 16384] = l;
  } else if (bx < 1432) {                // conv3 prep -> LDS-image layout: 98304
    int i = (bx-1048)*256 + t;
    int k = i % 1536, co = i / 1536;
    int ch = k / 96, rem = k % 96;
    int tap = rem >> 3, cil = rem & 7;
    int ci = ch*8 + cil, ky = tap >> 2, kx = tap & 3;
    float v = (kx < 3) ? c3w[(((long)co*128 + ci)*3 + ky)*3 + kx] : 0.f;
    unsigned short h,m,l; split3(v,h,m,l);
    long base = (long)ch*24576 + ((long)co*16 + (tap ^ (co&15)))*8 + cil;
    w2c3[base] = h; w2c3[base + 8192] = m; w2c3[base + 16384] = l;
  } else if (bx < 1944) {                // deconv1 image: 131072 (CI=64)
    prep_deconv_img((bx-1432)*256 + t, 64, d1w, w2d1);
  } else if (bx < 2968) {                // deconv2 image: 262144 (CI=128)
    prep_deconv_img((bx-1944)*256 + t, 128, d2w, w2d2);
  } else if (bx < 3064) {                // deconv3: 24576
    int i = (bx-2968)*256 + t;
    if (i < 24576) {
      int k = i % 1536, co = i / 1536;
      int ch = k / 96, rem = k % 96;
      int tap = rem >> 3, cil = rem & 7;
      int ci = ch*8 + cil, ky = tap >> 2, kx = tap & 3;
      float v = (co < 3 && kx < 3) ? d3w[(((long)ci*3 + co)*3 + ky)*3 + kx] : 0.f;
      w2d3[i] = bfbits(v);
    }
  } else {                               // esq: 512 codes
    int code = (bx-3064)*256 + t;
    if (code < 512) {
      const float4* ev = (const float4*)(emb + (long)code*64);
      float s = 0.f;
      #pragma unroll
      for (int q=0;q<16;q++){ float4 e4 = ev[q];
        s += e4.x*e4.x + e4.y*e4.y + e4.z*e4.z + e4.w*e4.w; }
      esq[code] = s;
    }
  }
}

// ---------------- conv1: f32 direct, out 3 bf16 planes INTERLEAVED ----------------
__global__ __launch_bounds__(256) void conv1_split(
    const float* __restrict__ x, const float* __restrict__ w2,
    const float* __restrict__ bias, unsigned short* __restrict__ h1, long PS1) {
  __shared__ __align__(16) float sIn[3][18][20];
  __shared__ __align__(16) float sW[3*16*64];
  const int tid = threadIdx.x;
  const int b = blockIdx.z >> 1, cog = blockIdx.z & 1;
  const int co0 = cog*64;
  const int oy0 = blockIdx.y*8, ox0 = blockIdx.x*8;
  const int cg2 = tid >> 5;
  const int pg2 = tid & 31;
  const int r = pg2 >> 2, pxp = (pg2 & 3)*2;
  float acc[8][2];
  #pragma unroll
  for (int c=0;c<8;c++){ float bv = bias[co0 + cg2*8 + c];
    acc[c][0]=bv; acc[c][1]=bv; }
  const float* xb = x + (long)b*3*256*256;
  const int iy0 = 2*oy0 - 1, ix0 = 2*ox0 - 1;
  for (int t=tid; t<3*18*18; t+=256) {
    int xx = t%18, yy=(t/18)%18, ci=t/324;
    int gy = iy0+yy, gx = ix0+xx;
    float v = 0.f;
    if (gy>=0 && gy<256 && gx>=0 && gx<256) v = xb[((long)ci*256+gy)*256+gx];
    sIn[ci][yy][xx] = v;
  }
  for (int t=tid; t<3*16*64; t+=256) {
    sW[t] = w2[(long)(t>>6)*128 + co0 + (t&63)];
  }
  __syncthreads();
  for (int ci=0; ci<3; ci++) {
    #pragma unroll
    for (int ky=0;ky<4;ky++)
    #pragma unroll
    for (int kx=0;kx<4;kx++) {
      const float* wp = &sW[(ci*16 + ky*4+kx)*64 + cg2*8];
      float4 w0 = *(const float4*)wp;
      float4 w1 = *(const float4*)(wp+4);
      const int yy = 2*r + ky;
      #pragma unroll
      for (int p=0;p<2;p++) {
        float iv = sIn[ci][yy][2*(pxp+p)+kx];
        acc[0][p] += w0.x*iv; acc[1][p] += w0.y*iv;
        acc[2][p] += w0.z*iv; acc[3][p] += w0.w*iv;
        acc[4][p] += w1.x*iv; acc[5][p] += w1.y*iv;
        acc[6][p] += w1.z*iv; acc[7][p] += w1.w*iv;
      }
    }
  }
  const int chg = cog*8 + cg2;
  #pragma unroll
  for (int p=0;p<2;p++) {
    unsigned short th[8], tm[8], tl[8];
    #pragma unroll
    for (int c=0;c<8;c++) {
      float v = fmaxf(acc[c][p], 0.f);
      split3(v, th[c], tm[c], tl[c]);
    }
    long base = (((long)(b*128 + oy0+r)*16 + chg)*128 + ox0+pxp+p)*8;
    *(uint4*)(h1 + base)          = *(uint4*)th;
    *(uint4*)(h1 + PS1 + base)    = *(uint4*)tm;
    *(uint4*)(h1 + 2*PS1 + base)  = *(uint4*)tl;
  }
}

// ---------------- conv2: MFMA 6-term split; post-barrier A prefetch ----------
__global__ __launch_bounds__(256, 2) void conv2_mfma(
    const unsigned short* __restrict__ h1, long PS1,
    const unsigned short* __restrict__ w2,   // LDS-image: [cog][ch][24576 shorts]
    const float* __restrict__ bias,
    unsigned short* __restrict__ h2I) {      // [b][row64][pl3][ch16][px64][8]
  __shared__ __align__(16) unsigned short sA[3][4][130][8];
  __shared__ __align__(16) unsigned short sB[24576];
  const int tid = threadIdx.x;
  const int oy = blockIdx.x, cog = blockIdx.y, b = blockIdx.z;
  const int wave = tid >> 6, lane = tid & 63;
  const int wr = wave >> 1, wc = wave & 1;
  const int col_l = lane & 15, kg = lane >> 4;
  const int iy0 = 2*oy - 1;
  f32x4 acc[2][2] = {};
  unsigned short* sAf = &sA[0][0][0][0];
  const unsigned short* bsrc = w2 + (long)cog*16*24576;

  int aOff[6], aLdsO[6]; bool aOk[6];
  #pragma unroll
  for (int j = 0; j < 6; ++j) {
    int idx = tid + j*256;
    int px = idx & 127, rr = (idx >> 7) & 3, pl = idx >> 9;
    int iy = iy0 + rr;
    aOk[j] = (iy >= 0 && iy < 128);
    aOff[j] = (int)(pl*PS1 + (long)(b*128 + (aOk[j]?iy:0))*16384 + px*8);
    aLdsO[j] = ((pl*4 + rr)*130 + px + 1)*8;
  }
  uint4 pA[6];
  #pragma unroll
  for (int j=0;j<6;j++)  pA[j] = aOk[j] ? *(const uint4*)(h1 + aOff[j]) : zero4();

  if (tid < 24) {
    int pl = tid>>3, rr=(tid>>1)&3, c=tid&1;
    *(uint4*)&sA[pl][rr][c?129:0][0] = zero4();
  }

  for (int ch = 0; ch < 16; ++ch) {
    __syncthreads();
    #pragma unroll
    for (int j=0;j<6;j++)  *(uint4*)(sAf + aLdsO[j]) = pA[j];
    #pragma unroll
    for (int j = 0; j < 12; ++j) {
      int blk = wave*12 + j;
      gload_lds16(bsrc + (long)ch*24576 + blk*512 + lane*8, &sB[blk*512]);
    }
    __syncthreads();
    // post-barrier A prefetch: HBM latency hides under this chunk's MFMA
    if (ch < 15) {
      #pragma unroll
      for (int j=0;j<6;j++)  pA[j] = aOk[j] ? *(const uint4*)(h1 + aOff[j] + (ch+1)*1024) : zero4();
      __builtin_amdgcn_sched_barrier(0);
    }
    #pragma unroll
    for (int s = 0; s < 4; ++s) {        // s = ky
      bf16x8 aF[2][3]; bf16x8 bF[2][3];
      const int tap = s*4 + kg;
      #pragma unroll
      for (int mf = 0; mf < 2; ++mf) {
        int ox = wr*32 + mf*16 + col_l;
        #pragma unroll
        for (int pl = 0; pl < 3; ++pl)
          aF[mf][pl] = *(const bf16x8*)&sA[pl][s][2*ox + kg][0];
      }
      #pragma unroll
      for (int nf = 0; nf < 2; ++nf) {
        int co = wc*32 + nf*16 + col_l;
        int ba = (co*16 + (tap ^ (co&15)))*8;
        bF[nf][0] = *(const bf16x8*)&sB[ba];
        bF[nf][1] = *(const bf16x8*)&sB[ba + 8192];
        bF[nf][2] = *(const bf16x8*)&sB[ba + 16384];
      }
      __builtin_amdgcn_s_setprio(1);
      #pragma unroll
      for (int mf = 0; mf < 2; ++mf)
      #pragma unroll
      for (int nf = 0; nf < 2; ++nf) {
        f32x4 a = acc[mf][nf];
        a = MFMA16(aF[mf][0], bF[nf][0], a);
        a = MFMA16(aF[mf][0], bF[nf][1], a);
        a = MFMA16(aF[mf][1], bF[nf][0], a);
        a = MFMA16(aF[mf][0], bF[nf][2], a);
        a = MFMA16(aF[mf][2], bF[nf][0], a);
        a = MFMA16(aF[mf][1], bF[nf][1], a);
        acc[mf][nf] = a;
      }
      __builtin_amdgcn_s_setprio(0);
    }
  }
  // epilogue: acc -> sB[pl][co64][72pad] -> interleaved h2I
  __syncthreads();
  #pragma unroll
  for (int nf = 0; nf < 2; ++nf) {
    int co = wc*32 + nf*16 + col_l;
    float bv = bias[cog*64 + co];
    #pragma unroll
    for (int mf = 0; mf < 2; ++mf) {
      int px0 = wr*32 + mf*16 + kg*4;
      u16x4 oh, om, ol;
      #pragma unroll
      for (int r = 0; r < 4; ++r) {
        float v = fmaxf(acc[mf][nf][r] + bv, 0.f);
        unsigned short h,m,l; split3(v,h,m,l);
        oh[r]=h; om[r]=m; ol[r]=l;
      }
      *(u16x4*)&sB[(0*64 + co)*72 + px0] = oh;
      *(u16x4*)&sB[(1*64 + co)*72 + px0] = om;
      *(u16x4*)&sB[(2*64 + co)*72 + px0] = ol;
    }
  }
  __syncthreads();
  #pragma unroll
  for (int j = 0; j < 6; ++j) {
    int idx = tid + j*256;
    int pl = idx >> 9, ch = (idx >> 6) & 7, px = idx & 63;
    unsigned short tmp[8];
    #pragma unroll
    for (int c = 0; c < 8; ++c) tmp[c] = sB[(pl*64 + ch*8 + c)*72 + px];
    *(uint4*)(h2I + ((((long)(b*64 + oy)*3 + pl)*16 + cog*8 + ch)*64 + px)*8) = *(uint4*)tmp;
  }
}

// ---------------- conv3: MFMA 6-term split; A+B via global_load_lds ----------------
__global__ __launch_bounds__(256, 2) void conv3_mfma(
    const unsigned short* __restrict__ h2I,  // [b][row64][pl3][ch16][px64][8]
    const unsigned short* __restrict__ w2,   // LDS-image: [ch][24576 shorts]
    const float* __restrict__ bias,
    unsigned short* __restrict__ zeH, unsigned short* __restrict__ zeM,
    unsigned short* __restrict__ zeL) {
  __shared__ __align__(16) unsigned short sA3[3][3][68][8];
  __shared__ __align__(16) unsigned short sB[24576];
  const int tid = threadIdx.x;
  const int oy = blockIdx.x, b = blockIdx.z;
  const int wave = tid >> 6, lane = tid & 63;
  const int wr = wave >> 1, wc = wave & 1;
  const int col_l = lane & 15, kg = lane >> 4;
  f32x4 acc[2][2] = {};
  if (tid < 27) {
    int row = tid/3, c = tid%3;
    int pl = row/3, rr = row%3;
    *(uint4*)&sA3[pl][rr][(c==0)?0:(64+c)][0] = zero4();
  }
  if (oy == 0 && tid < 192) {
    int pl = tid >> 6, px = tid & 63;
    *(uint4*)&sA3[pl][0][px+1][0] = zero4();
  }
  if (oy == 63 && tid < 192) {
    int pl = tid >> 6, px = tid & 63;
    *(uint4*)&sA3[pl][2][px+1][0] = zero4();
  }

  for (int ch = 0; ch < 16; ++ch) {
    __syncthreads();
    #pragma unroll
    for (int j = 0; j < 3; ++j) {
      int row = wave*3 + j;
      if (row < 9) {
        int pl = row/3, rr = row%3;
        int iy = oy + rr - 1;
        if (iy >= 0 && iy < 64)
          gload_lds16(h2I + ((((long)(b*64 + iy)*3 + pl)*16 + ch)*64)*8 + lane*8,
                      &sA3[pl][rr][1][0]);
      }
    }
    #pragma unroll
    for (int j = 0; j < 12; ++j) {
      int blk = wave*12 + j;
      gload_lds16(w2 + (long)ch*24576 + blk*512 + lane*8, &sB[blk*512]);
    }
    __syncthreads();
    #pragma unroll
    for (int s = 0; s < 3; ++s) {
      bf16x8 aF[2][3]; bf16x8 bF[2][3];
      const int tap = s*4 + kg;
      #pragma unroll
      for (int mf = 0; mf < 2; ++mf) {
        int ox = wr*32 + mf*16 + col_l;
        #pragma unroll
        for (int pl = 0; pl < 3; ++pl)
          aF[mf][pl] = *(const bf16x8*)&sA3[pl][s][ox + kg][0];
      }
      #pragma unroll
      for (int nf = 0; nf < 2; ++nf) {
        int co = wc*32 + nf*16 + col_l;
        int ba = (co*16 + (tap ^ (co&15)))*8;
        bF[nf][0] = *(const bf16x8*)&sB[ba];
        bF[nf][1] = *(const bf16x8*)&sB[ba + 8192];
        bF[nf][2] = *(const bf16x8*)&sB[ba + 16384];
      }
      __builtin_amdgcn_s_setprio(1);
      #pragma unroll
      for (int mf = 0; mf < 2; ++mf)
      #pragma unroll
      for (int nf = 0; nf < 2; ++nf) {
        f32x4 a = acc[mf][nf];
        a = MFMA16(aF[mf][0], bF[nf][0], a);
        a = MFMA16(aF[mf][0], bF[nf][1], a);
        a = MFMA16(aF[mf][1], bF[nf][0], a);
        a = MFMA16(aF[mf][0], bF[nf][2], a);
        a = MFMA16(aF[mf][2], bF[nf][0], a);
        a = MFMA16(aF[mf][1], bF[nf][1], a);
        acc[mf][nf] = a;
      }
      __builtin_amdgcn_s_setprio(0);
    }
  }
  __syncthreads();
  #pragma unroll
  for (int nf = 0; nf < 2; ++nf) {
    int co = wc*32 + nf*16 + col_l;
    float bv = bias[co];
    #pragma unroll
    for (int mf = 0; mf < 2; ++mf) {
      int px0 = wr*32 + mf*16 + kg*4;
      u16x4 oh, om, ol;
      #pragma unroll
      for (int r = 0; r < 4; ++r) {
        float v = acc[mf][nf][r] + bv;
        unsigned short h,m,l; split3(v,h,m,l);
        oh[r]=h; om[r]=m; ol[r]=l;
      }
      *(u16x4*)&sB[(0*64 + co)*72 + px0] = oh;
      *(u16x4*)&sB[(1*64 + co)*72 + px0] = om;
      *(u16x4*)&sB[(2*64 + co)*72 + px0] = ol;
    }
  }
  __syncthreads();
  #pragma unroll
  for (int j = 0; j < 6; ++j) {
    int idx = tid + j*256;
    int pl = idx >> 9, co_l = (idx >> 3) & 63, q = idx & 7;
    uint4 v = *(const uint4*)&sB[(pl*64 + co_l)*72 + q*8];
    unsigned short* dst = (pl==0) ? zeH : ((pl==1) ? zeM : zeL);
    *(uint4*)(dst + ((long)(b*64 + co_l)*64 + oy)*64 + q*8) = v;
  }
}

// ---------------- MFMA ConvTranspose2d s2k4p1; 2-pass epilogue; post-barrier prefetch -----
template<int TX, int MODE>
struct SmemD {
  union {
    struct { __align__(16) unsigned short In[2][TX+2][24];
             __align__(16) unsigned short W[2*128*64]; } o;
    struct { __align__(16) unsigned short In[2][TX+2][16];
             __align__(16) unsigned short W[2*128*64]; } v;
    __align__(16) unsigned short Out[128][136];
  };
};

template<int CIN, int TX, int MODE>
__global__ __launch_bounds__(TX*4, (TX==64)?4:6) void deconv_mfma(
    const void* __restrict__ xin, const unsigned short* __restrict__ w2,
    const float* __restrict__ bias, unsigned short* __restrict__ yI) {
  constexpr int NTHR = TX*4;
  constexpr int NWAVE = NTHR/64;
  constexpr int NWG  = 32/NWAVE;
  __shared__ SmemD<TX,MODE> sm;
  unsigned short* Wb = MODE ? &sm.v.W[0] : &sm.o.W[0];

  const int tid = threadIdx.x;
  const int ty = blockIdx.x, e = blockIdx.y, b = blockIdx.z;
  const int wave = tid >> 6, lane = tid & 63;
  const int wc = wave & 1, wr = wave >> 1;
  const int f = (wr*64) / TX;
  const int tx_base = (wr*64) & (TX-1);
  const int col_l = lane & 15, kg = lane >> 4;
  const unsigned short* wsrc = w2 + (long)e*(CIN/16)*16384;

  constexpr int TPR = NTHR/32;
  const int rowid = tid / TPR, liO = tid % TPR;
  const int sci = rowid >> 1, srr = rowid & 1;
  float4 pLo, pHi; uint4 pIn;
  long aBase = 0; bool aOk = false;
  int pxV = 0, halfV = 0, rrV = 0;
  if (MODE == 0) {
    int iy = ty + e - 1 + srr;
    aOk = (iy >= 0 && iy < TX);
    aBase = ((long)b*CIN + sci)*TX*TX + (long)(aOk?iy:0)*TX + liO*8;
    if (aOk) { const float4* s4 = (const float4*)((const float*)xin + aBase);
               pLo = s4[0]; pHi = s4[1]; }
  } else {
    halfV = tid & 1; pxV = (tid >> 1) & (TX-1); rrV = tid >> 8;
    int iy = ty + e - 1 + rrV;
    aOk = (iy >= 0 && iy < TX);
    aBase = ((long)b*TX + (aOk?iy:0))*((long)(CIN/8)*TX*8) + (long)halfV*TX*8 + pxV*8;
    pIn = aOk ? *(const uint4*)((const unsigned short*)xin + aBase) : zero4();
  }

  if (MODE == 0) {
    if (tid < 64) {
      int rr = tid & 1, cc = ((tid>>1)&1) ? TX+1 : 0, ci = tid >> 2;
      sm.o.In[rr][cc][ci] = 0;
    }
  } else {
    if (tid < 8) {
      int rr = tid & 1, c = (tid>>1)&1, hf = (tid>>2)&1;
      *(uint4*)&sm.v.In[rr][c?TX+1:0][hf*8] = zero4();
    }
  }

  f32x4 acc[4][4] = {};
  for (int ch = 0; ch < CIN/16; ++ch) {
    __syncthreads();
    if (MODE == 0) {
      unsigned short vals[8];
      if (aOk) {
        float4 lo = pLo, hi = pHi;
        vals[0]=bfbits(lo.x); vals[1]=bfbits(lo.y); vals[2]=bfbits(lo.z); vals[3]=bfbits(lo.w);
        vals[4]=bfbits(hi.x); vals[5]=bfbits(hi.y); vals[6]=bfbits(hi.z); vals[7]=bfbits(hi.w);
      } else {
        #pragma unroll
        for (int j=0;j<8;j++) vals[j] = 0;
      }
      #pragma unroll
      for (int j=0;j<8;j++) {
        int jj = (j + liO) & 7;
        sm.o.In[srr][1 + liO*8 + jj][sci] = vals[jj];
      }
    } else {
      *(uint4*)&sm.v.In[rrV][pxV+1][halfV*8] = pIn;
    }
    #pragma unroll
    for (int j = 0; j < NWG; ++j) {
      int blk = wave*NWG + j;
      gload_lds16(wsrc + (long)ch*16384 + blk*512 + lane*8, Wb + blk*512);
    }
    __syncthreads();
    // post-barrier A prefetch
    if (ch + 1 < CIN/16) {
      if (MODE == 0) {
        if (aOk) { const float4* s4 = (const float4*)((const float*)xin + aBase + (long)(ch+1)*16*TX*TX);
                   pLo = s4[0]; pHi = s4[1]; }
      } else {
        pIn = aOk ? *(const uint4*)((const unsigned short*)xin + aBase + (ch+1)*2*TX*8) : zero4();
      }
      __builtin_amdgcn_sched_barrier(0);
    }
    #pragma unroll
    for (int kk = 0; kk < 2; ++kk) {
      bf16x8 aF[4];
      const int tap = kk*2 + (kg >> 1), a = tap >> 1, bb = tap & 1;
      #pragma unroll
      for (int mf = 0; mf < 4; ++mf) {
        int tx = tx_base + mf*16 + col_l;
        if (MODE == 0) aF[mf] = *(const bf16x8*)&sm.o.In[1-a][tx + 1 + f - bb][(kg&1)*8];
        else           aF[mf] = *(const bf16x8*)&sm.v.In[1-a][tx + 1 + f - bb][(kg&1)*8];
      }
      const int slot = kk*4 + kg;
      __builtin_amdgcn_s_setprio(1);
      #pragma unroll
      for (int nf = 0; nf < 4; ++nf) {
        int co_l = nf*16 + col_l;
        bf16x8 bF = *(const bf16x8*)(Wb + (f*128 + wc*64 + co_l)*64 + (slot ^ (co_l & 7))*8);
        #pragma unroll
        for (int mf = 0; mf < 4; ++mf)
          acc[mf][nf] = MFMA16(aF[mf], bF, acc[mf][nf]);
      }
      __builtin_amdgcn_s_setprio(0);
    }
  }

  // epilogue
  __syncthreads();
  float bv[4];
  #pragma unroll
  for (int nf = 0; nf < 4; ++nf) bv[nf] = bias[wc*64 + nf*16 + col_l];
  const int oy = 2*ty + e;
  if constexpr (TX == 64) {
    #pragma unroll
    for (int mf = 0; mf < 4; ++mf)
    #pragma unroll
    for (int nf = 0; nf < 4; ++nf) {
      int co = wc*64 + nf*16 + col_l;
      #pragma unroll
      for (int r = 0; r < 4; ++r) {
        int tx = tx_base + mf*16 + kg*4 + r;
        float v = fmaxf(acc[mf][nf][r] + bv[nf], 0.f);
        int ox = 2*tx + f;
        sm.Out[ox][co ^ (((ox>>3)&7)<<3)] = bfbits(v);
      }
    }
    __syncthreads();
    #pragma unroll
    for (int j = 0; j < 8; ++j) {
      int i = tid + j*NTHR;
      int px = i & 127, chn = i >> 7;
      uint4 vv = *(const uint4*)&sm.Out[px][(chn*8) ^ (((px>>3)&7)<<3)];
      *(uint4*)(yI + ((((long)b*128 + oy)*16 + chn)*128 + px)*8) = vv;
    }
  } else {
    const int myp = wr & 1;   // wave-uniform: which 128-px half this wave produces
    #pragma unroll
    for (int p = 0; p < 2; ++p) {
      if (myp == p) {
        #pragma unroll
        for (int mf = 0; mf < 4; ++mf)
        #pragma unroll
        for (int nf = 0; nf < 4; ++nf) {
          int co = wc*64 + nf*16 + col_l;
          #pragma unroll
          for (int r = 0; r < 4; ++r) {
            int tx = tx_base + mf*16 + kg*4 + r;
            float v = fmaxf(acc[mf][nf][r] + bv[nf], 0.f);
            int ox = 2*tx + f;
            sm.Out[ox & 127][co ^ (((ox>>3)&7)<<3)] = bfbits(v);
          }
        }
      }
      __syncthreads();
      #pragma unroll
      for (int j = 0; j < 4; ++j) {
        int i = tid + j*NTHR;
        int px = i & 127, chn = i >> 7;
        uint4 vv = *(const uint4*)&sm.Out[px][(chn*8) ^ (((px>>3)&7)<<3)];
        int pxg = p*128 + px;
        *(uint4*)(yI + ((((long)b*256 + oy)*16 + chn)*256 + pxg)*8) = vv;
      }
      if (p == 0) __syncthreads();
    }
  }
}

// ---------------- deconv3: MFMA + sigmoid; post-barrier prefetch ----------
__global__ __launch_bounds__(256, 2) void deconv3_mfma(
    const unsigned short* __restrict__ g2I,
    const unsigned short* __restrict__ w2,
    const float* __restrict__ bias, float* __restrict__ y) {
  __shared__ __align__(16) unsigned short sA[3][260][8];
  __shared__ __align__(16) unsigned short sB[16*12*16*8];
  const int tid = threadIdx.x;
  const int oy = blockIdx.x, b = blockIdx.y;
  const int wave = tid >> 6, lane = tid & 63;
  const int col_l = lane & 15, kg = lane >> 4;
  const int pxb = wave*64;
  for (int i = tid; i < 3072; i += 256) {
    int co = i & 15, tap = (i>>4) % 12, ch = i/192;
    *(uint4*)&sB[((ch*12+tap)*16+co)*8] = *(const uint4*)(w2 + (long)co*1536 + ch*96 + tap*8);
  }
  if (tid < 12) {
    int dy = tid >> 2, c = tid & 3;
    *(uint4*)&sA[dy][(c<2)?c:(256+c)][0] = zero4();
  }
  long aBase[3]; int aLdsO[3]; bool aOk[3];
  #pragma unroll
  for (int u = 0; u < 3; ++u) {
    int idx = tid + u*256;
    int px = idx & 255, dy = idx >> 8;
    int iy = oy - 1 + dy;
    aOk[u] = (iy >= 0 && iy < 256);
    aBase[u] = ((long)(b*256 + (aOk[u]?iy:0)))*32768 + px*8;
    aLdsO[u] = (dy*260 + px + 2)*8;
  }
  uint4 pA[3];
  #pragma unroll
  for (int u=0;u<3;u++) pA[u] = aOk[u] ? *(const uint4*)(g2I + aBase[u]) : zero4();

  unsigned short* sAf = &sA[0][0][0];
  f32x4 acc[4] = {};
  for (int ch = 0; ch < 16; ++ch) {
    __syncthreads();
    #pragma unroll
    for (int u=0;u<3;u++) *(uint4*)(sAf + aLdsO[u]) = pA[u];
    __syncthreads();
    if (ch < 15) {
      #pragma unroll
      for (int u=0;u<3;u++)
        pA[u] = aOk[u] ? *(const uint4*)(g2I + aBase[u] + (ch+1)*2048) : zero4();
      __builtin_amdgcn_sched_barrier(0);
    }
    #pragma unroll
    for (int s = 0; s < 3; ++s) {
      bf16x8 bF = *(const bf16x8*)&sB[((ch*12 + s*4 + kg)*16 + col_l)*8];
      __builtin_amdgcn_s_setprio(1);
      #pragma unroll
      for (int mf = 0; mf < 4; ++mf) {
        int px = pxb + mf*16 + col_l;
        bf16x8 aF = *(const bf16x8*)&sA[2-s][px + 3 - kg][0];
        acc[mf] = MFMA16(aF, bF, acc[mf]);
      }
      __builtin_amdgcn_s_setprio(0);
    }
  }
  if (col_l < 3) {
    float bv = bias[col_l];
    #pragma unroll
    for (int mf = 0; mf < 4; ++mf) {
      int px = pxb + mf*16 + kg*4;
      float4 o;
      o.x = 1.f/(1.f + expf(-(acc[mf][0] + bv)));
      o.y = 1.f/(1.f + expf(-(acc[mf][1] + bv)));
      o.z = 1.f/(1.f + expf(-(acc[mf][2] + bv)));
      o.w = 1.f/(1.f + expf(-(acc[mf][3] + bv)));
      *(float4*)(y + ((long)(b*3 + col_l)*256 + oy)*256 + px) = o;
    }
  }
}

// ---------------- VQ via MFMA (unchanged) ----------------
__global__ __launch_bounds__(256, 2) void vq_mfma(
    const unsigned short* __restrict__ zeH, const unsigned short* __restrict__ zeM,
    const unsigned short* __restrict__ zeL,
    const float* __restrict__ emb, const float* __restrict__ esq,
    float* __restrict__ out_idx, float* __restrict__ zq) {
  __shared__ __align__(16) unsigned short sA[64*3*8*8];
  __shared__ __align__(16) unsigned short sB[128*3*8*8];
  __shared__ float snb[128];
  __shared__ int sidx[64];
  const int tid = threadIdx.x;
  const long n0 = (long)blockIdx.x*64;
  const int wave = tid >> 6, lane = tid & 63;
  const int col = lane & 15, kg = lane >> 4;

  #pragma unroll
  for (int j = 0; j < 6; ++j) {
    int idx = tid + j*256;
    int pl = idx >> 9, rem = idx & 511;
    int n = rem >> 3, slot = rem & 7;
    const unsigned short* src = (pl==0 ? zeH : (pl==1 ? zeM : zeL)) + (n0+n)*64 + slot*8;
    *(uint4*)&sA[((n*3 + pl)*8 + (slot ^ (n&7)))*8] = *(const uint4*)src;
  }

  const int codeT = tid >> 1, halfT = tid & 1;
  float4 pB[8];
  #pragma unroll
  for (int q = 0; q < 8; ++q)
    pB[q] = *(const float4*)(emb + (long)codeT*64 + halfT*32 + q*4);
  float pSn = (tid < 128) ? esq[tid] : 0.f;

  float best[4] = {3.4e38f,3.4e38f,3.4e38f,3.4e38f};
  int bidx[4] = {0,0,0,0};

  for (int ch = 0; ch < 4; ++ch) {
    __syncthreads();
    #pragma unroll
    for (int s4 = 0; s4 < 4; ++s4) {
      int slot = halfT*4 + s4;
      float4 lo = pB[s4*2], hi = pB[s4*2+1];
      unsigned short th[8], tm[8], tl[8];
      split3(lo.x, th[0], tm[0], tl[0]); split3(lo.y, th[1], tm[1], tl[1]);
      split3(lo.z, th[2], tm[2], tl[2]); split3(lo.w, th[3], tm[3], tl[3]);
      split3(hi.x, th[4], tm[4], tl[4]); split3(hi.y, th[5], tm[5], tl[5]);
      split3(hi.z, th[6], tm[6], tl[6]); split3(hi.w, th[7], tm[7], tl[7]);
      int base = ((codeT*3)*8 + (slot ^ (codeT&7)))*8;
      *(uint4*)&sB[base]       = *(uint4*)th;
      *(uint4*)&sB[base + 64]  = *(uint4*)tm;
      *(uint4*)&sB[base + 128] = *(uint4*)tl;
    }
    if (tid < 128) snb[tid] = pSn;
    if (ch < 3) {
      #pragma unroll
      for (int q = 0; q < 8; ++q)
        pB[q] = *(const float4*)(emb + ((long)(ch+1)*128 + codeT)*64 + halfT*32 + q*4);
      if (tid < 128) pSn = esq[(ch+1)*128 + tid];
    }
    __syncthreads();

    f32x4 acc[8] = {};
    #pragma unroll
    for (int kk = 0; kk < 2; ++kk) {
      const int nloc = wave*16 + col;
      const int slot = kk*4 + kg;
      bf16x8 aF[3];
      #pragma unroll
      for (int pl = 0; pl < 3; ++pl)
        aF[pl] = *(const bf16x8*)&sA[((nloc*3 + pl)*8 + (slot ^ (nloc&7)))*8];
      __builtin_amdgcn_s_setprio(1);
      #pragma unroll
      for (int cf = 0; cf < 8; ++cf) {
        int cl = cf*16 + col;
        int bb = ((cl*3)*8 + (slot ^ (cl&7)))*8;
        bf16x8 b0 = *(const bf16x8*)&sB[bb];
        bf16x8 b1 = *(const bf16x8*)&sB[bb + 64];
        bf16x8 b2 = *(const bf16x8*)&sB[bb + 128];
        f32x4 a = acc[cf];
        a = MFMA16(aF[0], b0, a);
        a = MFMA16(aF[0], b1, a);
        a = MFMA16(aF[1], b0, a);
        a = MFMA16(aF[0], b2, a);
        a = MFMA16(aF[2], b0, a);
        a = MFMA16(aF[1], b1, a);
        acc[cf] = a;
      }
      __builtin_amdgcn_s_setprio(0);
    }
    #pragma unroll
    for (int cf = 0; cf < 8; ++cf) {
      float sv = snb[cf*16 + col];
      int code = ch*128 + cf*16 + col;
      #pragma unroll
      for (int j = 0; j < 4; ++j) {
        float s = sv - 2.f*acc[cf][j];
        if (s < best[j]) { best[j] = s; bidx[j] = code; }
      }
    }
  }

  #pragma unroll
  for (int j = 0; j < 4; ++j) {
    float b = best[j]; int ii = bidx[j];
    #pragma unroll
    for (int off = 1; off < 16; off <<= 1) {
      float ob = __shfl_xor(b, off);
      int oi = __shfl_xor(ii, off);
      if (ob < b || (ob == b && oi < ii)) { b = ob; ii = oi; }
    }
    if (col == 0) sidx[wave*16 + kg*4 + j] = ii;
  }
  __syncthreads();
  if (tid < 64) out_idx[n0 + tid] = (float)sidx[tid];
  #pragma unroll
  for (int j = 0; j < 4; ++j) {
    int t = tid + j*256;
    int row = t >> 4, q = t & 15;
    float4 v = *(const float4*)(emb + (long)sidx[row]*64 + q*4);
    *(float4*)(zq + (n0 + row)*64 + q*4) = v;
  }
}

// ---------------- launch ----------------
extern "C" void kernel_launch(void* const* d_in, const int* in_sizes, int n_in,
                              void* d_out, int out_size, void* d_ws, size_t ws_size,
                              hipStream_t stream) {
  const float* x   = (const float*)d_in[0];
  const float* c1w = (const float*)d_in[1];  const float* c1b = (const float*)d_in[2];
  const float* c2w = (const float*)d_in[3];  const float* c2b = (const float*)d_in[4];
  const float* c3w = (const float*)d_in[5];  const float* c3b = (const float*)d_in[6];
  const float* emb = (const float*)d_in[7];
  const float* d1w = (const float*)d_in[8];  const float* d1b = (const float*)d_in[9];
  const float* d2w = (const float*)d_in[10]; const float* d2b = (const float*)d_in[11];
  const float* d3w = (const float*)d_in[12]; const float* d3b = (const float*)d_in[13];
  float* out = (float*)d_out;

  float* xrec = out;
  float* oidx = out + 3145728;
  float* zq   = out + 3211264;

  const long XB  = 196608;   // 3*256*256
  const long ZEB = 262144;   // ze elems per batch
  const long PS1 = 8388608;  // per-plane h1 (interleaved) in shorts
  const long H2B = 1572864;  // per-batch h2I stride in shorts

  const size_t NEEDED = 112273408ULL;  // known: ws_size >= 120,395,264
  if (ws_size < NEEDED) return;
  char* wsb = (char*)d_ws;
  unsigned short* h1grp = (unsigned short*)wsb;              // interleaved, 50.3MB
  unsigned short* g2grp = (unsigned short*)wsb;              // interleaved, 64MB
  unsigned short* h2I   = (unsigned short*)(wsb + 67108864); // interleaved 8-batch, 25.17MB
  unsigned short* g1grp = (unsigned short*)(wsb + 67108864); // interleaved, 16MB
  unsigned short* zeH = (unsigned short*)(wsb + 92274688);
  unsigned short* zeM = (unsigned short*)(wsb + 100663296);
  unsigned short* zeL = (unsigned short*)out;                // xrec region: dead until deconv3
  char* W = wsb + 109051904;
  float* w2c1          = (float*)(W);
  unsigned short* w2c2 = (unsigned short*)(W + 24576);
  unsigned short* w2c3 = (unsigned short*)(W + 1597440);
  unsigned short* w2d1 = (unsigned short*)(W + 2383872);
  unsigned short* w2d2 = (unsigned short*)(W + 2646016);
  unsigned short* w2d3 = (unsigned short*)(W + 3170304);
  float* esq           = (float*)(W + 3219456);

  wprep_all<<<3066, 256, 0, stream>>>(c1w, w2c1, c2w, w2c2, c3w, w2c3,
                                      d1w, w2d1, d2w, w2d2, d3w, w2d3, emb, esq);

  // encoder
  for (int g = 0; g < 4; ++g) {
    conv1_split<<<dim3(16,16,8), 256, 0, stream>>>(
        x + (long)g*4*XB, w2c1, c1b, h1grp, PS1);
    conv2_mfma<<<dim3(64,2,4), 256, 0, stream>>>(
        h1grp, PS1, w2c2, c2b, h2I + (long)(g&1)*4*H2B);
    if (g & 1) {
      long zo = (long)(g>>1)*8*ZEB;
      conv3_mfma<<<dim3(64,1,8), 256, 0, stream>>>(
          h2I, w2c3, c3b, zeH + zo, zeM + zo, zeL + zo);
    }
  }
  vq_mfma<<<1024, 256, 0, stream>>>(zeH, zeM, zeL, emb, esq, oidx, zq);

  // decoder
  for (int g = 0; g < 4; ++g) {
    deconv_mfma<64, 64, 0 ><<<dim3(64, 2, 4), 256, 0, stream>>>(
        (const void*)(zq + (long)g*4*ZEB), w2d1, d1b, g1grp);
    deconv_mfma<128,128,1 ><<<dim3(128,2,4), 512, 0, stream>>>(
        (const void*)g1grp, w2d2, d2b, g2grp);
    deconv3_mfma<<<dim3(256,4), 256, 0, stream>>>(
        g2grp, w2d3, d3b, xrec + (long)g*4*XB);
  }
}

// Round 14
// 744.488 us; speedup vs baseline: 3.0672x; 3.0672x over previous
//
#include <hip/hip_runtime.h>
#include <hip/hip_bf16.h>

#define DEV __device__ __forceinline__

typedef __attribute__((ext_vector_type(8))) short bf16x8;
typedef __attribute__((ext_vector_type(4))) float f32x4;
typedef __attribute__((ext_vector_type(4))) unsigned short u16x4;

#define MFMA16(a,b,c) __builtin_amdgcn_mfma_f32_16x16x32_bf16(a,b,c,0,0,0)

DEV unsigned short bfbits(float v){ __hip_bfloat16 h = __float2bfloat16(v); return *(unsigned short*)&h; }
DEV float bf2f(unsigned short u){ __hip_bfloat16 h = *(__hip_bfloat16*)&u; return __bfloat162float(h); }
DEV void split3(float v, unsigned short& h, unsigned short& m, unsigned short& l) {
  h = bfbits(v);        float r  = v - bf2f(h);
  m = bfbits(r);        float r2 = r - bf2f(m);
  l = bfbits(r2);
}
DEV uint4 zero4(){ uint4 z; z.x=0; z.y=0; z.z=0; z.w=0; return z; }
DEV void gload_lds16(const void* g, void* l) {
  __builtin_amdgcn_global_load_lds(
      (const __attribute__((address_space(1))) void*)g,
      (__attribute__((address_space(3))) void*)l, 16, 0, 0);
}

// ---------------- fused weight prep (one dispatch, 3066 blocks) ----------------
DEV void prep_deconv_img(int i, int CI, const float* __restrict__ w, unsigned short* __restrict__ w2) {
  const int nch = CI/16;
  int cil = i & 7, s = (i >> 3) & 7, co = (i >> 6) & 127, f = (i >> 13) & 1;
  int rest = i >> 14;
  int ch = rest % nch, e = rest / nch;
  int k = ch*64 + s*8 + cil;
  int ci = (k & 15) | ((k >> 6) << 4);
  int tap = (k >> 4) & 3, a = tap >> 1, b = tap & 1;
  float v = w[ (((long)ci*128 + co)*4 + (2*a+1-e))*4 + (2*b+1-f) ];
  w2[(long)(e*nch + ch)*16384 + ((long)(f*128 + co))*64 + ((s ^ (co&7))*8) + cil] = bfbits(v);
}
__global__ __launch_bounds__(256) void wprep_all(
    const float* __restrict__ c1w, float* __restrict__ w2c1,
    const float* __restrict__ c2w, unsigned short* __restrict__ w2c2,
    const float* __restrict__ c3w, unsigned short* __restrict__ w2c3,
    const float* __restrict__ d1w, unsigned short* __restrict__ w2d1,
    const float* __restrict__ d2w, unsigned short* __restrict__ w2d2,
    const float* __restrict__ d3w, unsigned short* __restrict__ w2d3,
    const float* __restrict__ emb, float* __restrict__ esq) {
  const int bx = blockIdx.x, t = threadIdx.x;
  if (bx < 24) {                         // conv1 transpose: 6144
    int i = bx*256 + t;
    if (i < 6144) {
      int tap = i & 15, ci = (i>>4) % 3, co = i / 48;
      w2c1[((long)ci*16 + tap)*128 + co] = c1w[i];
    }
  } else if (bx < 1048) {                // conv2 prep -> LDS-image layout
    int i = (bx-24)*256 + t;             // 0..262143
    int cil = i & 7, s = (i>>3) & 15, co = (i>>7) & 63;
    int ch = (i>>13) & 15, cog = i >> 17;
    int co_g = cog*64 + co, ci = ch*8 + cil, ky = s >> 2, kx = s & 3;
    float v = c2w[(((long)co_g*128 + ci)*4 + ky)*4 + kx];
    unsigned short h,m,l; split3(v,h,m,l);
    long base = (long)(cog*16 + ch)*24576 + ((long)co*16 + (s ^ (co&15)))*8 + cil;
    w2c2[base] = h; w2c2[base + 8192] = m; w2c2[base + 16384] = l;
  } else if (bx < 1432) {                // conv3 prep -> LDS-image layout: 98304
    int i = (bx-1048)*256 + t;
    int k = i % 1536, co = i / 1536;
    int ch = k / 96, rem = k % 96;
    int tap = rem >> 3, cil = rem & 7;
    int ci = ch*8 + cil, ky = tap >> 2, kx = tap & 3;
    float v = (kx < 3) ? c3w[(((long)co*128 + ci)*3 + ky)*3 + kx] : 0.f;
    unsigned short h,m,l; split3(v,h,m,l);
    long base = (long)ch*24576 + ((long)co*16 + (tap ^ (co&15)))*8 + cil;
    w2c3[base] = h; w2c3[base + 8192] = m; w2c3[base + 16384] = l;
  } else if (bx < 1944) {                // deconv1 image: 131072 (CI=64)
    prep_deconv_img((bx-1432)*256 + t, 64, d1w, w2d1);
  } else if (bx < 2968) {                // deconv2 image: 262144 (CI=128)
    prep_deconv_img((bx-1944)*256 + t, 128, d2w, w2d2);
  } else if (bx < 3064) {                // deconv3: 24576
    int i = (bx-2968)*256 + t;
    if (i < 24576) {
      int k = i % 1536, co = i / 1536;
      int ch = k / 96, rem = k % 96;
      int tap = rem >> 3, cil = rem & 7;
      int ci = ch*8 + cil, ky = tap >> 2, kx = tap & 3;
      float v = (co < 3 && kx < 3) ? d3w[(((long)ci*3 + co)*3 + ky)*3 + kx] : 0.f;
      w2d3[i] = bfbits(v);
    }
  } else {                               // esq: 512 codes
    int code = (bx-3064)*256 + t;
    if (code < 512) {
      const float4* ev = (const float4*)(emb + (long)code*64);
      float s = 0.f;
      #pragma unroll
      for (int q=0;q<16;q++){ float4 e4 = ev[q];
        s += e4.x*e4.x + e4.y*e4.y + e4.z*e4.z + e4.w*e4.w; }
      esq[code] = s;
    }
  }
}

// ---------------- conv1: f32 direct, out 3 bf16 planes INTERLEAVED ----------------
__global__ __launch_bounds__(256) void conv1_split(
    const float* __restrict__ x, const float* __restrict__ w2,
    const float* __restrict__ bias, unsigned short* __restrict__ h1, long PS1) {
  __shared__ __align__(16) float sIn[3][18][20];
  __shared__ __align__(16) float sW[3*16*64];
  const int tid = threadIdx.x;
  const int b = blockIdx.z >> 1, cog = blockIdx.z & 1;
  const int co0 = cog*64;
  const int oy0 = blockIdx.y*8, ox0 = blockIdx.x*8;
  const int cg2 = tid >> 5;
  const int pg2 = tid & 31;
  const int r = pg2 >> 2, pxp = (pg2 & 3)*2;
  float acc[8][2];
  #pragma unroll
  for (int c=0;c<8;c++){ float bv = bias[co0 + cg2*8 + c];
    acc[c][0]=bv; acc[c][1]=bv; }
  const float* xb = x + (long)b*3*256*256;
  const int iy0 = 2*oy0 - 1, ix0 = 2*ox0 - 1;
  for (int t=tid; t<3*18*18; t+=256) {
    int xx = t%18, yy=(t/18)%18, ci=t/324;
    int gy = iy0+yy, gx = ix0+xx;
    float v = 0.f;
    if (gy>=0 && gy<256 && gx>=0 && gx<256) v = xb[((long)ci*256+gy)*256+gx];
    sIn[ci][yy][xx] = v;
  }
  for (int t=tid; t<3*16*64; t+=256) {
    sW[t] = w2[(long)(t>>6)*128 + co0 + (t&63)];
  }
  __syncthreads();
  for (int ci=0; ci<3; ci++) {
    #pragma unroll
    for (int ky=0;ky<4;ky++)
    #pragma unroll
    for (int kx=0;kx<4;kx++) {
      const float* wp = &sW[(ci*16 + ky*4+kx)*64 + cg2*8];
      float4 w0 = *(const float4*)wp;
      float4 w1 = *(const float4*)(wp+4);
      const int yy = 2*r + ky;
      #pragma unroll
      for (int p=0;p<2;p++) {
        float iv = sIn[ci][yy][2*(pxp+p)+kx];
        acc[0][p] += w0.x*iv; acc[1][p] += w0.y*iv;
        acc[2][p] += w0.z*iv; acc[3][p] += w0.w*iv;
        acc[4][p] += w1.x*iv; acc[5][p] += w1.y*iv;
        acc[6][p] += w1.z*iv; acc[7][p] += w1.w*iv;
      }
    }
  }
  const int chg = cog*8 + cg2;
  #pragma unroll
  for (int p=0;p<2;p++) {
    unsigned short th[8], tm[8], tl[8];
    #pragma unroll
    for (int c=0;c<8;c++) {
      float v = fmaxf(acc[c][p], 0.f);
      split3(v, th[c], tm[c], tl[c]);
    }
    long base = (((long)(b*128 + oy0+r)*16 + chg)*128 + ox0+pxp+p)*8;
    *(uint4*)(h1 + base)          = *(uint4*)th;
    *(uint4*)(h1 + PS1 + base)    = *(uint4*)tm;
    *(uint4*)(h1 + 2*PS1 + base)  = *(uint4*)tl;
  }
}

// ---------------- conv2: MFMA 6-term split; post-barrier A prefetch ----------
__global__ __launch_bounds__(256, 2) void conv2_mfma(
    const unsigned short* __restrict__ h1, long PS1,
    const unsigned short* __restrict__ w2,   // LDS-image: [cog][ch][24576 shorts]
    const float* __restrict__ bias,
    unsigned short* __restrict__ h2I) {      // [b][row64][pl3][ch16][px64][8]
  __shared__ __align__(16) unsigned short sA[3][4][130][8];
  __shared__ __align__(16) unsigned short sB[24576];
  const int tid = threadIdx.x;
  const int oy = blockIdx.x, cog = blockIdx.y, b = blockIdx.z;
  const int wave = tid >> 6, lane = tid & 63;
  const int wr = wave >> 1, wc = wave & 1;
  const int col_l = lane & 15, kg = lane >> 4;
  const int iy0 = 2*oy - 1;
  f32x4 acc[2][2] = {};
  unsigned short* sAf = &sA[0][0][0][0];
  const unsigned short* bsrc = w2 + (long)cog*16*24576;

  int aOff[6], aLdsO[6]; bool aOk[6];
  #pragma unroll
  for (int j = 0; j < 6; ++j) {
    int idx = tid + j*256;
    int px = idx & 127, rr = (idx >> 7) & 3, pl = idx >> 9;
    int iy = iy0 + rr;
    aOk[j] = (iy >= 0 && iy < 128);
    aOff[j] = (int)(pl*PS1 + (long)(b*128 + (aOk[j]?iy:0))*16384 + px*8);
    aLdsO[j] = ((pl*4 + rr)*130 + px + 1)*8;
  }
  uint4 pA[6];
  #pragma unroll
  for (int j=0;j<6;j++)  pA[j] = aOk[j] ? *(const uint4*)(h1 + aOff[j]) : zero4();

  if (tid < 24) {
    int pl = tid>>3, rr=(tid>>1)&3, c=tid&1;
    *(uint4*)&sA[pl][rr][c?129:0][0] = zero4();
  }

  for (int ch = 0; ch < 16; ++ch) {
    __syncthreads();
    #pragma unroll
    for (int j=0;j<6;j++)  *(uint4*)(sAf + aLdsO[j]) = pA[j];
    #pragma unroll
    for (int j = 0; j < 12; ++j) {
      int blk = wave*12 + j;
      gload_lds16(bsrc + (long)ch*24576 + blk*512 + lane*8, &sB[blk*512]);
    }
    __syncthreads();
    if (ch < 15) {
      #pragma unroll
      for (int j=0;j<6;j++)  pA[j] = aOk[j] ? *(const uint4*)(h1 + aOff[j] + (ch+1)*1024) : zero4();
      __builtin_amdgcn_sched_barrier(0);
    }
    #pragma unroll
    for (int s = 0; s < 4; ++s) {        // s = ky
      bf16x8 aF[2][3]; bf16x8 bF[2][3];
      const int tap = s*4 + kg;
      #pragma unroll
      for (int mf = 0; mf < 2; ++mf) {
        int ox = wr*32 + mf*16 + col_l;
        #pragma unroll
        for (int pl = 0; pl < 3; ++pl)
          aF[mf][pl] = *(const bf16x8*)&sA[pl][s][2*ox + kg][0];
      }
      #pragma unroll
      for (int nf = 0; nf < 2; ++nf) {
        int co = wc*32 + nf*16 + col_l;
        int ba = (co*16 + (tap ^ (co&15)))*8;
        bF[nf][0] = *(const bf16x8*)&sB[ba];
        bF[nf][1] = *(const bf16x8*)&sB[ba + 8192];
        bF[nf][2] = *(const bf16x8*)&sB[ba + 16384];
      }
      __builtin_amdgcn_s_setprio(1);
      #pragma unroll
      for (int mf = 0; mf < 2; ++mf)
      #pragma unroll
      for (int nf = 0; nf < 2; ++nf) {
        f32x4 a = acc[mf][nf];
        a = MFMA16(aF[mf][0], bF[nf][0], a);
        a = MFMA16(aF[mf][0], bF[nf][1], a);
        a = MFMA16(aF[mf][1], bF[nf][0], a);
        a = MFMA16(aF[mf][0], bF[nf][2], a);
        a = MFMA16(aF[mf][2], bF[nf][0], a);
        a = MFMA16(aF[mf][1], bF[nf][1], a);
        acc[mf][nf] = a;
      }
      __builtin_amdgcn_s_setprio(0);
    }
  }
  // epilogue: acc -> sB[pl][co64][72pad] -> interleaved h2I
  __syncthreads();
  #pragma unroll
  for (int nf = 0; nf < 2; ++nf) {
    int co = wc*32 + nf*16 + col_l;
    float bv = bias[cog*64 + co];
    #pragma unroll
    for (int mf = 0; mf < 2; ++mf) {
      int px0 = wr*32 + mf*16 + kg*4;
      u16x4 oh, om, ol;
      #pragma unroll
      for (int r = 0; r < 4; ++r) {
        float v = fmaxf(acc[mf][nf][r] + bv, 0.f);
        unsigned short h,m,l; split3(v,h,m,l);
        oh[r]=h; om[r]=m; ol[r]=l;
      }
      *(u16x4*)&sB[(0*64 + co)*72 + px0] = oh;
      *(u16x4*)&sB[(1*64 + co)*72 + px0] = om;
      *(u16x4*)&sB[(2*64 + co)*72 + px0] = ol;
    }
  }
  __syncthreads();
  #pragma unroll
  for (int j = 0; j < 6; ++j) {
    int idx = tid + j*256;
    int pl = idx >> 9, ch = (idx >> 6) & 7, px = idx & 63;
    unsigned short tmp[8];
    #pragma unroll
    for (int c = 0; c < 8; ++c) tmp[c] = sB[(pl*64 + ch*8 + c)*72 + px];
    *(uint4*)(h2I + ((((long)(b*64 + oy)*3 + pl)*16 + cog*8 + ch)*64 + px)*8) = *(uint4*)tmp;
  }
}

// ---------------- conv3: MFMA 6-term split; A+B via global_load_lds ----------------
__global__ __launch_bounds__(256, 2) void conv3_mfma(
    const unsigned short* __restrict__ h2I,  // [b][row64][pl3][ch16][px64][8]
    const unsigned short* __restrict__ w2,   // LDS-image: [ch][24576 shorts]
    const float* __restrict__ bias,
    unsigned short* __restrict__ zeH, unsigned short* __restrict__ zeM,
    unsigned short* __restrict__ zeL) {
  __shared__ __align__(16) unsigned short sA3[3][3][68][8];
  __shared__ __align__(16) unsigned short sB[24576];
  const int tid = threadIdx.x;
  const int oy = blockIdx.x, b = blockIdx.z;
  const int wave = tid >> 6, lane = tid & 63;
  const int wr = wave >> 1, wc = wave & 1;
  const int col_l = lane & 15, kg = lane >> 4;
  f32x4 acc[2][2] = {};
  if (tid < 27) {
    int row = tid/3, c = tid%3;
    int pl = row/3, rr = row%3;
    *(uint4*)&sA3[pl][rr][(c==0)?0:(64+c)][0] = zero4();
  }
  if (oy == 0 && tid < 192) {
    int pl = tid >> 6, px = tid & 63;
    *(uint4*)&sA3[pl][0][px+1][0] = zero4();
  }
  if (oy == 63 && tid < 192) {
    int pl = tid >> 6, px = tid & 63;
    *(uint4*)&sA3[pl][2][px+1][0] = zero4();
  }

  for (int ch = 0; ch < 16; ++ch) {
    __syncthreads();
    #pragma unroll
    for (int j = 0; j < 3; ++j) {
      int row = wave*3 + j;
      if (row < 9) {
        int pl = row/3, rr = row%3;
        int iy = oy + rr - 1;
        if (iy >= 0 && iy < 64)
          gload_lds16(h2I + ((((long)(b*64 + iy)*3 + pl)*16 + ch)*64)*8 + lane*8,
                      &sA3[pl][rr][1][0]);
      }
    }
    #pragma unroll
    for (int j = 0; j < 12; ++j) {
      int blk = wave*12 + j;
      gload_lds16(w2 + (long)ch*24576 + blk*512 + lane*8, &sB[blk*512]);
    }
    __syncthreads();
    #pragma unroll
    for (int s = 0; s < 3; ++s) {
      bf16x8 aF[2][3]; bf16x8 bF[2][3];
      const int tap = s*4 + kg;
      #pragma unroll
      for (int mf = 0; mf < 2; ++mf) {
        int ox = wr*32 + mf*16 + col_l;
        #pragma unroll
        for (int pl = 0; pl < 3; ++pl)
          aF[mf][pl] = *(const bf16x8*)&sA3[pl][s][ox + kg][0];
      }
      #pragma unroll
      for (int nf = 0; nf < 2; ++nf) {
        int co = wc*32 + nf*16 + col_l;
        int ba = (co*16 + (tap ^ (co&15)))*8;
        bF[nf][0] = *(const bf16x8*)&sB[ba];
        bF[nf][1] = *(const bf16x8*)&sB[ba + 8192];
        bF[nf][2] = *(const bf16x8*)&sB[ba + 16384];
      }
      __builtin_amdgcn_s_setprio(1);
      #pragma unroll
      for (int mf = 0; mf < 2; ++mf)
      #pragma unroll
      for (int nf = 0; nf < 2; ++nf) {
        f32x4 a = acc[mf][nf];
        a = MFMA16(aF[mf][0], bF[nf][0], a);
        a = MFMA16(aF[mf][0], bF[nf][1], a);
        a = MFMA16(aF[mf][1], bF[nf][0], a);
        a = MFMA16(aF[mf][0], bF[nf][2], a);
        a = MFMA16(aF[mf][2], bF[nf][0], a);
        a = MFMA16(aF[mf][1], bF[nf][1], a);
        acc[mf][nf] = a;
      }
      __builtin_amdgcn_s_setprio(0);
    }
  }
  __syncthreads();
  #pragma unroll
  for (int nf = 0; nf < 2; ++nf) {
    int co = wc*32 + nf*16 + col_l;
    float bv = bias[co];
    #pragma unroll
    for (int mf = 0; mf < 2; ++mf) {
      int px0 = wr*32 + mf*16 + kg*4;
      u16x4 oh, om, ol;
      #pragma unroll
      for (int r = 0; r < 4; ++r) {
        float v = acc[mf][nf][r] + bv;
        unsigned short h,m,l; split3(v,h,m,l);
        oh[r]=h; om[r]=m; ol[r]=l;
      }
      *(u16x4*)&sB[(0*64 + co)*72 + px0] = oh;
      *(u16x4*)&sB[(1*64 + co)*72 + px0] = om;
      *(u16x4*)&sB[(2*64 + co)*72 + px0] = ol;
    }
  }
  __syncthreads();
  #pragma unroll
  for (int j = 0; j < 6; ++j) {
    int idx = tid + j*256;
    int pl = idx >> 9, co_l = (idx >> 3) & 63, q = idx & 7;
    uint4 v = *(const uint4*)&sB[(pl*64 + co_l)*72 + q*8];
    unsigned short* dst = (pl==0) ? zeH : ((pl==1) ? zeM : zeL);
    *(uint4*)(dst + ((long)(b*64 + co_l)*64 + oy)*64 + q*8) = v;
  }
}

// ---------------- MFMA ConvTranspose2d s2k4p1; 2-pass epilogue; post-barrier prefetch -----
template<int TX, int MODE>
struct SmemD {
  union {
    struct { __align__(16) unsigned short In[2][TX+2][24];
             __align__(16) unsigned short W[2*128*64]; } o;
    struct { __align__(16) unsigned short In[2][TX+2][16];
             __align__(16) unsigned short W[2*128*64]; } v;
    __align__(16) unsigned short Out[128][136];
  };
};

template<int CIN, int TX, int MODE>
__global__ __launch_bounds__(TX*4, (TX==64)?3:4) void deconv_mfma(
    const void* __restrict__ xin, const unsigned short* __restrict__ w2,
    const float* __restrict__ bias, unsigned short* __restrict__ yI) {
  constexpr int NTHR = TX*4;
  constexpr int NWAVE = NTHR/64;
  constexpr int NWG  = 32/NWAVE;
  __shared__ SmemD<TX,MODE> sm;
  unsigned short* Wb = MODE ? &sm.v.W[0] : &sm.o.W[0];

  const int tid = threadIdx.x;
  const int ty = blockIdx.x, e = blockIdx.y, b = blockIdx.z;
  const int wave = tid >> 6, lane = tid & 63;
  const int wc = wave & 1, wr = wave >> 1;
  const int f = (wr*64) / TX;
  const int tx_base = (wr*64) & (TX-1);
  const int col_l = lane & 15, kg = lane >> 4;
  const unsigned short* wsrc = w2 + (long)e*(CIN/16)*16384;

  constexpr int TPR = NTHR/32;
  const int rowid = tid / TPR, liO = tid % TPR;
  const int sci = rowid >> 1, srr = rowid & 1;
  float4 pLo, pHi; uint4 pIn;
  long aBase = 0; bool aOk = false;
  int pxV = 0, halfV = 0, rrV = 0;
  if (MODE == 0) {
    int iy = ty + e - 1 + srr;
    aOk = (iy >= 0 && iy < TX);
    aBase = ((long)b*CIN + sci)*TX*TX + (long)(aOk?iy:0)*TX + liO*8;
    if (aOk) { const float4* s4 = (const float4*)((const float*)xin + aBase);
               pLo = s4[0]; pHi = s4[1]; }
  } else {
    halfV = tid & 1; pxV = (tid >> 1) & (TX-1); rrV = tid >> 8;
    int iy = ty + e - 1 + rrV;
    aOk = (iy >= 0 && iy < TX);
    aBase = ((long)b*TX + (aOk?iy:0))*((long)(CIN/8)*TX*8) + (long)halfV*TX*8 + pxV*8;
    pIn = aOk ? *(const uint4*)((const unsigned short*)xin + aBase) : zero4();
  }

  if (MODE == 0) {
    if (tid < 64) {
      int rr = tid & 1, cc = ((tid>>1)&1) ? TX+1 : 0, ci = tid >> 2;
      sm.o.In[rr][cc][ci] = 0;
    }
  } else {
    if (tid < 8) {
      int rr = tid & 1, c = (tid>>1)&1, hf = (tid>>2)&1;
      *(uint4*)&sm.v.In[rr][c?TX+1:0][hf*8] = zero4();
    }
  }

  f32x4 acc[4][4] = {};
  for (int ch = 0; ch < CIN/16; ++ch) {
    __syncthreads();
    if (MODE == 0) {
      unsigned short vals[8];
      if (aOk) {
        float4 lo = pLo, hi = pHi;
        vals[0]=bfbits(lo.x); vals[1]=bfbits(lo.y); vals[2]=bfbits(lo.z); vals[3]=bfbits(lo.w);
        vals[4]=bfbits(hi.x); vals[5]=bfbits(hi.y); vals[6]=bfbits(hi.z); vals[7]=bfbits(hi.w);
      } else {
        #pragma unroll
        for (int j=0;j<8;j++) vals[j] = 0;
      }
      #pragma unroll
      for (int j=0;j<8;j++) {
        int jj = (j + liO) & 7;
        sm.o.In[srr][1 + liO*8 + jj][sci] = vals[jj];
      }
    } else {
      *(uint4*)&sm.v.In[rrV][pxV+1][halfV*8] = pIn;
    }
    #pragma unroll
    for (int j = 0; j < NWG; ++j) {
      int blk = wave*NWG + j;
      gload_lds16(wsrc + (long)ch*16384 + blk*512 + lane*8, Wb + blk*512);
    }
    __syncthreads();
    if (ch + 1 < CIN/16) {
      if (MODE == 0) {
        if (aOk) { const float4* s4 = (const float4*)((const float*)xin + aBase + (long)(ch+1)*16*TX*TX);
                   pLo = s4[0]; pHi = s4[1]; }
      } else {
        pIn = aOk ? *(const uint4*)((const unsigned short*)xin + aBase + (ch+1)*2*TX*8) : zero4();
      }
      __builtin_amdgcn_sched_barrier(0);
    }
    #pragma unroll
    for (int kk = 0; kk < 2; ++kk) {
      bf16x8 aF[4];
      const int tap = kk*2 + (kg >> 1), a = tap >> 1, bb = tap & 1;
      #pragma unroll
      for (int mf = 0; mf < 4; ++mf) {
        int tx = tx_base + mf*16 + col_l;
        if (MODE == 0) aF[mf] = *(const bf16x8*)&sm.o.In[1-a][tx + 1 + f - bb][(kg&1)*8];
        else           aF[mf] = *(const bf16x8*)&sm.v.In[1-a][tx + 1 + f - bb][(kg&1)*8];
      }
      const int slot = kk*4 + kg;
      __builtin_amdgcn_s_setprio(1);
      #pragma unroll
      for (int nf = 0; nf < 4; ++nf) {
        int co_l = nf*16 + col_l;
        bf16x8 bF = *(const bf16x8*)(Wb + (f*128 + wc*64 + co_l)*64 + (slot ^ (co_l & 7))*8);
        #pragma unroll
        for (int mf = 0; mf < 4; ++mf)
          acc[mf][nf] = MFMA16(aF[mf], bF, acc[mf][nf]);
      }
      __builtin_amdgcn_s_setprio(0);
    }
  }

  // epilogue
  __syncthreads();
  float bv[4];
  #pragma unroll
  for (int nf = 0; nf < 4; ++nf) bv[nf] = bias[wc*64 + nf*16 + col_l];
  const int oy = 2*ty + e;
  if constexpr (TX == 64) {
    #pragma unroll
    for (int mf = 0; mf < 4; ++mf)
    #pragma unroll
    for (int nf = 0; nf < 4; ++nf) {
      int co = wc*64 + nf*16 + col_l;
      #pragma unroll
      for (int r = 0; r < 4; ++r) {
        int tx = tx_base + mf*16 + kg*4 + r;
        float v = fmaxf(acc[mf][nf][r] + bv[nf], 0.f);
        int ox = 2*tx + f;
        sm.Out[ox][co ^ (((ox>>3)&7)<<3)] = bfbits(v);
      }
    }
    __syncthreads();
    #pragma unroll
    for (int j = 0; j < 8; ++j) {
      int i = tid + j*NTHR;
      int px = i & 127, chn = i >> 7;
      uint4 vv = *(const uint4*)&sm.Out[px][(chn*8) ^ (((px>>3)&7)<<3)];
      *(uint4*)(yI + ((((long)b*128 + oy)*16 + chn)*128 + px)*8) = vv;
    }
  } else {
    const int myp = wr & 1;   // wave-uniform: which 128-px half this wave produces
    #pragma unroll
    for (int p = 0; p < 2; ++p) {
      if (myp == p) {
        #pragma unroll
        for (int mf = 0; mf < 4; ++mf)
        #pragma unroll
        for (int nf = 0; nf < 4; ++nf) {
          int co = wc*64 + nf*16 + col_l;
          #pragma unroll
          for (int r = 0; r < 4; ++r) {
            int tx = tx_base + mf*16 + kg*4 + r;
            float v = fmaxf(acc[mf][nf][r] + bv[nf], 0.f);
            int ox = 2*tx + f;
            sm.Out[ox & 127][co ^ (((ox>>3)&7)<<3)] = bfbits(v);
          }
        }
      }
      __syncthreads();
      #pragma unroll
      for (int j = 0; j < 4; ++j) {
        int i = tid + j*NTHR;
        int px = i & 127, chn = i >> 7;
        uint4 vv = *(const uint4*)&sm.Out[px][(chn*8) ^ (((px>>3)&7)<<3)];
        int pxg = p*128 + px;
        *(uint4*)(yI + ((((long)b*256 + oy)*16 + chn)*256 + pxg)*8) = vv;
      }
      if (p == 0) __syncthreads();
    }
  }
}

// ---------------- deconv3: MFMA + sigmoid; post-barrier prefetch ----------
__global__ __launch_bounds__(256, 2) void deconv3_mfma(
    const unsigned short* __restrict__ g2I,
    const unsigned short* __restrict__ w2,
    const float* __restrict__ bias, float* __restrict__ y) {
  __shared__ __align__(16) unsigned short sA[3][260][8];
  __shared__ __align__(16) unsigned short sB[16*12*16*8];
  const int tid = threadIdx.x;
  const int oy = blockIdx.x, b = blockIdx.y;
  const int wave = tid >> 6, lane = tid & 63;
  const int col_l = lane & 15, kg = lane >> 4;
  const int pxb = wave*64;
  for (int i = tid; i < 3072; i += 256) {
    int co = i & 15, tap = (i>>4) % 12, ch = i/192;
    *(uint4*)&sB[((ch*12+tap)*16+co)*8] = *(const uint4*)(w2 + (long)co*1536 + ch*96 + tap*8);
  }
  if (tid < 12) {
    int dy = tid >> 2, c = tid & 3;
    *(uint4*)&sA[dy][(c<2)?c:(256+c)][0] = zero4();
  }
  long aBase[3]; int aLdsO[3]; bool aOk[3];
  #pragma unroll
  for (int u = 0; u < 3; ++u) {
    int idx = tid + u*256;
    int px = idx & 255, dy = idx >> 8;
    int iy = oy - 1 + dy;
    aOk[u] = (iy >= 0 && iy < 256);
    aBase[u] = ((long)(b*256 + (aOk[u]?iy:0)))*32768 + px*8;
    aLdsO[u] = (dy*260 + px + 2)*8;
  }
  uint4 pA[3];
  #pragma unroll
  for (int u=0;u<3;u++) pA[u] = aOk[u] ? *(const uint4*)(g2I + aBase[u]) : zero4();

  unsigned short* sAf = &sA[0][0][0];
  f32x4 acc[4] = {};
  for (int ch = 0; ch < 16; ++ch) {
    __syncthreads();
    #pragma unroll
    for (int u=0;u<3;u++) *(uint4*)(sAf + aLdsO[u]) = pA[u];
    __syncthreads();
    if (ch < 15) {
      #pragma unroll
      for (int u=0;u<3;u++)
        pA[u] = aOk[u] ? *(const uint4*)(g2I + aBase[u] + (ch+1)*2048) : zero4();
      __builtin_amdgcn_sched_barrier(0);
    }
    #pragma unroll
    for (int s = 0; s < 3; ++s) {
      bf16x8 bF = *(const bf16x8*)&sB[((ch*12 + s*4 + kg)*16 + col_l)*8];
      __builtin_amdgcn_s_setprio(1);
      #pragma unroll
      for (int mf = 0; mf < 4; ++mf) {
        int px = pxb + mf*16 + col_l;
        bf16x8 aF = *(const bf16x8*)&sA[2-s][px + 3 - kg][0];
        acc[mf] = MFMA16(aF, bF, acc[mf]);
      }
      __builtin_amdgcn_s_setprio(0);
    }
  }
  if (col_l < 3) {
    float bv = bias[col_l];
    #pragma unroll
    for (int mf = 0; mf < 4; ++mf) {
      int px = pxb + mf*16 + kg*4;
      float4 o;
      o.x = 1.f/(1.f + expf(-(acc[mf][0] + bv)));
      o.y = 1.f/(1.f + expf(-(acc[mf][1] + bv)));
      o.z = 1.f/(1.f + expf(-(acc[mf][2] + bv)));
      o.w = 1.f/(1.f + expf(-(acc[mf][3] + bv)));
      *(float4*)(y + ((long)(b*3 + col_l)*256 + oy)*256 + px) = o;
    }
  }
}

// ---------------- VQ via MFMA (unchanged) ----------------
__global__ __launch_bounds__(256, 2) void vq_mfma(
    const unsigned short* __restrict__ zeH, const unsigned short* __restrict__ zeM,
    const unsigned short* __restrict__ zeL,
    const float* __restrict__ emb, const float* __restrict__ esq,
    float* __restrict__ out_idx, float* __restrict__ zq) {
  __shared__ __align__(16) unsigned short sA[64*3*8*8];
  __shared__ __align__(16) unsigned short sB[128*3*8*8];
  __shared__ float snb[128];
  __shared__ int sidx[64];
  const int tid = threadIdx.x;
  const long n0 = (long)blockIdx.x*64;
  const int wave = tid >> 6, lane = tid & 63;
  const int col = lane & 15, kg = lane >> 4;

  #pragma unroll
  for (int j = 0; j < 6; ++j) {
    int idx = tid + j*256;
    int pl = idx >> 9, rem = idx & 511;
    int n = rem >> 3, slot = rem & 7;
    const unsigned short* src = (pl==0 ? zeH : (pl==1 ? zeM : zeL)) + (n0+n)*64 + slot*8;
    *(uint4*)&sA[((n*3 + pl)*8 + (slot ^ (n&7)))*8] = *(const uint4*)src;
  }

  const int codeT = tid >> 1, halfT = tid & 1;
  float4 pB[8];
  #pragma unroll
  for (int q = 0; q < 8; ++q)
    pB[q] = *(const float4*)(emb + (long)codeT*64 + halfT*32 + q*4);
  float pSn = (tid < 128) ? esq[tid] : 0.f;

  float best[4] = {3.4e38f,3.4e38f,3.4e38f,3.4e38f};
  int bidx[4] = {0,0,0,0};

  for (int ch = 0; ch < 4; ++ch) {
    __syncthreads();
    #pragma unroll
    for (int s4 = 0; s4 < 4; ++s4) {
      int slot = halfT*4 + s4;
      float4 lo = pB[s4*2], hi = pB[s4*2+1];
      unsigned short th[8], tm[8], tl[8];
      split3(lo.x, th[0], tm[0], tl[0]); split3(lo.y, th[1], tm[1], tl[1]);
      split3(lo.z, th[2], tm[2], tl[2]); split3(lo.w, th[3], tm[3], tl[3]);
      split3(hi.x, th[4], tm[4], tl[4]); split3(hi.y, th[5], tm[5], tl[5]);
      split3(hi.z, th[6], tm[6], tl[6]); split3(hi.w, th[7], tm[7], tl[7]);
      int base = ((codeT*3)*8 + (slot ^ (codeT&7)))*8;
      *(uint4*)&sB[base]       = *(uint4*)th;
      *(uint4*)&sB[base + 64]  = *(uint4*)tm;
      *(uint4*)&sB[base + 128] = *(uint4*)tl;
    }
    if (tid < 128) snb[tid] = pSn;
    if (ch < 3) {
      #pragma unroll
      for (int q = 0; q < 8; ++q)
        pB[q] = *(const float4*)(emb + ((long)(ch+1)*128 + codeT)*64 + halfT*32 + q*4);
      if (tid < 128) pSn = esq[(ch+1)*128 + tid];
    }
    __syncthreads();

    f32x4 acc[8] = {};
    #pragma unroll
    for (int kk = 0; kk < 2; ++kk) {
      const int nloc = wave*16 + col;
      const int slot = kk*4 + kg;
      bf16x8 aF[3];
      #pragma unroll
      for (int pl = 0; pl < 3; ++pl)
        aF[pl] = *(const bf16x8*)&sA[((nloc*3 + pl)*8 + (slot ^ (nloc&7)))*8];
      __builtin_amdgcn_s_setprio(1);
      #pragma unroll
      for (int cf = 0; cf < 8; ++cf) {
        int cl = cf*16 + col;
        int bb = ((cl*3)*8 + (slot ^ (cl&7)))*8;
        bf16x8 b0 = *(const bf16x8*)&sB[bb];
        bf16x8 b1 = *(const bf16x8*)&sB[bb + 64];
        bf16x8 b2 = *(const bf16x8*)&sB[bb + 128];
        f32x4 a = acc[cf];
        a = MFMA16(aF[0], b0, a);
        a = MFMA16(aF[0], b1, a);
        a = MFMA16(aF[1], b0, a);
        a = MFMA16(aF[0], b2, a);
        a = MFMA16(aF[2], b0, a);
        a = MFMA16(aF[1], b1, a);
        acc[cf] = a;
      }
      __builtin_amdgcn_s_setprio(0);
    }
    #pragma unroll
    for (int cf = 0; cf < 8; ++cf) {
      float sv = snb[cf*16 + col];
      int code = ch*128 + cf*16 + col;
      #pragma unroll
      for (int j = 0; j < 4; ++j) {
        float s = sv - 2.f*acc[cf][j];
        if (s < best[j]) { best[j] = s; bidx[j] = code; }
      }
    }
  }

  #pragma unroll
  for (int j = 0; j < 4; ++j) {
    float b = best[j]; int ii = bidx[j];
    #pragma unroll
    for (int off = 1; off < 16; off <<= 1) {
      float ob = __shfl_xor(b, off);
      int oi = __shfl_xor(ii, off);
      if (ob < b || (ob == b && oi < ii)) { b = ob; ii = oi; }
    }
    if (col == 0) sidx[wave*16 + kg*4 + j] = ii;
  }
  __syncthreads();
  if (tid < 64) out_idx[n0 + tid] = (float)sidx[tid];
  #pragma unroll
  for (int j = 0; j < 4; ++j) {
    int t = tid + j*256;
    int row = t >> 4, q = t & 15;
    float4 v = *(const float4*)(emb + (long)sidx[row]*64 + q*4);
    *(float4*)(zq + (n0 + row)*64 + q*4) = v;
  }
}

// ---------------- launch ----------------
extern "C" void kernel_launch(void* const* d_in, const int* in_sizes, int n_in,
                              void* d_out, int out_size, void* d_ws, size_t ws_size,
                              hipStream_t stream) {
  const float* x   = (const float*)d_in[0];
  const float* c1w = (const float*)d_in[1];  const float* c1b = (const float*)d_in[2];
  const float* c2w = (const float*)d_in[3];  const float* c2b = (const float*)d_in[4];
  const float* c3w = (const float*)d_in[5];  const float* c3b = (const float*)d_in[6];
  const float* emb = (const float*)d_in[7];
  const float* d1w = (const float*)d_in[8];  const float* d1b = (const float*)d_in[9];
  const float* d2w = (const float*)d_in[10]; const float* d2b = (const float*)d_in[11];
  const float* d3w = (const float*)d_in[12]; const float* d3b = (const float*)d_in[13];
  float* out = (float*)d_out;

  float* xrec = out;
  float* oidx = out + 3145728;
  float* zq   = out + 3211264;

  const long XB  = 196608;   // 3*256*256
  const long ZEB = 262144;   // ze elems per batch
  const long PS1 = 8388608;  // per-plane h1 (interleaved) in shorts
  const long H2B = 1572864;  // per-batch h2I stride in shorts

  const size_t NEEDED = 112273408ULL;  // known: ws_size >= 120,395,264
  if (ws_size < NEEDED) return;
  char* wsb = (char*)d_ws;
  unsigned short* h1grp = (unsigned short*)wsb;              // interleaved, 50.3MB
  unsigned short* g2grp = (unsigned short*)wsb;              // interleaved, 64MB
  unsigned short* h2I   = (unsigned short*)(wsb + 67108864); // interleaved 8-batch, 25.17MB
  unsigned short* g1grp = (unsigned short*)(wsb + 67108864); // interleaved, 16MB
  unsigned short* zeH = (unsigned short*)(wsb + 92274688);
  unsigned short* zeM = (unsigned short*)(wsb + 100663296);
  unsigned short* zeL = (unsigned short*)out;                // xrec region: dead until deconv3
  char* W = wsb + 109051904;
  float* w2c1          = (float*)(W);
  unsigned short* w2c2 = (unsigned short*)(W + 24576);
  unsigned short* w2c3 = (unsigned short*)(W + 1597440);
  unsigned short* w2d1 = (unsigned short*)(W + 2383872);
  unsigned short* w2d2 = (unsigned short*)(W + 2646016);
  unsigned short* w2d3 = (unsigned short*)(W + 3170304);
  float* esq           = (float*)(W + 3219456);

  wprep_all<<<3066, 256, 0, stream>>>(c1w, w2c1, c2w, w2c2, c3w, w2c3,
                                      d1w, w2d1, d2w, w2d2, d3w, w2d3, emb, esq);

  // encoder
  for (int g = 0; g < 4; ++g) {
    conv1_split<<<dim3(16,16,8), 256, 0, stream>>>(
        x + (long)g*4*XB, w2c1, c1b, h1grp, PS1);
    conv2_mfma<<<dim3(64,2,4), 256, 0, stream>>>(
        h1grp, PS1, w2c2, c2b, h2I + (long)(g&1)*4*H2B);
    if (g & 1) {
      long zo = (long)(g>>1)*8*ZEB;
      conv3_mfma<<<dim3(64,1,8), 256, 0, stream>>>(
          h2I, w2c3, c3b, zeH + zo, zeM + zo, zeL + zo);
    }
  }
  vq_mfma<<<1024, 256, 0, stream>>>(zeH, zeM, zeL, emb, esq, oidx, zq);

  // decoder
  for (int g = 0; g < 4; ++g) {
    deconv_mfma<64, 64, 0 ><<<dim3(64, 2, 4), 256, 0, stream>>>(
        (const void*)(zq + (long)g*4*ZEB), w2d1, d1b, g1grp);
    deconv_mfma<128,128,1 ><<<dim3(128,2,4), 512, 0, stream>>>(
        (const void*)g1grp, w2d2, d2b, g2grp);
    deconv3_mfma<<<dim3(256,4), 256, 0, stream>>>(
        g2grp, w2d3, d3b, xrec + (long)g*4*XB);
  }
}

// Round 15
// 672.425 us; speedup vs baseline: 3.3959x; 1.1072x over previous
//
#include <hip/hip_runtime.h>
#include <hip/hip_bf16.h>

#define DEV __device__ __forceinline__

typedef __attribute__((ext_vector_type(8))) short bf16x8;
typedef __attribute__((ext_vector_type(4))) float f32x4;
typedef __attribute__((ext_vector_type(4))) unsigned short u16x4;

#define MFMA16(a,b,c) __builtin_amdgcn_mfma_f32_16x16x32_bf16(a,b,c,0,0,0)

DEV unsigned short bfbits(float v){ __hip_bfloat16 h = __float2bfloat16(v); return *(unsigned short*)&h; }
DEV float bf2f(unsigned short u){ __hip_bfloat16 h = *(__hip_bfloat16*)&u; return __bfloat162float(h); }
DEV void split3(float v, unsigned short& h, unsigned short& m, unsigned short& l) {
  h = bfbits(v);        float r  = v - bf2f(h);
  m = bfbits(r);        float r2 = r - bf2f(m);
  l = bfbits(r2);
}
DEV uint4 zero4(){ uint4 z; z.x=0; z.y=0; z.z=0; z.w=0; return z; }
DEV void gload_lds16(const void* g, void* l) {
  __builtin_amdgcn_global_load_lds(
      (const __attribute__((address_space(1))) void*)g,
      (__attribute__((address_space(3))) void*)l, 16, 0, 0);
}

// ---------------- fused weight prep (one dispatch, 3066 blocks) ----------------
DEV void prep_deconv_img(int i, int CI, const float* __restrict__ w, unsigned short* __restrict__ w2) {
  const int nch = CI/16;
  int cil = i & 7, s = (i >> 3) & 7, co = (i >> 6) & 127, f = (i >> 13) & 1;
  int rest = i >> 14;
  int ch = rest % nch, e = rest / nch;
  int k = ch*64 + s*8 + cil;
  int ci = (k & 15) | ((k >> 6) << 4);
  int tap = (k >> 4) & 3, a = tap >> 1, b = tap & 1;
  float v = w[ (((long)ci*128 + co)*4 + (2*a+1-e))*4 + (2*b+1-f) ];
  w2[(long)(e*nch + ch)*16384 + ((long)(f*128 + co))*64 + ((s ^ (co&7))*8) + cil] = bfbits(v);
}
__global__ __launch_bounds__(256) void wprep_all(
    const float* __restrict__ c1w, float* __restrict__ w2c1,
    const float* __restrict__ c2w, unsigned short* __restrict__ w2c2,
    const float* __restrict__ c3w, unsigned short* __restrict__ w2c3,
    const float* __restrict__ d1w, unsigned short* __restrict__ w2d1,
    const float* __restrict__ d2w, unsigned short* __restrict__ w2d2,
    const float* __restrict__ d3w, unsigned short* __restrict__ w2d3,
    const float* __restrict__ emb, float* __restrict__ esq) {
  const int bx = blockIdx.x, t = threadIdx.x;
  if (bx < 24) {                         // conv1 transpose: 6144
    int i = bx*256 + t;
    if (i < 6144) {
      int tap = i & 15, ci = (i>>4) % 3, co = i / 48;
      w2c1[((long)ci*16 + tap)*128 + co] = c1w[i];
    }
  } else if (bx < 1048) {                // conv2 prep -> LDS-image layout
    int i = (bx-24)*256 + t;             // 0..262143
    int cil = i & 7, s = (i>>3) & 15, co = (i>>7) & 63;
    int ch = (i>>13) & 15, cog = i >> 17;
    int co_g = cog*64 + co, ci = ch*8 + cil, ky = s >> 2, kx = s & 3;
    float v = c2w[(((long)co_g*128 + ci)*4 + ky)*4 + kx];
    unsigned short h,m,l; split3(v,h,m,l);
    long base = (long)(cog*16 + ch)*24576 + ((long)co*16 + (s ^ (co&15)))*8 + cil;
    w2c2[base] = h; w2c2[base + 8192] = m; w2c2[base + 16384] = l;
  } else if (bx < 1432) {                // conv3 prep -> LDS-image layout: 98304
    int i = (bx-1048)*256 + t;
    int k = i % 1536, co = i / 1536;
    int ch = k / 96, rem = k % 96;
    int tap = rem >> 3, cil = rem & 7;
    int ci = ch*8 + cil, ky = tap >> 2, kx = tap & 3;
    float v = (kx < 3) ? c3w[(((long)co*128 + ci)*3 + ky)*3 + kx] : 0.f;
    unsigned short h,m,l; split3(v,h,m,l);
    long base = (long)ch*24576 + ((long)co*16 + (tap ^ (co&15)))*8 + cil;
    w2c3[base] = h; w2c3[base + 8192] = m; w2c3[base + 16384] = l;
  } else if (bx < 1944) {                // deconv1 image: 131072 (CI=64)
    prep_deconv_img((bx-1432)*256 + t, 64, d1w, w2d1);
  } else if (bx < 2968) {                // deconv2 image: 262144 (CI=128)
    prep_deconv_img((bx-1944)*256 + t, 128, d2w, w2d2);
  } else if (bx < 3064) {                // deconv3: 24576
    int i = (bx-2968)*256 + t;
    if (i < 24576) {
      int k = i % 1536, co = i / 1536;
      int ch = k / 96, rem = k % 96;
      int tap = rem >> 3, cil = rem & 7;
      int ci = ch*8 + cil, ky = tap >> 2, kx = tap & 3;
      float v = (co < 3 && kx < 3) ? d3w[(((long)ci*3 + co)*3 + ky)*3 + kx] : 0.f;
      w2d3[i] = bfbits(v);
    }
  } else {                               // esq: 512 codes
    int code = (bx-3064)*256 + t;
    if (code < 512) {
      const float4* ev = (const float4*)(emb + (long)code*64);
      float s = 0.f;
      #pragma unroll
      for (int q=0;q<16;q++){ float4 e4 = ev[q];
        s += e4.x*e4.x + e4.y*e4.y + e4.z*e4.z + e4.w*e4.w; }
      esq[code] = s;
    }
  }
}

// ---------------- conv1: f32 direct, out 3 bf16 planes INTERLEAVED ----------------
__global__ __launch_bounds__(256) void conv1_split(
    const float* __restrict__ x, const float* __restrict__ w2,
    const float* __restrict__ bias, unsigned short* __restrict__ h1, long PS1) {
  __shared__ __align__(16) float sIn[3][18][20];
  __shared__ __align__(16) float sW[3*16*64];
  const int tid = threadIdx.x;
  const int b = blockIdx.z >> 1, cog = blockIdx.z & 1;
  const int co0 = cog*64;
  const int oy0 = blockIdx.y*8, ox0 = blockIdx.x*8;
  const int cg2 = tid >> 5;
  const int pg2 = tid & 31;
  const int r = pg2 >> 2, pxp = (pg2 & 3)*2;
  float acc[8][2];
  #pragma unroll
  for (int c=0;c<8;c++){ float bv = bias[co0 + cg2*8 + c];
    acc[c][0]=bv; acc[c][1]=bv; }
  const float* xb = x + (long)b*3*256*256;
  const int iy0 = 2*oy0 - 1, ix0 = 2*ox0 - 1;
  for (int t=tid; t<3*18*18; t+=256) {
    int xx = t%18, yy=(t/18)%18, ci=t/324;
    int gy = iy0+yy, gx = ix0+xx;
    float v = 0.f;
    if (gy>=0 && gy<256 && gx>=0 && gx<256) v = xb[((long)ci*256+gy)*256+gx];
    sIn[ci][yy][xx] = v;
  }
  for (int t=tid; t<3*16*64; t+=256) {
    sW[t] = w2[(long)(t>>6)*128 + co0 + (t&63)];
  }
  __syncthreads();
  for (int ci=0; ci<3; ci++) {
    #pragma unroll
    for (int ky=0;ky<4;ky++)
    #pragma unroll
    for (int kx=0;kx<4;kx++) {
      const float* wp = &sW[(ci*16 + ky*4+kx)*64 + cg2*8];
      float4 w0 = *(const float4*)wp;
      float4 w1 = *(const float4*)(wp+4);
      const int yy = 2*r + ky;
      #pragma unroll
      for (int p=0;p<2;p++) {
        float iv = sIn[ci][yy][2*(pxp+p)+kx];
        acc[0][p] += w0.x*iv; acc[1][p] += w0.y*iv;
        acc[2][p] += w0.z*iv; acc[3][p] += w0.w*iv;
        acc[4][p] += w1.x*iv; acc[5][p] += w1.y*iv;
        acc[6][p] += w1.z*iv; acc[7][p] += w1.w*iv;
      }
    }
  }
  const int chg = cog*8 + cg2;
  #pragma unroll
  for (int p=0;p<2;p++) {
    unsigned short th[8], tm[8], tl[8];
    #pragma unroll
    for (int c=0;c<8;c++) {
      float v = fmaxf(acc[c][p], 0.f);
      split3(v, th[c], tm[c], tl[c]);
    }
    long base = (((long)(b*128 + oy0+r)*16 + chg)*128 + ox0+pxp+p)*8;
    *(uint4*)(h1 + base)          = *(uint4*)th;
    *(uint4*)(h1 + PS1 + base)    = *(uint4*)tm;
    *(uint4*)(h1 + 2*PS1 + base)  = *(uint4*)tl;
  }
}

// ---------------- conv2: MFMA 6-term split; post-barrier A prefetch ----------
__global__ __launch_bounds__(256, 2) void conv2_mfma(
    const unsigned short* __restrict__ h1, long PS1,
    const unsigned short* __restrict__ w2,   // LDS-image: [cog][ch][24576 shorts]
    const float* __restrict__ bias,
    unsigned short* __restrict__ h2I) {      // [b][row64][pl3][ch16][px64][8]
  __shared__ __align__(16) unsigned short sA[3][4][130][8];
  __shared__ __align__(16) unsigned short sB[24576];
  const int tid = threadIdx.x;
  const int oy = blockIdx.x, cog = blockIdx.y, b = blockIdx.z;
  const int wave = tid >> 6, lane = tid & 63;
  const int wr = wave >> 1, wc = wave & 1;
  const int col_l = lane & 15, kg = lane >> 4;
  const int iy0 = 2*oy - 1;
  f32x4 acc[2][2] = {};
  unsigned short* sAf = &sA[0][0][0][0];
  const unsigned short* bsrc = w2 + (long)cog*16*24576;

  int aOff[6], aLdsO[6]; bool aOk[6];
  #pragma unroll
  for (int j = 0; j < 6; ++j) {
    int idx = tid + j*256;
    int px = idx & 127, rr = (idx >> 7) & 3, pl = idx >> 9;
    int iy = iy0 + rr;
    aOk[j] = (iy >= 0 && iy < 128);
    aOff[j] = (int)(pl*PS1 + (long)(b*128 + (aOk[j]?iy:0))*16384 + px*8);
    aLdsO[j] = ((pl*4 + rr)*130 + px + 1)*8;
  }
  uint4 pA[6];
  #pragma unroll
  for (int j=0;j<6;j++)  pA[j] = aOk[j] ? *(const uint4*)(h1 + aOff[j]) : zero4();

  if (tid < 24) {
    int pl = tid>>3, rr=(tid>>1)&3, c=tid&1;
    *(uint4*)&sA[pl][rr][c?129:0][0] = zero4();
  }

  for (int ch = 0; ch < 16; ++ch) {
    __syncthreads();
    #pragma unroll
    for (int j=0;j<6;j++)  *(uint4*)(sAf + aLdsO[j]) = pA[j];
    #pragma unroll
    for (int j = 0; j < 12; ++j) {
      int blk = wave*12 + j;
      gload_lds16(bsrc + (long)ch*24576 + blk*512 + lane*8, &sB[blk*512]);
    }
    __syncthreads();
    if (ch < 15) {
      #pragma unroll
      for (int j=0;j<6;j++)  pA[j] = aOk[j] ? *(const uint4*)(h1 + aOff[j] + (ch+1)*1024) : zero4();
      __builtin_amdgcn_sched_barrier(0);
    }
    #pragma unroll
    for (int s = 0; s < 4; ++s) {        // s = ky
      bf16x8 aF[2][3]; bf16x8 bF[2][3];
      const int tap = s*4 + kg;
      #pragma unroll
      for (int mf = 0; mf < 2; ++mf) {
        int ox = wr*32 + mf*16 + col_l;
        #pragma unroll
        for (int pl = 0; pl < 3; ++pl)
          aF[mf][pl] = *(const bf16x8*)&sA[pl][s][2*ox + kg][0];
      }
      #pragma unroll
      for (int nf = 0; nf < 2; ++nf) {
        int co = wc*32 + nf*16 + col_l;
        int ba = (co*16 + (tap ^ (co&15)))*8;
        bF[nf][0] = *(const bf16x8*)&sB[ba];
        bF[nf][1] = *(const bf16x8*)&sB[ba + 8192];
        bF[nf][2] = *(const bf16x8*)&sB[ba + 16384];
      }
      __builtin_amdgcn_s_setprio(1);
      #pragma unroll
      for (int mf = 0; mf < 2; ++mf)
      #pragma unroll
      for (int nf = 0; nf < 2; ++nf) {
        f32x4 a = acc[mf][nf];
        a = MFMA16(aF[mf][0], bF[nf][0], a);
        a = MFMA16(aF[mf][0], bF[nf][1], a);
        a = MFMA16(aF[mf][1], bF[nf][0], a);
        a = MFMA16(aF[mf][0], bF[nf][2], a);
        a = MFMA16(aF[mf][2], bF[nf][0], a);
        a = MFMA16(aF[mf][1], bF[nf][1], a);
        acc[mf][nf] = a;
      }
      __builtin_amdgcn_s_setprio(0);
    }
  }
  // epilogue: acc -> sB[pl][co64][72pad] -> interleaved h2I
  __syncthreads();
  #pragma unroll
  for (int nf = 0; nf < 2; ++nf) {
    int co = wc*32 + nf*16 + col_l;
    float bv = bias[cog*64 + co];
    #pragma unroll
    for (int mf = 0; mf < 2; ++mf) {
      int px0 = wr*32 + mf*16 + kg*4;
      u16x4 oh, om, ol;
      #pragma unroll
      for (int r = 0; r < 4; ++r) {
        float v = fmaxf(acc[mf][nf][r] + bv, 0.f);
        unsigned short h,m,l; split3(v,h,m,l);
        oh[r]=h; om[r]=m; ol[r]=l;
      }
      *(u16x4*)&sB[(0*64 + co)*72 + px0] = oh;
      *(u16x4*)&sB[(1*64 + co)*72 + px0] = om;
      *(u16x4*)&sB[(2*64 + co)*72 + px0] = ol;
    }
  }
  __syncthreads();
  #pragma unroll
  for (int j = 0; j < 6; ++j) {
    int idx = tid + j*256;
    int pl = idx >> 9, ch = (idx >> 6) & 7, px = idx & 63;
    unsigned short tmp[8];
    #pragma unroll
    for (int c = 0; c < 8; ++c) tmp[c] = sB[(pl*64 + ch*8 + c)*72 + px];
    *(uint4*)(h2I + ((((long)(b*64 + oy)*3 + pl)*16 + cog*8 + ch)*64 + px)*8) = *(uint4*)tmp;
  }
}

// ---------------- conv3: MFMA 6-term split; A+B via global_load_lds ----------------
__global__ __launch_bounds__(256, 2) void conv3_mfma(
    const unsigned short* __restrict__ h2I,  // [b][row64][pl3][ch16][px64][8]
    const unsigned short* __restrict__ w2,   // LDS-image: [ch][24576 shorts]
    const float* __restrict__ bias,
    unsigned short* __restrict__ zeH, unsigned short* __restrict__ zeM,
    unsigned short* __restrict__ zeL) {
  __shared__ __align__(16) unsigned short sA3[3][3][68][8];
  __shared__ __align__(16) unsigned short sB[24576];
  const int tid = threadIdx.x;
  const int oy = blockIdx.x, b = blockIdx.z;
  const int wave = tid >> 6, lane = tid & 63;
  const int wr = wave >> 1, wc = wave & 1;
  const int col_l = lane & 15, kg = lane >> 4;
  f32x4 acc[2][2] = {};
  if (tid < 27) {
    int row = tid/3, c = tid%3;
    int pl = row/3, rr = row%3;
    *(uint4*)&sA3[pl][rr][(c==0)?0:(64+c)][0] = zero4();
  }
  if (oy == 0 && tid < 192) {
    int pl = tid >> 6, px = tid & 63;
    *(uint4*)&sA3[pl][0][px+1][0] = zero4();
  }
  if (oy == 63 && tid < 192) {
    int pl = tid >> 6, px = tid & 63;
    *(uint4*)&sA3[pl][2][px+1][0] = zero4();
  }

  for (int ch = 0; ch < 16; ++ch) {
    __syncthreads();
    #pragma unroll
    for (int j = 0; j < 3; ++j) {
      int row = wave*3 + j;
      if (row < 9) {
        int pl = row/3, rr = row%3;
        int iy = oy + rr - 1;
        if (iy >= 0 && iy < 64)
          gload_lds16(h2I + ((((long)(b*64 + iy)*3 + pl)*16 + ch)*64)*8 + lane*8,
                      &sA3[pl][rr][1][0]);
      }
    }
    #pragma unroll
    for (int j = 0; j < 12; ++j) {
      int blk = wave*12 + j;
      gload_lds16(w2 + (long)ch*24576 + blk*512 + lane*8, &sB[blk*512]);
    }
    __syncthreads();
    #pragma unroll
    for (int s = 0; s < 3; ++s) {
      bf16x8 aF[2][3]; bf16x8 bF[2][3];
      const int tap = s*4 + kg;
      #pragma unroll
      for (int mf = 0; mf < 2; ++mf) {
        int ox = wr*32 + mf*16 + col_l;
        #pragma unroll
        for (int pl = 0; pl < 3; ++pl)
          aF[mf][pl] = *(const bf16x8*)&sA3[pl][s][ox + kg][0];
      }
      #pragma unroll
      for (int nf = 0; nf < 2; ++nf) {
        int co = wc*32 + nf*16 + col_l;
        int ba = (co*16 + (tap ^ (co&15)))*8;
        bF[nf][0] = *(const bf16x8*)&sB[ba];
        bF[nf][1] = *(const bf16x8*)&sB[ba + 8192];
        bF[nf][2] = *(const bf16x8*)&sB[ba + 16384];
      }
      __builtin_amdgcn_s_setprio(1);
      #pragma unroll
      for (int mf = 0; mf < 2; ++mf)
      #pragma unroll
      for (int nf = 0; nf < 2; ++nf) {
        f32x4 a = acc[mf][nf];
        a = MFMA16(aF[mf][0], bF[nf][0], a);
        a = MFMA16(aF[mf][0], bF[nf][1], a);
        a = MFMA16(aF[mf][1], bF[nf][0], a);
        a = MFMA16(aF[mf][0], bF[nf][2], a);
        a = MFMA16(aF[mf][2], bF[nf][0], a);
        a = MFMA16(aF[mf][1], bF[nf][1], a);
        acc[mf][nf] = a;
      }
      __builtin_amdgcn_s_setprio(0);
    }
  }
  __syncthreads();
  #pragma unroll
  for (int nf = 0; nf < 2; ++nf) {
    int co = wc*32 + nf*16 + col_l;
    float bv = bias[co];
    #pragma unroll
    for (int mf = 0; mf < 2; ++mf) {
      int px0 = wr*32 + mf*16 + kg*4;
      u16x4 oh, om, ol;
      #pragma unroll
      for (int r = 0; r < 4; ++r) {
        float v = acc[mf][nf][r] + bv;
        unsigned short h,m,l; split3(v,h,m,l);
        oh[r]=h; om[r]=m; ol[r]=l;
      }
      *(u16x4*)&sB[(0*64 + co)*72 + px0] = oh;
      *(u16x4*)&sB[(1*64 + co)*72 + px0] = om;
      *(u16x4*)&sB[(2*64 + co)*72 + px0] = ol;
    }
  }
  __syncthreads();
  #pragma unroll
  for (int j = 0; j < 6; ++j) {
    int idx = tid + j*256;
    int pl = idx >> 9, co_l = (idx >> 3) & 63, q = idx & 7;
    uint4 v = *(const uint4*)&sB[(pl*64 + co_l)*72 + q*8];
    unsigned short* dst = (pl==0) ? zeH : ((pl==1) ? zeM : zeL);
    *(uint4*)(dst + ((long)(b*64 + co_l)*64 + oy)*64 + q*8) = v;
  }
}

// ---------------- MFMA ConvTranspose2d s2k4p1; 2-pass epilogue; post-barrier prefetch -----
template<int TX, int MODE>
struct SmemD {
  union {
    struct { __align__(16) unsigned short In[2][TX+2][24];
             __align__(16) unsigned short W[2*128*64]; } o;
    struct { __align__(16) unsigned short In[2][TX+2][16];
             __align__(16) unsigned short W[2*128*64]; } v;
    __align__(16) unsigned short Out[128][136];
  };
};

template<int CIN, int TX, int MODE>
__global__ __launch_bounds__(TX*4, (TX==64)?3:4) void deconv_mfma(
    const void* __restrict__ xin, const unsigned short* __restrict__ w2,
    const float* __restrict__ bias, unsigned short* __restrict__ yI) {
  constexpr int NTHR = TX*4;
  constexpr int NWAVE = NTHR/64;
  constexpr int NWG  = 32/NWAVE;
  __shared__ SmemD<TX,MODE> sm;
  unsigned short* Wb = MODE ? &sm.v.W[0] : &sm.o.W[0];

  const int tid = threadIdx.x;
  const int ty = blockIdx.x, e = blockIdx.y, b = blockIdx.z;
  const int wave = tid >> 6, lane = tid & 63;
  const int wc = wave & 1, wr = wave >> 1;
  const int f = (wr*64) / TX;
  const int tx_base = (wr*64) & (TX-1);
  const int col_l = lane & 15, kg = lane >> 4;
  const unsigned short* wsrc = w2 + (long)e*(CIN/16)*16384;

  constexpr int TPR = NTHR/32;
  const int rowid = tid / TPR, liO = tid % TPR;
  const int sci = rowid >> 1, srr = rowid & 1;
  float4 pLo, pHi; uint4 pIn;
  long aBase = 0; bool aOk = false;
  int pxV = 0, halfV = 0, rrV = 0;
  if (MODE == 0) {
    int iy = ty + e - 1 + srr;
    aOk = (iy >= 0 && iy < TX);
    aBase = ((long)b*CIN + sci)*TX*TX + (long)(aOk?iy:0)*TX + liO*8;
    if (aOk) { const float4* s4 = (const float4*)((const float*)xin + aBase);
               pLo = s4[0]; pHi = s4[1]; }
  } else {
    halfV = tid & 1; pxV = (tid >> 1) & (TX-1); rrV = tid >> 8;
    int iy = ty + e - 1 + rrV;
    aOk = (iy >= 0 && iy < TX);
    aBase = ((long)b*TX + (aOk?iy:0))*((long)(CIN/8)*TX*8) + (long)halfV*TX*8 + pxV*8;
    pIn = aOk ? *(const uint4*)((const unsigned short*)xin + aBase) : zero4();
  }

  if (MODE == 0) {
    if (tid < 64) {
      int rr = tid & 1, cc = ((tid>>1)&1) ? TX+1 : 0, ci = tid >> 2;
      sm.o.In[rr][cc][ci] = 0;
    }
  } else {
    if (tid < 8) {
      int rr = tid & 1, c = (tid>>1)&1, hf = (tid>>2)&1;
      *(uint4*)&sm.v.In[rr][c?TX+1:0][hf*8] = zero4();
    }
  }

  f32x4 acc[4][4] = {};
  for (int ch = 0; ch < CIN/16; ++ch) {
    __syncthreads();
    if (MODE == 0) {
      unsigned short vals[8];
      if (aOk) {
        float4 lo = pLo, hi = pHi;
        vals[0]=bfbits(lo.x); vals[1]=bfbits(lo.y); vals[2]=bfbits(lo.z); vals[3]=bfbits(lo.w);
        vals[4]=bfbits(hi.x); vals[5]=bfbits(hi.y); vals[6]=bfbits(hi.z); vals[7]=bfbits(hi.w);
      } else {
        #pragma unroll
        for (int j=0;j<8;j++) vals[j] = 0;
      }
      #pragma unroll
      for (int j=0;j<8;j++) {
        int jj = (j + liO) & 7;
        sm.o.In[srr][1 + liO*8 + jj][sci] = vals[jj];
      }
    } else {
      *(uint4*)&sm.v.In[rrV][pxV+1][halfV*8] = pIn;
    }
    #pragma unroll
    for (int j = 0; j < NWG; ++j) {
      int blk = wave*NWG + j;
      gload_lds16(wsrc + (long)ch*16384 + blk*512 + lane*8, Wb + blk*512);
    }
    __syncthreads();
    if (ch + 1 < CIN/16) {
      if (MODE == 0) {
        if (aOk) { const float4* s4 = (const float4*)((const float*)xin + aBase + (long)(ch+1)*16*TX*TX);
                   pLo = s4[0]; pHi = s4[1]; }
      } else {
        pIn = aOk ? *(const uint4*)((const unsigned short*)xin + aBase + (ch+1)*2*TX*8) : zero4();
      }
      __builtin_amdgcn_sched_barrier(0);
    }
    #pragma unroll
    for (int kk = 0; kk < 2; ++kk) {
      bf16x8 aF[4];
      const int tap = kk*2 + (kg >> 1), a = tap >> 1, bb = tap & 1;
      #pragma unroll
      for (int mf = 0; mf < 4; ++mf) {
        int tx = tx_base + mf*16 + col_l;
        if (MODE == 0) aF[mf] = *(const bf16x8*)&sm.o.In[1-a][tx + 1 + f - bb][(kg&1)*8];
        else           aF[mf] = *(const bf16x8*)&sm.v.In[1-a][tx + 1 + f - bb][(kg&1)*8];
      }
      const int slot = kk*4 + kg;
      __builtin_amdgcn_s_setprio(1);
      #pragma unroll
      for (int nf = 0; nf < 4; ++nf) {
        int co_l = nf*16 + col_l;
        bf16x8 bF = *(const bf16x8*)(Wb + (f*128 + wc*64 + co_l)*64 + (slot ^ (co_l & 7))*8);
        #pragma unroll
        for (int mf = 0; mf < 4; ++mf)
          acc[mf][nf] = MFMA16(aF[mf], bF, acc[mf][nf]);
      }
      __builtin_amdgcn_s_setprio(0);
    }
  }

  // epilogue
  __syncthreads();
  float bv[4];
  #pragma unroll
  for (int nf = 0; nf < 4; ++nf) bv[nf] = bias[wc*64 + nf*16 + col_l];
  const int oy = 2*ty + e;
  if constexpr (TX == 64) {
    #pragma unroll
    for (int mf = 0; mf < 4; ++mf)
    #pragma unroll
    for (int nf = 0; nf < 4; ++nf) {
      int co = wc*64 + nf*16 + col_l;
      #pragma unroll
      for (int r = 0; r < 4; ++r) {
        int tx = tx_base + mf*16 + kg*4 + r;
        float v = fmaxf(acc[mf][nf][r] + bv[nf], 0.f);
        int ox = 2*tx + f;
        sm.Out[ox][co ^ (((ox>>3)&7)<<3)] = bfbits(v);
      }
    }
    __syncthreads();
    #pragma unroll
    for (int j = 0; j < 8; ++j) {
      int i = tid + j*NTHR;
      int px = i & 127, chn = i >> 7;
      uint4 vv = *(const uint4*)&sm.Out[px][(chn*8) ^ (((px>>3)&7)<<3)];
      *(uint4*)(yI + ((((long)b*128 + oy)*16 + chn)*128 + px)*8) = vv;
    }
  } else {
    const int myp = wr & 1;
    #pragma unroll
    for (int p = 0; p < 2; ++p) {
      if (myp == p) {
        #pragma unroll
        for (int mf = 0; mf < 4; ++mf)
        #pragma unroll
        for (int nf = 0; nf < 4; ++nf) {
          int co = wc*64 + nf*16 + col_l;
          #pragma unroll
          for (int r = 0; r < 4; ++r) {
            int tx = tx_base + mf*16 + kg*4 + r;
            float v = fmaxf(acc[mf][nf][r] + bv[nf], 0.f);
            int ox = 2*tx + f;
            sm.Out[ox & 127][co ^ (((ox>>3)&7)<<3)] = bfbits(v);
          }
        }
      }
      __syncthreads();
      #pragma unroll
      for (int j = 0; j < 4; ++j) {
        int i = tid + j*NTHR;
        int px = i & 127, chn = i >> 7;
        uint4 vv = *(const uint4*)&sm.Out[px][(chn*8) ^ (((px>>3)&7)<<3)];
        int pxg = p*128 + px;
        *(uint4*)(yI + ((((long)b*256 + oy)*16 + chn)*256 + pxg)*8) = vv;
      }
      if (p == 0) __syncthreads();
    }
  }
}

// ---------------- deconv3: MFMA + sigmoid; 2 output rows per block ----------
__global__ __launch_bounds__(512, 4) void deconv3_mfma(
    const unsigned short* __restrict__ g2I,
    const unsigned short* __restrict__ w2,
    const float* __restrict__ bias, float* __restrict__ y) {
  __shared__ __align__(16) unsigned short sA[4][260][8];   // dy: iy = oy0-1+dy
  __shared__ __align__(16) unsigned short sB[16*12*16*8];
  const int tid = threadIdx.x;
  const int oy0 = blockIdx.x*2, b = blockIdx.y;
  const int wave = tid >> 6, lane = tid & 63;
  const int col_l = lane & 15, kg = lane >> 4;
  const int r = wave >> 2;            // output row selector
  const int pxb = (wave & 3)*64;
  for (int i = tid; i < 3072; i += 512) {
    int co = i & 15, tap = (i>>4) % 12, ch = i/192;
    *(uint4*)&sB[((ch*12+tap)*16+co)*8] = *(const uint4*)(w2 + (long)co*1536 + ch*96 + tap*8);
  }
  if (tid < 16) {           // zero cols {0,1,258,259} x 4 dy
    int dy = tid >> 2, c = tid & 3;
    *(uint4*)&sA[dy][(c<2)?c:(256+c)][0] = zero4();
  }
  // A prefetch: 4 rows x 256 px = 1024 units over 512 thr = 2 each
  long aBase[2]; int aLdsO[2]; bool aOk[2];
  #pragma unroll
  for (int u = 0; u < 2; ++u) {
    int idx = tid + u*512;
    int px = idx & 255, dy = idx >> 8;
    int iy = oy0 - 1 + dy;
    aOk[u] = (iy >= 0 && iy < 256);
    aBase[u] = ((long)(b*256 + (aOk[u]?iy:0)))*32768 + px*8;
    aLdsO[u] = (dy*260 + px + 2)*8;
  }
  uint4 pA[2];
  #pragma unroll
  for (int u=0;u<2;u++) pA[u] = aOk[u] ? *(const uint4*)(g2I + aBase[u]) : zero4();

  unsigned short* sAf = &sA[0][0][0];
  f32x4 acc[4] = {};
  for (int ch = 0; ch < 16; ++ch) {
    __syncthreads();
    #pragma unroll
    for (int u=0;u<2;u++) *(uint4*)(sAf + aLdsO[u]) = pA[u];
    __syncthreads();
    if (ch < 15) {
      #pragma unroll
      for (int u=0;u<2;u++)
        pA[u] = aOk[u] ? *(const uint4*)(g2I + aBase[u] + (ch+1)*2048) : zero4();
      __builtin_amdgcn_sched_barrier(0);
    }
    #pragma unroll
    for (int s = 0; s < 3; ++s) {
      bf16x8 bF = *(const bf16x8*)&sB[((ch*12 + s*4 + kg)*16 + col_l)*8];
      __builtin_amdgcn_s_setprio(1);
      #pragma unroll
      for (int mf = 0; mf < 4; ++mf) {
        int px = pxb + mf*16 + col_l;
        bf16x8 aF = *(const bf16x8*)&sA[r + 2 - s][px + 3 - kg][0];
        acc[mf] = MFMA16(aF, bF, acc[mf]);
      }
      __builtin_amdgcn_s_setprio(0);
    }
  }
  if (col_l < 3) {
    const int oy = oy0 + r;
    float bv = bias[col_l];
    #pragma unroll
    for (int mf = 0; mf < 4; ++mf) {
      int px = pxb + mf*16 + kg*4;
      float4 o;
      o.x = 1.f/(1.f + expf(-(acc[mf][0] + bv)));
      o.y = 1.f/(1.f + expf(-(acc[mf][1] + bv)));
      o.z = 1.f/(1.f + expf(-(acc[mf][2] + bv)));
      o.w = 1.f/(1.f + expf(-(acc[mf][3] + bv)));
      *(float4*)(y + ((long)(b*3 + col_l)*256 + oy)*256 + px) = o;
    }
  }
}

// ---------------- VQ via MFMA (unchanged) ----------------
__global__ __launch_bounds__(256, 2) void vq_mfma(
    const unsigned short* __restrict__ zeH, const unsigned short* __restrict__ zeM,
    const unsigned short* __restrict__ zeL,
    const float* __restrict__ emb, const float* __restrict__ esq,
    float* __restrict__ out_idx, float* __restrict__ zq) {
  __shared__ __align__(16) unsigned short sA[64*3*8*8];
  __shared__ __align__(16) unsigned short sB[128*3*8*8];
  __shared__ float snb[128];
  __shared__ int sidx[64];
  const int tid = threadIdx.x;
  const long n0 = (long)blockIdx.x*64;
  const int wave = tid >> 6, lane = tid & 63;
  const int col = lane & 15, kg = lane >> 4;

  #pragma unroll
  for (int j = 0; j < 6; ++j) {
    int idx = tid + j*256;
    int pl = idx >> 9, rem = idx & 511;
    int n = rem >> 3, slot = rem & 7;
    const unsigned short* src = (pl==0 ? zeH : (pl==1 ? zeM : zeL)) + (n0+n)*64 + slot*8;
    *(uint4*)&sA[((n*3 + pl)*8 + (slot ^ (n&7)))*8] = *(const uint4*)src;
  }

  const int codeT = tid >> 1, halfT = tid & 1;
  float4 pB[8];
  #pragma unroll
  for (int q = 0; q < 8; ++q)
    pB[q] = *(const float4*)(emb + (long)codeT*64 + halfT*32 + q*4);
  float pSn = (tid < 128) ? esq[tid] : 0.f;

  float best[4] = {3.4e38f,3.4e38f,3.4e38f,3.4e38f};
  int bidx[4] = {0,0,0,0};

  for (int ch = 0; ch < 4; ++ch) {
    __syncthreads();
    #pragma unroll
    for (int s4 = 0; s4 < 4; ++s4) {
      int slot = halfT*4 + s4;
      float4 lo = pB[s4*2], hi = pB[s4*2+1];
      unsigned short th[8], tm[8], tl[8];
      split3(lo.x, th[0], tm[0], tl[0]); split3(lo.y, th[1], tm[1], tl[1]);
      split3(lo.z, th[2], tm[2], tl[2]); split3(lo.w, th[3], tm[3], tl[3]);
      split3(hi.x, th[4], tm[4], tl[4]); split3(hi.y, th[5], tm[5], tl[5]);
      split3(hi.z, th[6], tm[6], tl[6]); split3(hi.w, th[7], tm[7], tl[7]);
      int base = ((codeT*3)*8 + (slot ^ (codeT&7)))*8;
      *(uint4*)&sB[base]       = *(uint4*)th;
      *(uint4*)&sB[base + 64]  = *(uint4*)tm;
      *(uint4*)&sB[base + 128] = *(uint4*)tl;
    }
    if (tid < 128) snb[tid] = pSn;
    if (ch < 3) {
      #pragma unroll
      for (int q = 0; q < 8; ++q)
        pB[q] = *(const float4*)(emb + ((long)(ch+1)*128 + codeT)*64 + halfT*32 + q*4);
      if (tid < 128) pSn = esq[(ch+1)*128 + tid];
    }
    __syncthreads();

    f32x4 acc[8] = {};
    #pragma unroll
    for (int kk = 0; kk < 2; ++kk) {
      const int nloc = wave*16 + col;
      const int slot = kk*4 + kg;
      bf16x8 aF[3];
      #pragma unroll
      for (int pl = 0; pl < 3; ++pl)
        aF[pl] = *(const bf16x8*)&sA[((nloc*3 + pl)*8 + (slot ^ (nloc&7)))*8];
      __builtin_amdgcn_s_setprio(1);
      #pragma unroll
      for (int cf = 0; cf < 8; ++cf) {
        int cl = cf*16 + col;
        int bb = ((cl*3)*8 + (slot ^ (cl&7)))*8;
        bf16x8 b0 = *(const bf16x8*)&sB[bb];
        bf16x8 b1 = *(const bf16x8*)&sB[bb + 64];
        bf16x8 b2 = *(const bf16x8*)&sB[bb + 128];
        f32x4 a = acc[cf];
        a = MFMA16(aF[0], b0, a);
        a = MFMA16(aF[0], b1, a);
        a = MFMA16(aF[1], b0, a);
        a = MFMA16(aF[0], b2, a);
        a = MFMA16(aF[2], b0, a);
        a = MFMA16(aF[1], b1, a);
        acc[cf] = a;
      }
      __builtin_amdgcn_s_setprio(0);
    }
    #pragma unroll
    for (int cf = 0; cf < 8; ++cf) {
      float sv = snb[cf*16 + col];
      int code = ch*128 + cf*16 + col;
      #pragma unroll
      for (int j = 0; j < 4; ++j) {
        float s = sv - 2.f*acc[cf][j];
        if (s < best[j]) { best[j] = s; bidx[j] = code; }
      }
    }
  }

  #pragma unroll
  for (int j = 0; j < 4; ++j) {
    float b = best[j]; int ii = bidx[j];
    #pragma unroll
    for (int off = 1; off < 16; off <<= 1) {
      float ob = __shfl_xor(b, off);
      int oi = __shfl_xor(ii, off);
      if (ob < b || (ob == b && oi < ii)) { b = ob; ii = oi; }
    }
    if (col == 0) sidx[wave*16 + kg*4 + j] = ii;
  }
  __syncthreads();
  if (tid < 64) out_idx[n0 + tid] = (float)sidx[tid];
  #pragma unroll
  for (int j = 0; j < 4; ++j) {
    int t = tid + j*256;
    int row = t >> 4, q = t & 15;
    float4 v = *(const float4*)(emb + (long)sidx[row]*64 + q*4);
    *(float4*)(zq + (n0 + row)*64 + q*4) = v;
  }
}

// ---------------- launch ----------------
extern "C" void kernel_launch(void* const* d_in, const int* in_sizes, int n_in,
                              void* d_out, int out_size, void* d_ws, size_t ws_size,
                              hipStream_t stream) {
  const float* x   = (const float*)d_in[0];
  const float* c1w = (const float*)d_in[1];  const float* c1b = (const float*)d_in[2];
  const float* c2w = (const float*)d_in[3];  const float* c2b = (const float*)d_in[4];
  const float* c3w = (const float*)d_in[5];  const float* c3b = (const float*)d_in[6];
  const float* emb = (const float*)d_in[7];
  const float* d1w = (const float*)d_in[8];  const float* d1b = (const float*)d_in[9];
  const float* d2w = (const float*)d_in[10]; const float* d2b = (const float*)d_in[11];
  const float* d3w = (const float*)d_in[12]; const float* d3b = (const float*)d_in[13];
  float* out = (float*)d_out;

  float* xrec = out;
  float* oidx = out + 3145728;
  float* zq   = out + 3211264;

  const long XB  = 196608;   // 3*256*256
  const long ZEB = 262144;   // ze elems per batch
  const long PS1 = 8388608;  // per-plane h1 (interleaved) in shorts
  const long H2B = 1572864;  // per-batch h2I stride in shorts

  const size_t NEEDED  = 112273408ULL;           // 4-batch tier
  const size_t NEEDED8 = 170994688ULL;           // 8-batch decoder tier
  if (ws_size < NEEDED) return;
  const bool use8 = (ws_size >= NEEDED8);
  char* wsb = (char*)d_ws;
  unsigned short* h1grp = (unsigned short*)wsb;              // interleaved, 50.3MB
  unsigned short* h2I   = (unsigned short*)(wsb + 67108864); // interleaved 8-batch, 25.17MB
  unsigned short* zeH = (unsigned short*)(wsb + 92274688);
  unsigned short* zeM = (unsigned short*)(wsb + 100663296);
  unsigned short* zeL = (unsigned short*)out;                // xrec region: dead until deconv3
  // weights: branch-consistent base
  char* W = use8 ? (wsb + 167772160) : (wsb + 109051904);
  float* w2c1          = (float*)(W);
  unsigned short* w2c2 = (unsigned short*)(W + 24576);
  unsigned short* w2c3 = (unsigned short*)(W + 1597440);
  unsigned short* w2d1 = (unsigned short*)(W + 2383872);
  unsigned short* w2d2 = (unsigned short*)(W + 2646016);
  unsigned short* w2d3 = (unsigned short*)(W + 3170304);
  float* esq           = (float*)(W + 3219456);

  wprep_all<<<3066, 256, 0, stream>>>(c1w, w2c1, c2w, w2c2, c3w, w2c3,
                                      d1w, w2d1, d2w, w2d2, d3w, w2d3, emb, esq);

  // encoder
  for (int g = 0; g < 4; ++g) {
    conv1_split<<<dim3(16,16,8), 256, 0, stream>>>(
        x + (long)g*4*XB, w2c1, c1b, h1grp, PS1);
    conv2_mfma<<<dim3(64,2,4), 256, 0, stream>>>(
        h1grp, PS1, w2c2, c2b, h2I + (long)(g&1)*4*H2B);
    if (g & 1) {
      long zo = (long)(g>>1)*8*ZEB;
      conv3_mfma<<<dim3(64,1,8), 256, 0, stream>>>(
          h2I, w2c3, c3b, zeH + zo, zeM + zo, zeL + zo);
    }
  }
  vq_mfma<<<1024, 256, 0, stream>>>(zeH, zeM, zeL, emb, esq, oidx, zq);

  // decoder
  if (use8) {
    unsigned short* g2g = (unsigned short*)wsb;               // 128MB
    unsigned short* g1g = (unsigned short*)(wsb + 134217728); // 32MB
    for (int g = 0; g < 2; ++g) {
      deconv_mfma<64, 64, 0 ><<<dim3(64, 2, 8), 256, 0, stream>>>(
          (const void*)(zq + (long)g*8*ZEB), w2d1, d1b, g1g);
      deconv_mfma<128,128,1 ><<<dim3(128,2,8), 512, 0, stream>>>(
          (const void*)g1g, w2d2, d2b, g2g);
      deconv3_mfma<<<dim3(128,8), 512, 0, stream>>>(
          g2g, w2d3, d3b, xrec + (long)g*8*XB);
    }
  } else {
    unsigned short* g2g = (unsigned short*)wsb;               // 64MB
    unsigned short* g1g = (unsigned short*)(wsb + 67108864);  // 16MB
    for (int g = 0; g < 4; ++g) {
      deconv_mfma<64, 64, 0 ><<<dim3(64, 2, 4), 256, 0, stream>>>(
          (const void*)(zq + (long)g*4*ZEB), w2d1, d1b, g1g);
      deconv_mfma<128,128,1 ><<<dim3(128,2,4), 512, 0, stream>>>(
          (const void*)g1g, w2d2, d2b, g2g);
      deconv3_mfma<<<dim3(128,4), 512, 0, stream>>>(
          g2g, w2d3, d3b, xrec + (long)g*4*XB);
    }
  }
}

// Round 16
// 670.858 us; speedup vs baseline: 3.4039x; 1.0023x over previous
//
#include <hip/hip_runtime.h>
#include <hip/hip_bf16.h>

#define DEV __device__ __forceinline__

typedef __attribute__((ext_vector_type(8))) short bf16x8;
typedef __attribute__((ext_vector_type(4))) float f32x4;
typedef __attribute__((ext_vector_type(4))) unsigned short u16x4;

#define MFMA16(a,b,c) __builtin_amdgcn_mfma_f32_16x16x32_bf16(a,b,c,0,0,0)

DEV unsigned short bfbits(float v){ __hip_bfloat16 h = __float2bfloat16(v); return *(unsigned short*)&h; }
DEV float bf2f(unsigned short u){ __hip_bfloat16 h = *(__hip_bfloat16*)&u; return __bfloat162float(h); }
DEV void split3(float v, unsigned short& h, unsigned short& m, unsigned short& l) {
  h = bfbits(v);        float r  = v - bf2f(h);
  m = bfbits(r);        float r2 = r - bf2f(m);
  l = bfbits(r2);
}
DEV uint4 zero4(){ uint4 z; z.x=0; z.y=0; z.z=0; z.w=0; return z; }
DEV void gload_lds16(const void* g, void* l) {
  __builtin_amdgcn_global_load_lds(
      (const __attribute__((address_space(1))) void*)g,
      (__attribute__((address_space(3))) void*)l, 16, 0, 0);
}

// ---------------- fused weight prep (one dispatch, 3066 blocks) ----------------
DEV void prep_deconv_img(int i, int CI, const float* __restrict__ w, unsigned short* __restrict__ w2) {
  const int nch = CI/16;
  int cil = i & 7, s = (i >> 3) & 7, co = (i >> 6) & 127, f = (i >> 13) & 1;
  int rest = i >> 14;
  int ch = rest % nch, e = rest / nch;
  int k = ch*64 + s*8 + cil;
  int ci = (k & 15) | ((k >> 6) << 4);
  int tap = (k >> 4) & 3, a = tap >> 1, b = tap & 1;
  float v = w[ (((long)ci*128 + co)*4 + (2*a+1-e))*4 + (2*b+1-f) ];
  w2[(long)(e*nch + ch)*16384 + ((long)(f*128 + co))*64 + ((s ^ (co&7))*8) + cil] = bfbits(v);
}
__global__ __launch_bounds__(256) void wprep_all(
    const float* __restrict__ c1w, float* __restrict__ w2c1,
    const float* __restrict__ c2w, unsigned short* __restrict__ w2c2,
    const float* __restrict__ c3w, unsigned short* __restrict__ w2c3,
    const float* __restrict__ d1w, unsigned short* __restrict__ w2d1,
    const float* __restrict__ d2w, unsigned short* __restrict__ w2d2,
    const float* __restrict__ d3w, unsigned short* __restrict__ w2d3,
    const float* __restrict__ emb, float* __restrict__ esq) {
  const int bx = blockIdx.x, t = threadIdx.x;
  if (bx < 24) {                         // conv1 transpose: 6144
    int i = bx*256 + t;
    if (i < 6144) {
      int tap = i & 15, ci = (i>>4) % 3, co = i / 48;
      w2c1[((long)ci*16 + tap)*128 + co] = c1w[i];
    }
  } else if (bx < 1048) {                // conv2 prep -> LDS-image layout
    int i = (bx-24)*256 + t;             // 0..262143
    int cil = i & 7, s = (i>>3) & 15, co = (i>>7) & 63;
    int ch = (i>>13) & 15, cog = i >> 17;
    int co_g = cog*64 + co, ci = ch*8 + cil, ky = s >> 2, kx = s & 3;
    float v = c2w[(((long)co_g*128 + ci)*4 + ky)*4 + kx];
    unsigned short h,m,l; split3(v,h,m,l);
    long base = (long)(cog*16 + ch)*24576 + ((long)co*16 + (s ^ (co&15)))*8 + cil;
    w2c2[base] = h; w2c2[base + 8192] = m; w2c2[base + 16384] = l;
  } else if (bx < 1432) {                // conv3 prep -> LDS-image layout: 98304
    int i = (bx-1048)*256 + t;
    int k = i % 1536, co = i / 1536;
    int ch = k / 96, rem = k % 96;
    int tap = rem >> 3, cil = rem & 7;
    int ci = ch*8 + cil, ky = tap >> 2, kx = tap & 3;
    float v = (kx < 3) ? c3w[(((long)co*128 + ci)*3 + ky)*3 + kx] : 0.f;
    unsigned short h,m,l; split3(v,h,m,l);
    long base = (long)ch*24576 + ((long)co*16 + (tap ^ (co&15)))*8 + cil;
    w2c3[base] = h; w2c3[base + 8192] = m; w2c3[base + 16384] = l;
  } else if (bx < 1944) {                // deconv1 image: 131072 (CI=64)
    prep_deconv_img((bx-1432)*256 + t, 64, d1w, w2d1);
  } else if (bx < 2968) {                // deconv2 image: 262144 (CI=128)
    prep_deconv_img((bx-1944)*256 + t, 128, d2w, w2d2);
  } else if (bx < 3064) {                // deconv3: 24576
    int i = (bx-2968)*256 + t;
    if (i < 24576) {
      int k = i % 1536, co = i / 1536;
      int ch = k / 96, rem = k % 96;
      int tap = rem >> 3, cil = rem & 7;
      int ci = ch*8 + cil, ky = tap >> 2, kx = tap & 3;
      float v = (co < 3 && kx < 3) ? d3w[(((long)ci*3 + co)*3 + ky)*3 + kx] : 0.f;
      w2d3[i] = bfbits(v);
    }
  } else {                               // esq: 512 codes
    int code = (bx-3064)*256 + t;
    if (code < 512) {
      const float4* ev = (const float4*)(emb + (long)code*64);
      float s = 0.f;
      #pragma unroll
      for (int q=0;q<16;q++){ float4 e4 = ev[q];
        s += e4.x*e4.x + e4.y*e4.y + e4.z*e4.z + e4.w*e4.w; }
      esq[code] = s;
    }
  }
}

// ---------------- conv1: f32 direct, out 3 bf16 planes INTERLEAVED ----------------
__global__ __launch_bounds__(256) void conv1_split(
    const float* __restrict__ x, const float* __restrict__ w2,
    const float* __restrict__ bias, unsigned short* __restrict__ h1, long PS1) {
  __shared__ __align__(16) float sIn[3][18][20];
  __shared__ __align__(16) float sW[3*16*64];
  const int tid = threadIdx.x;
  const int b = blockIdx.z >> 1, cog = blockIdx.z & 1;
  const int co0 = cog*64;
  const int oy0 = blockIdx.y*8, ox0 = blockIdx.x*8;
  const int cg2 = tid >> 5;
  const int pg2 = tid & 31;
  const int r = pg2 >> 2, pxp = (pg2 & 3)*2;
  float acc[8][2];
  #pragma unroll
  for (int c=0;c<8;c++){ float bv = bias[co0 + cg2*8 + c];
    acc[c][0]=bv; acc[c][1]=bv; }
  const float* xb = x + (long)b*3*256*256;
  const int iy0 = 2*oy0 - 1, ix0 = 2*ox0 - 1;
  for (int t=tid; t<3*18*18; t+=256) {
    int xx = t%18, yy=(t/18)%18, ci=t/324;
    int gy = iy0+yy, gx = ix0+xx;
    float v = 0.f;
    if (gy>=0 && gy<256 && gx>=0 && gx<256) v = xb[((long)ci*256+gy)*256+gx];
    sIn[ci][yy][xx] = v;
  }
  for (int t=tid; t<3*16*64; t+=256) {
    sW[t] = w2[(long)(t>>6)*128 + co0 + (t&63)];
  }
  __syncthreads();
  for (int ci=0; ci<3; ci++) {
    #pragma unroll
    for (int ky=0;ky<4;ky++)
    #pragma unroll
    for (int kx=0;kx<4;kx++) {
      const float* wp = &sW[(ci*16 + ky*4+kx)*64 + cg2*8];
      float4 w0 = *(const float4*)wp;
      float4 w1 = *(const float4*)(wp+4);
      const int yy = 2*r + ky;
      #pragma unroll
      for (int p=0;p<2;p++) {
        float iv = sIn[ci][yy][2*(pxp+p)+kx];
        acc[0][p] += w0.x*iv; acc[1][p] += w0.y*iv;
        acc[2][p] += w0.z*iv; acc[3][p] += w0.w*iv;
        acc[4][p] += w1.x*iv; acc[5][p] += w1.y*iv;
        acc[6][p] += w1.z*iv; acc[7][p] += w1.w*iv;
      }
    }
  }
  const int chg = cog*8 + cg2;
  #pragma unroll
  for (int p=0;p<2;p++) {
    unsigned short th[8], tm[8], tl[8];
    #pragma unroll
    for (int c=0;c<8;c++) {
      float v = fmaxf(acc[c][p], 0.f);
      split3(v, th[c], tm[c], tl[c]);
    }
    long base = (((long)(b*128 + oy0+r)*16 + chg)*128 + ox0+pxp+p)*8;
    *(uint4*)(h1 + base)          = *(uint4*)th;
    *(uint4*)(h1 + PS1 + base)    = *(uint4*)tm;
    *(uint4*)(h1 + 2*PS1 + base)  = *(uint4*)tl;
  }
}

// ---------------- conv2: MFMA 6-term split; post-barrier A prefetch ----------
__global__ __launch_bounds__(256, 2) void conv2_mfma(
    const unsigned short* __restrict__ h1, long PS1,
    const unsigned short* __restrict__ w2,   // LDS-image: [cog][ch][24576 shorts]
    const float* __restrict__ bias,
    unsigned short* __restrict__ h2I) {      // [b][row64][pl3][ch16][px64][8]
  __shared__ __align__(16) unsigned short sA[3][4][130][8];
  __shared__ __align__(16) unsigned short sB[24576];
  const int tid = threadIdx.x;
  const int oy = blockIdx.x, cog = blockIdx.y, b = blockIdx.z;
  const int wave = tid >> 6, lane = tid & 63;
  const int wr = wave >> 1, wc = wave & 1;
  const int col_l = lane & 15, kg = lane >> 4;
  const int iy0 = 2*oy - 1;
  f32x4 acc[2][2] = {};
  unsigned short* sAf = &sA[0][0][0][0];
  const unsigned short* bsrc = w2 + (long)cog*16*24576;

  long aOff[6]; int aLdsO[6]; bool aOk[6];
  #pragma unroll
  for (int j = 0; j < 6; ++j) {
    int idx = tid + j*256;
    int px = idx & 127, rr = (idx >> 7) & 3, pl = idx >> 9;
    int iy = iy0 + rr;
    aOk[j] = (iy >= 0 && iy < 128);
    aOff[j] = (long)pl*PS1 + (long)(b*128 + (aOk[j]?iy:0))*16384 + px*8;
    aLdsO[j] = ((pl*4 + rr)*130 + px + 1)*8;
  }
  uint4 pA[6];
  #pragma unroll
  for (int j=0;j<6;j++)  pA[j] = aOk[j] ? *(const uint4*)(h1 + aOff[j]) : zero4();

  if (tid < 24) {
    int pl = tid>>3, rr=(tid>>1)&3, c=tid&1;
    *(uint4*)&sA[pl][rr][c?129:0][0] = zero4();
  }

  for (int ch = 0; ch < 16; ++ch) {
    __syncthreads();
    #pragma unroll
    for (int j=0;j<6;j++)  *(uint4*)(sAf + aLdsO[j]) = pA[j];
    #pragma unroll
    for (int j = 0; j < 12; ++j) {
      int blk = wave*12 + j;
      gload_lds16(bsrc + (long)ch*24576 + blk*512 + lane*8, &sB[blk*512]);
    }
    __syncthreads();
    if (ch < 15) {
      #pragma unroll
      for (int j=0;j<6;j++)  pA[j] = aOk[j] ? *(const uint4*)(h1 + aOff[j] + (ch+1)*1024) : zero4();
      __builtin_amdgcn_sched_barrier(0);
    }
    #pragma unroll
    for (int s = 0; s < 4; ++s) {        // s = ky
      bf16x8 aF[2][3]; bf16x8 bF[2][3];
      const int tap = s*4 + kg;
      #pragma unroll
      for (int mf = 0; mf < 2; ++mf) {
        int ox = wr*32 + mf*16 + col_l;
        #pragma unroll
        for (int pl = 0; pl < 3; ++pl)
          aF[mf][pl] = *(const bf16x8*)&sA[pl][s][2*ox + kg][0];
      }
      #pragma unroll
      for (int nf = 0; nf < 2; ++nf) {
        int co = wc*32 + nf*16 + col_l;
        int ba = (co*16 + (tap ^ (co&15)))*8;
        bF[nf][0] = *(const bf16x8*)&sB[ba];
        bF[nf][1] = *(const bf16x8*)&sB[ba + 8192];
        bF[nf][2] = *(const bf16x8*)&sB[ba + 16384];
      }
      __builtin_amdgcn_s_setprio(1);
      #pragma unroll
      for (int mf = 0; mf < 2; ++mf)
      #pragma unroll
      for (int nf = 0; nf < 2; ++nf) {
        f32x4 a = acc[mf][nf];
        a = MFMA16(aF[mf][0], bF[nf][0], a);
        a = MFMA16(aF[mf][0], bF[nf][1], a);
        a = MFMA16(aF[mf][1], bF[nf][0], a);
        a = MFMA16(aF[mf][0], bF[nf][2], a);
        a = MFMA16(aF[mf][2], bF[nf][0], a);
        a = MFMA16(aF[mf][1], bF[nf][1], a);
        acc[mf][nf] = a;
      }
      __builtin_amdgcn_s_setprio(0);
    }
  }
  // epilogue: acc -> sB[pl][co64][72pad] -> interleaved h2I
  __syncthreads();
  #pragma unroll
  for (int nf = 0; nf < 2; ++nf) {
    int co = wc*32 + nf*16 + col_l;
    float bv = bias[cog*64 + co];
    #pragma unroll
    for (int mf = 0; mf < 2; ++mf) {
      int px0 = wr*32 + mf*16 + kg*4;
      u16x4 oh, om, ol;
      #pragma unroll
      for (int r = 0; r < 4; ++r) {
        float v = fmaxf(acc[mf][nf][r] + bv, 0.f);
        unsigned short h,m,l; split3(v,h,m,l);
        oh[r]=h; om[r]=m; ol[r]=l;
      }
      *(u16x4*)&sB[(0*64 + co)*72 + px0] = oh;
      *(u16x4*)&sB[(1*64 + co)*72 + px0] = om;
      *(u16x4*)&sB[(2*64 + co)*72 + px0] = ol;
    }
  }
  __syncthreads();
  #pragma unroll
  for (int j = 0; j < 6; ++j) {
    int idx = tid + j*256;
    int pl = idx >> 9, ch = (idx >> 6) & 7, px = idx & 63;
    unsigned short tmp[8];
    #pragma unroll
    for (int c = 0; c < 8; ++c) tmp[c] = sB[(pl*64 + ch*8 + c)*72 + px];
    *(uint4*)(h2I + ((((long)(b*64 + oy)*3 + pl)*16 + cog*8 + ch)*64 + px)*8) = *(uint4*)tmp;
  }
}

// ---------------- conv3: MFMA 6-term split; A+B via global_load_lds ----------------
__global__ __launch_bounds__(256, 2) void conv3_mfma(
    const unsigned short* __restrict__ h2I,  // [b][row64][pl3][ch16][px64][8]
    const unsigned short* __restrict__ w2,   // LDS-image: [ch][24576 shorts]
    const float* __restrict__ bias,
    unsigned short* __restrict__ zeH, unsigned short* __restrict__ zeM,
    unsigned short* __restrict__ zeL) {
  __shared__ __align__(16) unsigned short sA3[3][3][68][8];
  __shared__ __align__(16) unsigned short sB[24576];
  const int tid = threadIdx.x;
  const int oy = blockIdx.x, b = blockIdx.z;
  const int wave = tid >> 6, lane = tid & 63;
  const int wr = wave >> 1, wc = wave & 1;
  const int col_l = lane & 15, kg = lane >> 4;
  f32x4 acc[2][2] = {};
  if (tid < 27) {
    int row = tid/3, c = tid%3;
    int pl = row/3, rr = row%3;
    *(uint4*)&sA3[pl][rr][(c==0)?0:(64+c)][0] = zero4();
  }
  if (oy == 0 && tid < 192) {
    int pl = tid >> 6, px = tid & 63;
    *(uint4*)&sA3[pl][0][px+1][0] = zero4();
  }
  if (oy == 63 && tid < 192) {
    int pl = tid >> 6, px = tid & 63;
    *(uint4*)&sA3[pl][2][px+1][0] = zero4();
  }

  for (int ch = 0; ch < 16; ++ch) {
    __syncthreads();
    #pragma unroll
    for (int j = 0; j < 3; ++j) {
      int row = wave*3 + j;
      if (row < 9) {
        int pl = row/3, rr = row%3;
        int iy = oy + rr - 1;
        if (iy >= 0 && iy < 64)
          gload_lds16(h2I + ((((long)(b*64 + iy)*3 + pl)*16 + ch)*64)*8 + lane*8,
                      &sA3[pl][rr][1][0]);
      }
    }
    #pragma unroll
    for (int j = 0; j < 12; ++j) {
      int blk = wave*12 + j;
      gload_lds16(w2 + (long)ch*24576 + blk*512 + lane*8, &sB[blk*512]);
    }
    __syncthreads();
    #pragma unroll
    for (int s = 0; s < 3; ++s) {
      bf16x8 aF[2][3]; bf16x8 bF[2][3];
      const int tap = s*4 + kg;
      #pragma unroll
      for (int mf = 0; mf < 2; ++mf) {
        int ox = wr*32 + mf*16 + col_l;
        #pragma unroll
        for (int pl = 0; pl < 3; ++pl)
          aF[mf][pl] = *(const bf16x8*)&sA3[pl][s][ox + kg][0];
      }
      #pragma unroll
      for (int nf = 0; nf < 2; ++nf) {
        int co = wc*32 + nf*16 + col_l;
        int ba = (co*16 + (tap ^ (co&15)))*8;
        bF[nf][0] = *(const bf16x8*)&sB[ba];
        bF[nf][1] = *(const bf16x8*)&sB[ba + 8192];
        bF[nf][2] = *(const bf16x8*)&sB[ba + 16384];
      }
      __builtin_amdgcn_s_setprio(1);
      #pragma unroll
      for (int mf = 0; mf < 2; ++mf)
      #pragma unroll
      for (int nf = 0; nf < 2; ++nf) {
        f32x4 a = acc[mf][nf];
        a = MFMA16(aF[mf][0], bF[nf][0], a);
        a = MFMA16(aF[mf][0], bF[nf][1], a);
        a = MFMA16(aF[mf][1], bF[nf][0], a);
        a = MFMA16(aF[mf][0], bF[nf][2], a);
        a = MFMA16(aF[mf][2], bF[nf][0], a);
        a = MFMA16(aF[mf][1], bF[nf][1], a);
        acc[mf][nf] = a;
      }
      __builtin_amdgcn_s_setprio(0);
    }
  }
  __syncthreads();
  #pragma unroll
  for (int nf = 0; nf < 2; ++nf) {
    int co = wc*32 + nf*16 + col_l;
    float bv = bias[co];
    #pragma unroll
    for (int mf = 0; mf < 2; ++mf) {
      int px0 = wr*32 + mf*16 + kg*4;
      u16x4 oh, om, ol;
      #pragma unroll
      for (int r = 0; r < 4; ++r) {
        float v = acc[mf][nf][r] + bv;
        unsigned short h,m,l; split3(v,h,m,l);
        oh[r]=h; om[r]=m; ol[r]=l;
      }
      *(u16x4*)&sB[(0*64 + co)*72 + px0] = oh;
      *(u16x4*)&sB[(1*64 + co)*72 + px0] = om;
      *(u16x4*)&sB[(2*64 + co)*72 + px0] = ol;
    }
  }
  __syncthreads();
  #pragma unroll
  for (int j = 0; j < 6; ++j) {
    int idx = tid + j*256;
    int pl = idx >> 9, co_l = (idx >> 3) & 63, q = idx & 7;
    uint4 v = *(const uint4*)&sB[(pl*64 + co_l)*72 + q*8];
    unsigned short* dst = (pl==0) ? zeH : ((pl==1) ? zeM : zeL);
    *(uint4*)(dst + ((long)(b*64 + co_l)*64 + oy)*64 + q*8) = v;
  }
}

// ---------------- MFMA ConvTranspose2d s2k4p1; 2-pass epilogue; post-barrier prefetch -----
template<int TX, int MODE>
struct SmemD {
  union {
    struct { __align__(16) unsigned short In[2][TX+2][24];
             __align__(16) unsigned short W[2*128*64]; } o;
    struct { __align__(16) unsigned short In[2][TX+2][16];
             __align__(16) unsigned short W[2*128*64]; } v;
    __align__(16) unsigned short Out[128][136];
  };
};

template<int CIN, int TX, int MODE>
__global__ __launch_bounds__(TX*4, (TX==64)?3:4) void deconv_mfma(
    const void* __restrict__ xin, const unsigned short* __restrict__ w2,
    const float* __restrict__ bias, unsigned short* __restrict__ yI) {
  constexpr int NTHR = TX*4;
  constexpr int NWAVE = NTHR/64;
  constexpr int NWG  = 32/NWAVE;
  __shared__ SmemD<TX,MODE> sm;
  unsigned short* Wb = MODE ? &sm.v.W[0] : &sm.o.W[0];

  const int tid = threadIdx.x;
  const int ty = blockIdx.x, e = blockIdx.y, b = blockIdx.z;
  const int wave = tid >> 6, lane = tid & 63;
  const int wc = wave & 1, wr = wave >> 1;
  const int f = (wr*64) / TX;
  const int tx_base = (wr*64) & (TX-1);
  const int col_l = lane & 15, kg = lane >> 4;
  const unsigned short* wsrc = w2 + (long)e*(CIN/16)*16384;

  constexpr int TPR = NTHR/32;
  const int rowid = tid / TPR, liO = tid % TPR;
  const int sci = rowid >> 1, srr = rowid & 1;
  float4 pLo, pHi; uint4 pIn;
  long aBase = 0; bool aOk = false;
  int pxV = 0, halfV = 0, rrV = 0;
  if (MODE == 0) {
    int iy = ty + e - 1 + srr;
    aOk = (iy >= 0 && iy < TX);
    aBase = ((long)b*CIN + sci)*TX*TX + (long)(aOk?iy:0)*TX + liO*8;
    if (aOk) { const float4* s4 = (const float4*)((const float*)xin + aBase);
               pLo = s4[0]; pHi = s4[1]; }
  } else {
    halfV = tid & 1; pxV = (tid >> 1) & (TX-1); rrV = tid >> 8;
    int iy = ty + e - 1 + rrV;
    aOk = (iy >= 0 && iy < TX);
    aBase = ((long)b*TX + (aOk?iy:0))*((long)(CIN/8)*TX*8) + (long)halfV*TX*8 + pxV*8;
    pIn = aOk ? *(const uint4*)((const unsigned short*)xin + aBase) : zero4();
  }

  if (MODE == 0) {
    if (tid < 64) {
      int rr = tid & 1, cc = ((tid>>1)&1) ? TX+1 : 0, ci = tid >> 2;
      sm.o.In[rr][cc][ci] = 0;
    }
  } else {
    if (tid < 8) {
      int rr = tid & 1, c = (tid>>1)&1, hf = (tid>>2)&1;
      *(uint4*)&sm.v.In[rr][c?TX+1:0][hf*8] = zero4();
    }
  }

  f32x4 acc[4][4] = {};
  for (int ch = 0; ch < CIN/16; ++ch) {
    __syncthreads();
    if (MODE == 0) {
      unsigned short vals[8];
      if (aOk) {
        float4 lo = pLo, hi = pHi;
        vals[0]=bfbits(lo.x); vals[1]=bfbits(lo.y); vals[2]=bfbits(lo.z); vals[3]=bfbits(lo.w);
        vals[4]=bfbits(hi.x); vals[5]=bfbits(hi.y); vals[6]=bfbits(hi.z); vals[7]=bfbits(hi.w);
      } else {
        #pragma unroll
        for (int j=0;j<8;j++) vals[j] = 0;
      }
      #pragma unroll
      for (int j=0;j<8;j++) {
        int jj = (j + liO) & 7;
        sm.o.In[srr][1 + liO*8 + jj][sci] = vals[jj];
      }
    } else {
      *(uint4*)&sm.v.In[rrV][pxV+1][halfV*8] = pIn;
    }
    #pragma unroll
    for (int j = 0; j < NWG; ++j) {
      int blk = wave*NWG + j;
      gload_lds16(wsrc + (long)ch*16384 + blk*512 + lane*8, Wb + blk*512);
    }
    __syncthreads();
    if (ch + 1 < CIN/16) {
      if (MODE == 0) {
        if (aOk) { const float4* s4 = (const float4*)((const float*)xin + aBase + (long)(ch+1)*16*TX*TX);
                   pLo = s4[0]; pHi = s4[1]; }
      } else {
        pIn = aOk ? *(const uint4*)((const unsigned short*)xin + aBase + (ch+1)*2*TX*8) : zero4();
      }
      __builtin_amdgcn_sched_barrier(0);
    }
    #pragma unroll
    for (int kk = 0; kk < 2; ++kk) {
      bf16x8 aF[4];
      const int tap = kk*2 + (kg >> 1), a = tap >> 1, bb = tap & 1;
      #pragma unroll
      for (int mf = 0; mf < 4; ++mf) {
        int tx = tx_base + mf*16 + col_l;
        if (MODE == 0) aF[mf] = *(const bf16x8*)&sm.o.In[1-a][tx + 1 + f - bb][(kg&1)*8];
        else           aF[mf] = *(const bf16x8*)&sm.v.In[1-a][tx + 1 + f - bb][(kg&1)*8];
      }
      const int slot = kk*4 + kg;
      __builtin_amdgcn_s_setprio(1);
      #pragma unroll
      for (int nf = 0; nf < 4; ++nf) {
        int co_l = nf*16 + col_l;
        bf16x8 bF = *(const bf16x8*)(Wb + (f*128 + wc*64 + co_l)*64 + (slot ^ (co_l & 7))*8);
        #pragma unroll
        for (int mf = 0; mf < 4; ++mf)
          acc[mf][nf] = MFMA16(aF[mf], bF, acc[mf][nf]);
      }
      __builtin_amdgcn_s_setprio(0);
    }
  }

  // epilogue
  __syncthreads();
  float bv[4];
  #pragma unroll
  for (int nf = 0; nf < 4; ++nf) bv[nf] = bias[wc*64 + nf*16 + col_l];
  const int oy = 2*ty + e;
  if constexpr (TX == 64) {
    #pragma unroll
    for (int mf = 0; mf < 4; ++mf)
    #pragma unroll
    for (int nf = 0; nf < 4; ++nf) {
      int co = wc*64 + nf*16 + col_l;
      #pragma unroll
      for (int r = 0; r < 4; ++r) {
        int tx = tx_base + mf*16 + kg*4 + r;
        float v = fmaxf(acc[mf][nf][r] + bv[nf], 0.f);
        int ox = 2*tx + f;
        sm.Out[ox][co ^ (((ox>>3)&7)<<3)] = bfbits(v);
      }
    }
    __syncthreads();
    #pragma unroll
    for (int j = 0; j < 8; ++j) {
      int i = tid + j*NTHR;
      int px = i & 127, chn = i >> 7;
      uint4 vv = *(const uint4*)&sm.Out[px][(chn*8) ^ (((px>>3)&7)<<3)];
      *(uint4*)(yI + ((((long)b*128 + oy)*16 + chn)*128 + px)*8) = vv;
    }
  } else {
    const int myp = wr & 1;
    #pragma unroll
    for (int p = 0; p < 2; ++p) {
      if (myp == p) {
        #pragma unroll
        for (int mf = 0; mf < 4; ++mf)
        #pragma unroll
        for (int nf = 0; nf < 4; ++nf) {
          int co = wc*64 + nf*16 + col_l;
          #pragma unroll
          for (int r = 0; r < 4; ++r) {
            int tx = tx_base + mf*16 + kg*4 + r;
            float v = fmaxf(acc[mf][nf][r] + bv[nf], 0.f);
            int ox = 2*tx + f;
            sm.Out[ox & 127][co ^ (((ox>>3)&7)<<3)] = bfbits(v);
          }
        }
      }
      __syncthreads();
      #pragma unroll
      for (int j = 0; j < 4; ++j) {
        int i = tid + j*NTHR;
        int px = i & 127, chn = i >> 7;
        uint4 vv = *(const uint4*)&sm.Out[px][(chn*8) ^ (((px>>3)&7)<<3)];
        int pxg = p*128 + px;
        *(uint4*)(yI + ((((long)b*256 + oy)*16 + chn)*256 + pxg)*8) = vv;
      }
      if (p == 0) __syncthreads();
    }
  }
}

// ---------------- deconv3: MFMA + sigmoid; 2 output rows per block ----------
__global__ __launch_bounds__(512, 4) void deconv3_mfma(
    const unsigned short* __restrict__ g2I,
    const unsigned short* __restrict__ w2,
    const float* __restrict__ bias, float* __restrict__ y) {
  __shared__ __align__(16) unsigned short sA[4][260][8];
  __shared__ __align__(16) unsigned short sB[16*12*16*8];
  const int tid = threadIdx.x;
  const int oy0 = blockIdx.x*2, b = blockIdx.y;
  const int wave = tid >> 6, lane = tid & 63;
  const int col_l = lane & 15, kg = lane >> 4;
  const int r = wave >> 2;
  const int pxb = (wave & 3)*64;
  for (int i = tid; i < 3072; i += 512) {
    int co = i & 15, tap = (i>>4) % 12, ch = i/192;
    *(uint4*)&sB[((ch*12+tap)*16+co)*8] = *(const uint4*)(w2 + (long)co*1536 + ch*96 + tap*8);
  }
  if (tid < 16) {
    int dy = tid >> 2, c = tid & 3;
    *(uint4*)&sA[dy][(c<2)?c:(256+c)][0] = zero4();
  }
  long aBase[2]; int aLdsO[2]; bool aOk[2];
  #pragma unroll
  for (int u = 0; u < 2; ++u) {
    int idx = tid + u*512;
    int px = idx & 255, dy = idx >> 8;
    int iy = oy0 - 1 + dy;
    aOk[u] = (iy >= 0 && iy < 256);
    aBase[u] = ((long)(b*256 + (aOk[u]?iy:0)))*32768 + px*8;
    aLdsO[u] = (dy*260 + px + 2)*8;
  }
  uint4 pA[2];
  #pragma unroll
  for (int u=0;u<2;u++) pA[u] = aOk[u] ? *(const uint4*)(g2I + aBase[u]) : zero4();

  unsigned short* sAf = &sA[0][0][0];
  f32x4 acc[4] = {};
  for (int ch = 0; ch < 16; ++ch) {
    __syncthreads();
    #pragma unroll
    for (int u=0;u<2;u++) *(uint4*)(sAf + aLdsO[u]) = pA[u];
    __syncthreads();
    if (ch < 15) {
      #pragma unroll
      for (int u=0;u<2;u++)
        pA[u] = aOk[u] ? *(const uint4*)(g2I + aBase[u] + (ch+1)*2048) : zero4();
      __builtin_amdgcn_sched_barrier(0);
    }
    #pragma unroll
    for (int s = 0; s < 3; ++s) {
      bf16x8 bF = *(const bf16x8*)&sB[((ch*12 + s*4 + kg)*16 + col_l)*8];
      __builtin_amdgcn_s_setprio(1);
      #pragma unroll
      for (int mf = 0; mf < 4; ++mf) {
        int px = pxb + mf*16 + col_l;
        bf16x8 aF = *(const bf16x8*)&sA[r + 2 - s][px + 3 - kg][0];
        acc[mf] = MFMA16(aF, bF, acc[mf]);
      }
      __builtin_amdgcn_s_setprio(0);
    }
  }
  if (col_l < 3) {
    const int oy = oy0 + r;
    float bv = bias[col_l];
    #pragma unroll
    for (int mf = 0; mf < 4; ++mf) {
      int px = pxb + mf*16 + kg*4;
      float4 o;
      o.x = 1.f/(1.f + expf(-(acc[mf][0] + bv)));
      o.y = 1.f/(1.f + expf(-(acc[mf][1] + bv)));
      o.z = 1.f/(1.f + expf(-(acc[mf][2] + bv)));
      o.w = 1.f/(1.f + expf(-(acc[mf][3] + bv)));
      *(float4*)(y + ((long)(b*3 + col_l)*256 + oy)*256 + px) = o;
    }
  }
}

// ---------------- VQ via MFMA (unchanged) ----------------
__global__ __launch_bounds__(256, 2) void vq_mfma(
    const unsigned short* __restrict__ zeH, const unsigned short* __restrict__ zeM,
    const unsigned short* __restrict__ zeL,
    const float* __restrict__ emb, const float* __restrict__ esq,
    float* __restrict__ out_idx, float* __restrict__ zq) {
  __shared__ __align__(16) unsigned short sA[64*3*8*8];
  __shared__ __align__(16) unsigned short sB[128*3*8*8];
  __shared__ float snb[128];
  __shared__ int sidx[64];
  const int tid = threadIdx.x;
  const long n0 = (long)blockIdx.x*64;
  const int wave = tid >> 6, lane = tid & 63;
  const int col = lane & 15, kg = lane >> 4;

  #pragma unroll
  for (int j = 0; j < 6; ++j) {
    int idx = tid + j*256;
    int pl = idx >> 9, rem = idx & 511;
    int n = rem >> 3, slot = rem & 7;
    const unsigned short* src = (pl==0 ? zeH : (pl==1 ? zeM : zeL)) + (n0+n)*64 + slot*8;
    *(uint4*)&sA[((n*3 + pl)*8 + (slot ^ (n&7)))*8] = *(const uint4*)src;
  }

  const int codeT = tid >> 1, halfT = tid & 1;
  float4 pB[8];
  #pragma unroll
  for (int q = 0; q < 8; ++q)
    pB[q] = *(const float4*)(emb + (long)codeT*64 + halfT*32 + q*4);
  float pSn = (tid < 128) ? esq[tid] : 0.f;

  float best[4] = {3.4e38f,3.4e38f,3.4e38f,3.4e38f};
  int bidx[4] = {0,0,0,0};

  for (int ch = 0; ch < 4; ++ch) {
    __syncthreads();
    #pragma unroll
    for (int s4 = 0; s4 < 4; ++s4) {
      int slot = halfT*4 + s4;
      float4 lo = pB[s4*2], hi = pB[s4*2+1];
      unsigned short th[8], tm[8], tl[8];
      split3(lo.x, th[0], tm[0], tl[0]); split3(lo.y, th[1], tm[1], tl[1]);
      split3(lo.z, th[2], tm[2], tl[2]); split3(lo.w, th[3], tm[3], tl[3]);
      split3(hi.x, th[4], tm[4], tl[4]); split3(hi.y, th[5], tm[5], tl[5]);
      split3(hi.z, th[6], tm[6], tl[6]); split3(hi.w, th[7], tm[7], tl[7]);
      int base = ((codeT*3)*8 + (slot ^ (codeT&7)))*8;
      *(uint4*)&sB[base]       = *(uint4*)th;
      *(uint4*)&sB[base + 64]  = *(uint4*)tm;
      *(uint4*)&sB[base + 128] = *(uint4*)tl;
    }
    if (tid < 128) snb[tid] = pSn;
    if (ch < 3) {
      #pragma unroll
      for (int q = 0; q < 8; ++q)
        pB[q] = *(const float4*)(emb + ((long)(ch+1)*128 + codeT)*64 + halfT*32 + q*4);
      if (tid < 128) pSn = esq[(ch+1)*128 + tid];
    }
    __syncthreads();

    f32x4 acc[8] = {};
    #pragma unroll
    for (int kk = 0; kk < 2; ++kk) {
      const int nloc = wave*16 + col;
      const int slot = kk*4 + kg;
      bf16x8 aF[3];
      #pragma unroll
      for (int pl = 0; pl < 3; ++pl)
        aF[pl] = *(const bf16x8*)&sA[((nloc*3 + pl)*8 + (slot ^ (nloc&7)))*8];
      __builtin_amdgcn_s_setprio(1);
      #pragma unroll
      for (int cf = 0; cf < 8; ++cf) {
        int cl = cf*16 + col;
        int bb = ((cl*3)*8 + (slot ^ (cl&7)))*8;
        bf16x8 b0 = *(const bf16x8*)&sB[bb];
        bf16x8 b1 = *(const bf16x8*)&sB[bb + 64];
        bf16x8 b2 = *(const bf16x8*)&sB[bb + 128];
        f32x4 a = acc[cf];
        a = MFMA16(aF[0], b0, a);
        a = MFMA16(aF[0], b1, a);
        a = MFMA16(aF[1], b0, a);
        a = MFMA16(aF[0], b2, a);
        a = MFMA16(aF[2], b0, a);
        a = MFMA16(aF[1], b1, a);
        acc[cf] = a;
      }
      __builtin_amdgcn_s_setprio(0);
    }
    #pragma unroll
    for (int cf = 0; cf < 8; ++cf) {
      float sv = snb[cf*16 + col];
      int code = ch*128 + cf*16 + col;
      #pragma unroll
      for (int j = 0; j < 4; ++j) {
        float s = sv - 2.f*acc[cf][j];
        if (s < best[j]) { best[j] = s; bidx[j] = code; }
      }
    }
  }

  #pragma unroll
  for (int j = 0; j < 4; ++j) {
    float b = best[j]; int ii = bidx[j];
    #pragma unroll
    for (int off = 1; off < 16; off <<= 1) {
      float ob = __shfl_xor(b, off);
      int oi = __shfl_xor(ii, off);
      if (ob < b || (ob == b && oi < ii)) { b = ob; ii = oi; }
    }
    if (col == 0) sidx[wave*16 + kg*4 + j] = ii;
  }
  __syncthreads();
  if (tid < 64) out_idx[n0 + tid] = (float)sidx[tid];
  #pragma unroll
  for (int j = 0; j < 4; ++j) {
    int t = tid + j*256;
    int row = t >> 4, q = t & 15;
    float4 v = *(const float4*)(emb + (long)sidx[row]*64 + q*4);
    *(float4*)(zq + (n0 + row)*64 + q*4) = v;
  }
}

// ---------------- launch ----------------
extern "C" void kernel_launch(void* const* d_in, const int* in_sizes, int n_in,
                              void* d_out, int out_size, void* d_ws, size_t ws_size,
                              hipStream_t stream) {
  const float* x   = (const float*)d_in[0];
  const float* c1w = (const float*)d_in[1];  const float* c1b = (const float*)d_in[2];
  const float* c2w = (const float*)d_in[3];  const float* c2b = (const float*)d_in[4];
  const float* c3w = (const float*)d_in[5];  const float* c3b = (const float*)d_in[6];
  const float* emb = (const float*)d_in[7];
  const float* d1w = (const float*)d_in[8];  const float* d1b = (const float*)d_in[9];
  const float* d2w = (const float*)d_in[10]; const float* d2b = (const float*)d_in[11];
  const float* d3w = (const float*)d_in[12]; const float* d3b = (const float*)d_in[13];
  float* out = (float*)d_out;

  float* xrec = out;
  float* oidx = out + 3145728;
  float* zq   = out + 3211264;

  const long XB  = 196608;   // 3*256*256
  const long ZEB = 262144;   // ze elems per batch
  const long H2B = 1572864;  // per-batch h2I stride in shorts

  const size_t NEEDED   = 112273408ULL;   // 4-batch tier
  const size_t NEEDED8  = 170994688ULL;   // 8-batch decoder tier
  const size_t NEEDED16 = 288434176ULL;   // 16-batch single-pass encoder tier
  if (ws_size < NEEDED) return;
  const bool use16 = (ws_size >= NEEDED16);
  const bool use8  = (ws_size >= NEEDED8);
  char* wsb = (char*)d_ws;

  unsigned short* zeL = (unsigned short*)out;   // xrec region: dead until deconv3

  if (use16) {
    // ---- 16-batch single-pass encoder ----
    unsigned short* h1  = (unsigned short*)wsb;                  // 201.3MB, PS1=33554432
    unsigned short* h2I = (unsigned short*)(wsb + 201326592);    // 50.3MB
    unsigned short* zeH = (unsigned short*)(wsb + 251658240);
    unsigned short* zeM = (unsigned short*)(wsb + 268435456);
    char* W = wsb + 285212672;
    float* w2c1          = (float*)(W);
    unsigned short* w2c2 = (unsigned short*)(W + 24576);
    unsigned short* w2c3 = (unsigned short*)(W + 1597440);
    unsigned short* w2d1 = (unsigned short*)(W + 2383872);
    unsigned short* w2d2 = (unsigned short*)(W + 2646016);
    unsigned short* w2d3 = (unsigned short*)(W + 3170304);
    float* esq           = (float*)(W + 3219456);

    wprep_all<<<3066, 256, 0, stream>>>(c1w, w2c1, c2w, w2c2, c3w, w2c3,
                                        d1w, w2d1, d2w, w2d2, d3w, w2d3, emb, esq);
    conv1_split<<<dim3(16,16,32), 256, 0, stream>>>(x, w2c1, c1b, h1, 33554432L);
    conv2_mfma<<<dim3(64,2,16), 256, 0, stream>>>(h1, 33554432L, w2c2, c2b, h2I);
    conv3_mfma<<<dim3(64,1,16), 256, 0, stream>>>(h2I, w2c3, c3b, zeH, zeM, zeL);
    vq_mfma<<<1024, 256, 0, stream>>>(zeH, zeM, zeL, emb, esq, oidx, zq);

    // decoder: 8-batch x2, in dead h1 region
    unsigned short* g2g = (unsigned short*)wsb;                 // 134MB
    unsigned short* g1g = (unsigned short*)(wsb + 134217728);   // 34MB
    for (int g = 0; g < 2; ++g) {
      deconv_mfma<64, 64, 0 ><<<dim3(64, 2, 8), 256, 0, stream>>>(
          (const void*)(zq + (long)g*8*ZEB), w2d1, d1b, g1g);
      deconv_mfma<128,128,1 ><<<dim3(128,2,8), 512, 0, stream>>>(
          (const void*)g1g, w2d2, d2b, g2g);
      deconv3_mfma<<<dim3(128,8), 512, 0, stream>>>(
          g2g, w2d3, d3b, xrec + (long)g*8*XB);
    }
    return;
  }

  // ---- fallback tiers (r15 layout) ----
  unsigned short* h1grp = (unsigned short*)wsb;
  unsigned short* h2I   = (unsigned short*)(wsb + 67108864);
  unsigned short* zeH = (unsigned short*)(wsb + 92274688);
  unsigned short* zeM = (unsigned short*)(wsb + 100663296);
  char* W = use8 ? (wsb + 167772160) : (wsb + 109051904);
  float* w2c1          = (float*)(W);
  unsigned short* w2c2 = (unsigned short*)(W + 24576);
  unsigned short* w2c3 = (unsigned short*)(W + 1597440);
  unsigned short* w2d1 = (unsigned short*)(W + 2383872);
  unsigned short* w2d2 = (unsigned short*)(W + 2646016);
  unsigned short* w2d3 = (unsigned short*)(W + 3170304);
  float* esq           = (float*)(W + 3219456);

  wprep_all<<<3066, 256, 0, stream>>>(c1w, w2c1, c2w, w2c2, c3w, w2c3,
                                      d1w, w2d1, d2w, w2d2, d3w, w2d3, emb, esq);

  const long PS1 = 8388608;
  for (int g = 0; g < 4; ++g) {
    conv1_split<<<dim3(16,16,8), 256, 0, stream>>>(
        x + (long)g*4*XB, w2c1, c1b, h1grp, PS1);
    conv2_mfma<<<dim3(64,2,4), 256, 0, stream>>>(
        h1grp, PS1, w2c2, c2b, h2I + (long)(g&1)*4*H2B);
    if (g & 1) {
      long zo = (long)(g>>1)*8*ZEB;
      conv3_mfma<<<dim3(64,1,8), 256, 0, stream>>>(
          h2I, w2c3, c3b, zeH + zo, zeM + zo, zeL + zo);
    }
  }
  vq_mfma<<<1024, 256, 0, stream>>>(zeH, zeM, zeL, emb, esq, oidx, zq);

  if (use8) {
    unsigned short* g2g = (unsigned short*)wsb;
    unsigned short* g1g = (unsigned short*)(wsb + 134217728);
    for (int g = 0; g < 2; ++g) {
      deconv_mfma<64, 64, 0 ><<<dim3(64, 2, 8), 256, 0, stream>>>(
          (const void*)(zq + (long)g*8*ZEB), w2d1, d1b, g1g);
      deconv_mfma<128,128,1 ><<<dim3(128,2,8), 512, 0, stream>>>(
          (const void*)g1g, w2d2, d2b, g2g);
      deconv3_mfma<<<dim3(128,8), 512, 0, stream>>>(
          g2g, w2d3, d3b, xrec + (long)g*8*XB);
    }
  } else {
    unsigned short* g2g = (unsigned short*)wsb;
    unsigned short* g1g = (unsigned short*)(wsb + 67108864);
    for (int g = 0; g < 4; ++g) {
      deconv_mfma<64, 64, 0 ><<<dim3(64, 2, 4), 256, 0, stream>>>(
          (const void*)(zq + (long)g*4*ZEB), w2d1, d1b, g1g);
      deconv_mfma<128,128,1 ><<<dim3(128,2,4), 512, 0, stream>>>(
          (const void*)g1g, w2d2, d2b, g2g);
      deconv3_mfma<<<dim3(128,4), 512, 0, stream>>>(
          g2g, w2d3, d3b, xrec + (long)g*4*XB);
    }
  }
}

// Round 17
// 668.534 us; speedup vs baseline: 3.4157x; 1.0035x over previous
//
#include <hip/hip_runtime.h>
#include <hip/hip_bf16.h>

#define DEV __device__ __forceinline__

typedef __attribute__((ext_vector_type(8))) short bf16x8;
typedef __attribute__((ext_vector_type(4))) float f32x4;
typedef __attribute__((ext_vector_type(4))) unsigned short u16x4;

#define MFMA16(a,b,c) __builtin_amdgcn_mfma_f32_16x16x32_bf16(a,b,c,0,0,0)

DEV unsigned short bfbits(float v){ __hip_bfloat16 h = __float2bfloat16(v); return *(unsigned short*)&h; }
DEV float bf2f(unsigned short u){ __hip_bfloat16 h = *(__hip_bfloat16*)&u; return __bfloat162float(h); }
DEV void split3(float v, unsigned short& h, unsigned short& m, unsigned short& l) {
  h = bfbits(v);        float r  = v - bf2f(h);
  m = bfbits(r);        float r2 = r - bf2f(m);
  l = bfbits(r2);
}
DEV uint4 zero4(){ uint4 z; z.x=0; z.y=0; z.z=0; z.w=0; return z; }
DEV void gload_lds16(const void* g, void* l) {
  __builtin_amdgcn_global_load_lds(
      (const __attribute__((address_space(1))) void*)g,
      (__attribute__((address_space(3))) void*)l, 16, 0, 0);
}

// ---------------- fused weight prep (one dispatch, 3066 blocks) ----------------
DEV void prep_deconv_img(int i, int CI, const float* __restrict__ w, unsigned short* __restrict__ w2) {
  const int nch = CI/16;
  int cil = i & 7, s = (i >> 3) & 7, co = (i >> 6) & 127, f = (i >> 13) & 1;
  int rest = i >> 14;
  int ch = rest % nch, e = rest / nch;
  int k = ch*64 + s*8 + cil;
  int ci = (k & 15) | ((k >> 6) << 4);
  int tap = (k >> 4) & 3, a = tap >> 1, b = tap & 1;
  float v = w[ (((long)ci*128 + co)*4 + (2*a+1-e))*4 + (2*b+1-f) ];
  w2[(long)(e*nch + ch)*16384 + ((long)(f*128 + co))*64 + ((s ^ (co&7))*8) + cil] = bfbits(v);
}
__global__ __launch_bounds__(256) void wprep_all(
    const float* __restrict__ c1w, float* __restrict__ w2c1,
    const float* __restrict__ c2w, unsigned short* __restrict__ w2c2,
    const float* __restrict__ c3w, unsigned short* __restrict__ w2c3,
    const float* __restrict__ d1w, unsigned short* __restrict__ w2d1,
    const float* __restrict__ d2w, unsigned short* __restrict__ w2d2,
    const float* __restrict__ d3w, unsigned short* __restrict__ w2d3,
    const float* __restrict__ emb, float* __restrict__ esq) {
  const int bx = blockIdx.x, t = threadIdx.x;
  if (bx < 24) {                         // conv1 transpose: 6144
    int i = bx*256 + t;
    if (i < 6144) {
      int tap = i & 15, ci = (i>>4) % 3, co = i / 48;
      w2c1[((long)ci*16 + tap)*128 + co] = c1w[i];
    }
  } else if (bx < 1048) {                // conv2 prep -> LDS-image layout
    int i = (bx-24)*256 + t;             // 0..262143
    int cil = i & 7, s = (i>>3) & 15, co = (i>>7) & 63;
    int ch = (i>>13) & 15, cog = i >> 17;
    int co_g = cog*64 + co, ci = ch*8 + cil, ky = s >> 2, kx = s & 3;
    float v = c2w[(((long)co_g*128 + ci)*4 + ky)*4 + kx];
    unsigned short h,m,l; split3(v,h,m,l);
    long base = (long)(cog*16 + ch)*24576 + ((long)co*16 + (s ^ (co&15)))*8 + cil;
    w2c2[base] = h; w2c2[base + 8192] = m; w2c2[base + 16384] = l;
  } else if (bx < 1432) {                // conv3 prep -> LDS-image layout: 98304
    int i = (bx-1048)*256 + t;
    int k = i % 1536, co = i / 1536;
    int ch = k / 96, rem = k % 96;
    int tap = rem >> 3, cil = rem & 7;
    int ci = ch*8 + cil, ky = tap >> 2, kx = tap & 3;
    float v = (kx < 3) ? c3w[(((long)co*128 + ci)*3 + ky)*3 + kx] : 0.f;
    unsigned short h,m,l; split3(v,h,m,l);
    long base = (long)ch*24576 + ((long)co*16 + (tap ^ (co&15)))*8 + cil;
    w2c3[base] = h; w2c3[base + 8192] = m; w2c3[base + 16384] = l;
  } else if (bx < 1944) {                // deconv1 image: 131072 (CI=64)
    prep_deconv_img((bx-1432)*256 + t, 64, d1w, w2d1);
  } else if (bx < 2968) {                // deconv2 image: 262144 (CI=128)
    prep_deconv_img((bx-1944)*256 + t, 128, d2w, w2d2);
  } else if (bx < 3064) {                // deconv3: 24576
    int i = (bx-2968)*256 + t;
    if (i < 24576) {
      int k = i % 1536, co = i / 1536;
      int ch = k / 96, rem = k % 96;
      int tap = rem >> 3, cil = rem & 7;
      int ci = ch*8 + cil, ky = tap >> 2, kx = tap & 3;
      float v = (co < 3 && kx < 3) ? d3w[(((long)ci*3 + co)*3 + ky)*3 + kx] : 0.f;
      w2d3[i] = bfbits(v);
    }
  } else {                               // esq: 512 codes
    int code = (bx-3064)*256 + t;
    if (code < 512) {
      const float4* ev = (const float4*)(emb + (long)code*64);
      float s = 0.f;
      #pragma unroll
      for (int q=0;q<16;q++){ float4 e4 = ev[q];
        s += e4.x*e4.x + e4.y*e4.y + e4.z*e4.z + e4.w*e4.w; }
      esq[code] = s;
    }
  }
}

// ---------------- conv1: f32 direct, out 3 bf16 planes INTERLEAVED ----------------
__global__ __launch_bounds__(256) void conv1_split(
    const float* __restrict__ x, const float* __restrict__ w2,
    const float* __restrict__ bias, unsigned short* __restrict__ h1, long PS1) {
  __shared__ __align__(16) float sIn[3][18][20];
  __shared__ __align__(16) float sW[3*16*64];
  const int tid = threadIdx.x;
  const int b = blockIdx.z >> 1, cog = blockIdx.z & 1;
  const int co0 = cog*64;
  const int oy0 = blockIdx.y*8, ox0 = blockIdx.x*8;
  const int cg2 = tid >> 5;
  const int pg2 = tid & 31;
  const int r = pg2 >> 2, pxp = (pg2 & 3)*2;
  float acc[8][2];
  #pragma unroll
  for (int c=0;c<8;c++){ float bv = bias[co0 + cg2*8 + c];
    acc[c][0]=bv; acc[c][1]=bv; }
  const float* xb = x + (long)b*3*256*256;
  const int iy0 = 2*oy0 - 1, ix0 = 2*ox0 - 1;
  for (int t=tid; t<3*18*18; t+=256) {
    int xx = t%18, yy=(t/18)%18, ci=t/324;
    int gy = iy0+yy, gx = ix0+xx;
    float v = 0.f;
    if (gy>=0 && gy<256 && gx>=0 && gx<256) v = xb[((long)ci*256+gy)*256+gx];
    sIn[ci][yy][xx] = v;
  }
  for (int t=tid; t<3*16*64; t+=256) {
    sW[t] = w2[(long)(t>>6)*128 + co0 + (t&63)];
  }
  __syncthreads();
  for (int ci=0; ci<3; ci++) {
    #pragma unroll
    for (int ky=0;ky<4;ky++)
    #pragma unroll
    for (int kx=0;kx<4;kx++) {
      const float* wp = &sW[(ci*16 + ky*4+kx)*64 + cg2*8];
      float4 w0 = *(const float4*)wp;
      float4 w1 = *(const float4*)(wp+4);
      const int yy = 2*r + ky;
      #pragma unroll
      for (int p=0;p<2;p++) {
        float iv = sIn[ci][yy][2*(pxp+p)+kx];
        acc[0][p] += w0.x*iv; acc[1][p] += w0.y*iv;
        acc[2][p] += w0.z*iv; acc[3][p] += w0.w*iv;
        acc[4][p] += w1.x*iv; acc[5][p] += w1.y*iv;
        acc[6][p] += w1.z*iv; acc[7][p] += w1.w*iv;
      }
    }
  }
  const int chg = cog*8 + cg2;
  #pragma unroll
  for (int p=0;p<2;p++) {
    unsigned short th[8], tm[8], tl[8];
    #pragma unroll
    for (int c=0;c<8;c++) {
      float v = fmaxf(acc[c][p], 0.f);
      split3(v, th[c], tm[c], tl[c]);
    }
    long base = (((long)(b*128 + oy0+r)*16 + chg)*128 + ox0+pxp+p)*8;
    *(uint4*)(h1 + base)          = *(uint4*)th;
    *(uint4*)(h1 + PS1 + base)    = *(uint4*)tm;
    *(uint4*)(h1 + 2*PS1 + base)  = *(uint4*)tl;
  }
}

// ---------------- conv2: MFMA 6-term split; post-barrier A prefetch ----------
__global__ __launch_bounds__(256, 2) void conv2_mfma(
    const unsigned short* __restrict__ h1, long PS1,
    const unsigned short* __restrict__ w2,   // LDS-image: [cog][ch][24576 shorts]
    const float* __restrict__ bias,
    unsigned short* __restrict__ h2I) {      // [b][row64][pl3][ch16][px64][8]
  __shared__ __align__(16) unsigned short sA[3][4][130][8];
  __shared__ __align__(16) unsigned short sB[24576];
  const int tid = threadIdx.x;
  const int oy = blockIdx.x, cog = blockIdx.y, b = blockIdx.z;
  const int wave = tid >> 6, lane = tid & 63;
  const int wr = wave >> 1, wc = wave & 1;
  const int col_l = lane & 15, kg = lane >> 4;
  const int iy0 = 2*oy - 1;
  f32x4 acc[2][2] = {};
  unsigned short* sAf = &sA[0][0][0][0];
  const unsigned short* bsrc = w2 + (long)cog*16*24576;

  long aOff[6]; int aLdsO[6]; bool aOk[6];
  #pragma unroll
  for (int j = 0; j < 6; ++j) {
    int idx = tid + j*256;
    int px = idx & 127, rr = (idx >> 7) & 3, pl = idx >> 9;
    int iy = iy0 + rr;
    aOk[j] = (iy >= 0 && iy < 128);
    aOff[j] = (long)pl*PS1 + (long)(b*128 + (aOk[j]?iy:0))*16384 + px*8;
    aLdsO[j] = ((pl*4 + rr)*130 + px + 1)*8;
  }
  uint4 pA[6];
  #pragma unroll
  for (int j=0;j<6;j++)  pA[j] = aOk[j] ? *(const uint4*)(h1 + aOff[j]) : zero4();

  if (tid < 24) {
    int pl = tid>>3, rr=(tid>>1)&3, c=tid&1;
    *(uint4*)&sA[pl][rr][c?129:0][0] = zero4();
  }

  for (int ch = 0; ch < 16; ++ch) {
    __syncthreads();
    #pragma unroll
    for (int j=0;j<6;j++)  *(uint4*)(sAf + aLdsO[j]) = pA[j];
    #pragma unroll
    for (int j = 0; j < 12; ++j) {
      int blk = wave*12 + j;
      gload_lds16(bsrc + (long)ch*24576 + blk*512 + lane*8, &sB[blk*512]);
    }
    __syncthreads();
    if (ch < 15) {
      #pragma unroll
      for (int j=0;j<6;j++)  pA[j] = aOk[j] ? *(const uint4*)(h1 + aOff[j] + (ch+1)*1024) : zero4();
      __builtin_amdgcn_sched_barrier(0);
    }
    #pragma unroll
    for (int s = 0; s < 4; ++s) {        // s = ky
      bf16x8 aF[2][3]; bf16x8 bF[2][3];
      const int tap = s*4 + kg;
      #pragma unroll
      for (int mf = 0; mf < 2; ++mf) {
        int ox = wr*32 + mf*16 + col_l;
        #pragma unroll
        for (int pl = 0; pl < 3; ++pl)
          aF[mf][pl] = *(const bf16x8*)&sA[pl][s][2*ox + kg][0];
      }
      #pragma unroll
      for (int nf = 0; nf < 2; ++nf) {
        int co = wc*32 + nf*16 + col_l;
        int ba = (co*16 + (tap ^ (co&15)))*8;
        bF[nf][0] = *(const bf16x8*)&sB[ba];
        bF[nf][1] = *(const bf16x8*)&sB[ba + 8192];
        bF[nf][2] = *(const bf16x8*)&sB[ba + 16384];
      }
      __builtin_amdgcn_s_setprio(1);
      #pragma unroll
      for (int mf = 0; mf < 2; ++mf)
      #pragma unroll
      for (int nf = 0; nf < 2; ++nf) {
        f32x4 a = acc[mf][nf];
        a = MFMA16(aF[mf][0], bF[nf][0], a);
        a = MFMA16(aF[mf][0], bF[nf][1], a);
        a = MFMA16(aF[mf][1], bF[nf][0], a);
        a = MFMA16(aF[mf][0], bF[nf][2], a);
        a = MFMA16(aF[mf][2], bF[nf][0], a);
        a = MFMA16(aF[mf][1], bF[nf][1], a);
        acc[mf][nf] = a;
      }
      __builtin_amdgcn_s_setprio(0);
    }
  }
  // epilogue: acc -> sB[pl][co64][72pad] -> interleaved h2I
  __syncthreads();
  #pragma unroll
  for (int nf = 0; nf < 2; ++nf) {
    int co = wc*32 + nf*16 + col_l;
    float bv = bias[cog*64 + co];
    #pragma unroll
    for (int mf = 0; mf < 2; ++mf) {
      int px0 = wr*32 + mf*16 + kg*4;
      u16x4 oh, om, ol;
      #pragma unroll
      for (int r = 0; r < 4; ++r) {
        float v = fmaxf(acc[mf][nf][r] + bv, 0.f);
        unsigned short h,m,l; split3(v,h,m,l);
        oh[r]=h; om[r]=m; ol[r]=l;
      }
      *(u16x4*)&sB[(0*64 + co)*72 + px0] = oh;
      *(u16x4*)&sB[(1*64 + co)*72 + px0] = om;
      *(u16x4*)&sB[(2*64 + co)*72 + px0] = ol;
    }
  }
  __syncthreads();
  #pragma unroll
  for (int j = 0; j < 6; ++j) {
    int idx = tid + j*256;
    int pl = idx >> 9, ch = (idx >> 6) & 7, px = idx & 63;
    unsigned short tmp[8];
    #pragma unroll
    for (int c = 0; c < 8; ++c) tmp[c] = sB[(pl*64 + ch*8 + c)*72 + px];
    *(uint4*)(h2I + ((((long)(b*64 + oy)*3 + pl)*16 + cog*8 + ch)*64 + px)*8) = *(uint4*)tmp;
  }
}

// ---------------- conv3: MFMA 6-term split; A+B via global_load_lds ----------------
__global__ __launch_bounds__(256, 2) void conv3_mfma(
    const unsigned short* __restrict__ h2I,  // [b][row64][pl3][ch16][px64][8]
    const unsigned short* __restrict__ w2,   // LDS-image: [ch][24576 shorts]
    const float* __restrict__ bias,
    unsigned short* __restrict__ zeH, unsigned short* __restrict__ zeM,
    unsigned short* __restrict__ zeL) {
  __shared__ __align__(16) unsigned short sA3[3][3][68][8];
  __shared__ __align__(16) unsigned short sB[24576];
  const int tid = threadIdx.x;
  const int oy = blockIdx.x, b = blockIdx.z;
  const int wave = tid >> 6, lane = tid & 63;
  const int wr = wave >> 1, wc = wave & 1;
  const int col_l = lane & 15, kg = lane >> 4;
  f32x4 acc[2][2] = {};
  if (tid < 27) {
    int row = tid/3, c = tid%3;
    int pl = row/3, rr = row%3;
    *(uint4*)&sA3[pl][rr][(c==0)?0:(64+c)][0] = zero4();
  }
  if (oy == 0 && tid < 192) {
    int pl = tid >> 6, px = tid & 63;
    *(uint4*)&sA3[pl][0][px+1][0] = zero4();
  }
  if (oy == 63 && tid < 192) {
    int pl = tid >> 6, px = tid & 63;
    *(uint4*)&sA3[pl][2][px+1][0] = zero4();
  }

  for (int ch = 0; ch < 16; ++ch) {
    __syncthreads();
    #pragma unroll
    for (int j = 0; j < 3; ++j) {
      int row = wave*3 + j;
      if (row < 9) {
        int pl = row/3, rr = row%3;
        int iy = oy + rr - 1;
        if (iy >= 0 && iy < 64)
          gload_lds16(h2I + ((((long)(b*64 + iy)*3 + pl)*16 + ch)*64)*8 + lane*8,
                      &sA3[pl][rr][1][0]);
      }
    }
    #pragma unroll
    for (int j = 0; j < 12; ++j) {
      int blk = wave*12 + j;
      gload_lds16(w2 + (long)ch*24576 + blk*512 + lane*8, &sB[blk*512]);
    }
    __syncthreads();
    #pragma unroll
    for (int s = 0; s < 3; ++s) {
      bf16x8 aF[2][3]; bf16x8 bF[2][3];
      const int tap = s*4 + kg;
      #pragma unroll
      for (int mf = 0; mf < 2; ++mf) {
        int ox = wr*32 + mf*16 + col_l;
        #pragma unroll
        for (int pl = 0; pl < 3; ++pl)
          aF[mf][pl] = *(const bf16x8*)&sA3[pl][s][ox + kg][0];
      }
      #pragma unroll
      for (int nf = 0; nf < 2; ++nf) {
        int co = wc*32 + nf*16 + col_l;
        int ba = (co*16 + (tap ^ (co&15)))*8;
        bF[nf][0] = *(const bf16x8*)&sB[ba];
        bF[nf][1] = *(const bf16x8*)&sB[ba + 8192];
        bF[nf][2] = *(const bf16x8*)&sB[ba + 16384];
      }
      __builtin_amdgcn_s_setprio(1);
      #pragma unroll
      for (int mf = 0; mf < 2; ++mf)
      #pragma unroll
      for (int nf = 0; nf < 2; ++nf) {
        f32x4 a = acc[mf][nf];
        a = MFMA16(aF[mf][0], bF[nf][0], a);
        a = MFMA16(aF[mf][0], bF[nf][1], a);
        a = MFMA16(aF[mf][1], bF[nf][0], a);
        a = MFMA16(aF[mf][0], bF[nf][2], a);
        a = MFMA16(aF[mf][2], bF[nf][0], a);
        a = MFMA16(aF[mf][1], bF[nf][1], a);
        acc[mf][nf] = a;
      }
      __builtin_amdgcn_s_setprio(0);
    }
  }
  __syncthreads();
  #pragma unroll
  for (int nf = 0; nf < 2; ++nf) {
    int co = wc*32 + nf*16 + col_l;
    float bv = bias[co];
    #pragma unroll
    for (int mf = 0; mf < 2; ++mf) {
      int px0 = wr*32 + mf*16 + kg*4;
      u16x4 oh, om, ol;
      #pragma unroll
      for (int r = 0; r < 4; ++r) {
        float v = acc[mf][nf][r] + bv;
        unsigned short h,m,l; split3(v,h,m,l);
        oh[r]=h; om[r]=m; ol[r]=l;
      }
      *(u16x4*)&sB[(0*64 + co)*72 + px0] = oh;
      *(u16x4*)&sB[(1*64 + co)*72 + px0] = om;
      *(u16x4*)&sB[(2*64 + co)*72 + px0] = ol;
    }
  }
  __syncthreads();
  #pragma unroll
  for (int j = 0; j < 6; ++j) {
    int idx = tid + j*256;
    int pl = idx >> 9, co_l = (idx >> 3) & 63, q = idx & 7;
    uint4 v = *(const uint4*)&sB[(pl*64 + co_l)*72 + q*8];
    unsigned short* dst = (pl==0) ? zeH : ((pl==1) ? zeM : zeL);
    *(uint4*)(dst + ((long)(b*64 + co_l)*64 + oy)*64 + q*8) = v;
  }
}

// ---------------- deconv1: generic ConvTranspose2d s2k4p1 (TX=64, f32 in) ----------
template<int TX, int MODE>
struct SmemD {
  union {
    struct { __align__(16) unsigned short In[2][TX+2][24];
             __align__(16) unsigned short W[2*128*64]; } o;
    struct { __align__(16) unsigned short In[2][TX+2][16];
             __align__(16) unsigned short W[2*128*64]; } v;
    __align__(16) unsigned short Out[128][136];
  };
};

template<int CIN, int TX, int MODE>
__global__ __launch_bounds__(TX*4, (TX==64)?3:4) void deconv_mfma(
    const void* __restrict__ xin, const unsigned short* __restrict__ w2,
    const float* __restrict__ bias, unsigned short* __restrict__ yI) {
  constexpr int NTHR = TX*4;
  constexpr int NWAVE = NTHR/64;
  constexpr int NWG  = 32/NWAVE;
  __shared__ SmemD<TX,MODE> sm;
  unsigned short* Wb = MODE ? &sm.v.W[0] : &sm.o.W[0];

  const int tid = threadIdx.x;
  const int ty = blockIdx.x, e = blockIdx.y, b = blockIdx.z;
  const int wave = tid >> 6, lane = tid & 63;
  const int wc = wave & 1, wr = wave >> 1;
  const int f = (wr*64) / TX;
  const int tx_base = (wr*64) & (TX-1);
  const int col_l = lane & 15, kg = lane >> 4;
  const unsigned short* wsrc = w2 + (long)e*(CIN/16)*16384;

  constexpr int TPR = NTHR/32;
  const int rowid = tid / TPR, liO = tid % TPR;
  const int sci = rowid >> 1, srr = rowid & 1;
  float4 pLo, pHi; uint4 pIn;
  long aBase = 0; bool aOk = false;
  int pxV = 0, halfV = 0, rrV = 0;
  if (MODE == 0) {
    int iy = ty + e - 1 + srr;
    aOk = (iy >= 0 && iy < TX);
    aBase = ((long)b*CIN + sci)*TX*TX + (long)(aOk?iy:0)*TX + liO*8;
    if (aOk) { const float4* s4 = (const float4*)((const float*)xin + aBase);
               pLo = s4[0]; pHi = s4[1]; }
  } else {
    halfV = tid & 1; pxV = (tid >> 1) & (TX-1); rrV = tid >> 8;
    int iy = ty + e - 1 + rrV;
    aOk = (iy >= 0 && iy < TX);
    aBase = ((long)b*TX + (aOk?iy:0))*((long)(CIN/8)*TX*8) + (long)halfV*TX*8 + pxV*8;
    pIn = aOk ? *(const uint4*)((const unsigned short*)xin + aBase) : zero4();
  }

  if (MODE == 0) {
    if (tid < 64) {
      int rr = tid & 1, cc = ((tid>>1)&1) ? TX+1 : 0, ci = tid >> 2;
      sm.o.In[rr][cc][ci] = 0;
    }
  } else {
    if (tid < 8) {
      int rr = tid & 1, c = (tid>>1)&1, hf = (tid>>2)&1;
      *(uint4*)&sm.v.In[rr][c?TX+1:0][hf*8] = zero4();
    }
  }

  f32x4 acc[4][4] = {};
  for (int ch = 0; ch < CIN/16; ++ch) {
    __syncthreads();
    if (MODE == 0) {
      unsigned short vals[8];
      if (aOk) {
        float4 lo = pLo, hi = pHi;
        vals[0]=bfbits(lo.x); vals[1]=bfbits(lo.y); vals[2]=bfbits(lo.z); vals[3]=bfbits(lo.w);
        vals[4]=bfbits(hi.x); vals[5]=bfbits(hi.y); vals[6]=bfbits(hi.z); vals[7]=bfbits(hi.w);
      } else {
        #pragma unroll
        for (int j=0;j<8;j++) vals[j] = 0;
      }
      #pragma unroll
      for (int j=0;j<8;j++) {
        int jj = (j + liO) & 7;
        sm.o.In[srr][1 + liO*8 + jj][sci] = vals[jj];
      }
    } else {
      *(uint4*)&sm.v.In[rrV][pxV+1][halfV*8] = pIn;
    }
    #pragma unroll
    for (int j = 0; j < NWG; ++j) {
      int blk = wave*NWG + j;
      gload_lds16(wsrc + (long)ch*16384 + blk*512 + lane*8, Wb + blk*512);
    }
    __syncthreads();
    if (ch + 1 < CIN/16) {
      if (MODE == 0) {
        if (aOk) { const float4* s4 = (const float4*)((const float*)xin + aBase + (long)(ch+1)*16*TX*TX);
                   pLo = s4[0]; pHi = s4[1]; }
      } else {
        pIn = aOk ? *(const uint4*)((const unsigned short*)xin + aBase + (ch+1)*2*TX*8) : zero4();
      }
      __builtin_amdgcn_sched_barrier(0);
    }
    #pragma unroll
    for (int kk = 0; kk < 2; ++kk) {
      bf16x8 aF[4];
      const int tap = kk*2 + (kg >> 1), a = tap >> 1, bb = tap & 1;
      #pragma unroll
      for (int mf = 0; mf < 4; ++mf) {
        int tx = tx_base + mf*16 + col_l;
        if (MODE == 0) aF[mf] = *(const bf16x8*)&sm.o.In[1-a][tx + 1 + f - bb][(kg&1)*8];
        else           aF[mf] = *(const bf16x8*)&sm.v.In[1-a][tx + 1 + f - bb][(kg&1)*8];
      }
      const int slot = kk*4 + kg;
      __builtin_amdgcn_s_setprio(1);
      #pragma unroll
      for (int nf = 0; nf < 4; ++nf) {
        int co_l = nf*16 + col_l;
        bf16x8 bF = *(const bf16x8*)(Wb + (f*128 + wc*64 + co_l)*64 + (slot ^ (co_l & 7))*8);
        #pragma unroll
        for (int mf = 0; mf < 4; ++mf)
          acc[mf][nf] = MFMA16(aF[mf], bF, acc[mf][nf]);
      }
      __builtin_amdgcn_s_setprio(0);
    }
  }

  // epilogue
  __syncthreads();
  float bv[4];
  #pragma unroll
  for (int nf = 0; nf < 4; ++nf) bv[nf] = bias[wc*64 + nf*16 + col_l];
  const int oy = 2*ty + e;
  if constexpr (TX == 64) {
    #pragma unroll
    for (int mf = 0; mf < 4; ++mf)
    #pragma unroll
    for (int nf = 0; nf < 4; ++nf) {
      int co = wc*64 + nf*16 + col_l;
      #pragma unroll
      for (int r = 0; r < 4; ++r) {
        int tx = tx_base + mf*16 + kg*4 + r;
        float v = fmaxf(acc[mf][nf][r] + bv[nf], 0.f);
        int ox = 2*tx + f;
        sm.Out[ox][co ^ (((ox>>3)&7)<<3)] = bfbits(v);
      }
    }
    __syncthreads();
    #pragma unroll
    for (int j = 0; j < 8; ++j) {
      int i = tid + j*NTHR;
      int px = i & 127, chn = i >> 7;
      uint4 vv = *(const uint4*)&sm.Out[px][(chn*8) ^ (((px>>3)&7)<<3)];
      *(uint4*)(yI + ((((long)b*128 + oy)*16 + chn)*128 + px)*8) = vv;
    }
  } else {
    const int myp = wr & 1;
    #pragma unroll
    for (int p = 0; p < 2; ++p) {
      if (myp == p) {
        #pragma unroll
        for (int mf = 0; mf < 4; ++mf)
        #pragma unroll
        for (int nf = 0; nf < 4; ++nf) {
          int co = wc*64 + nf*16 + col_l;
          #pragma unroll
          for (int r = 0; r < 4; ++r) {
            int tx = tx_base + mf*16 + kg*4 + r;
            float v = fmaxf(acc[mf][nf][r] + bv[nf], 0.f);
            int ox = 2*tx + f;
            sm.Out[ox & 127][co ^ (((ox>>3)&7)<<3)] = bfbits(v);
          }
        }
      }
      __syncthreads();
      #pragma unroll
      for (int j = 0; j < 4; ++j) {
        int i = tid + j*NTHR;
        int px = i & 127, chn = i >> 7;
        uint4 vv = *(const uint4*)&sm.Out[px][(chn*8) ^ (((px>>3)&7)<<3)];
        int pxg = p*128 + px;
        *(uint4*)(yI + ((((long)b*256 + oy)*16 + chn)*256 + pxg)*8) = vv;
      }
      if (p == 0) __syncthreads();
    }
  }
}

// ---------------- deconv2: counted-vmcnt pipelined (CIN=128, TX=128, bf16 interleaved) -----
__global__ __launch_bounds__(512, 4) void deconv2_pipe(
    const unsigned short* __restrict__ xin,  // g1 interleaved [b][row128][ch16][px128][8]
    const unsigned short* __restrict__ w2,   // [e][ch8][16384]
    const float* __restrict__ bias, unsigned short* __restrict__ yI) {
  __shared__ union {
    struct { __align__(16) unsigned short In[2][130][16];
             __align__(16) unsigned short W[2][16384]; } s;
    __align__(16) unsigned short Out[128][136];
  } sm;
  const int tid = threadIdx.x;
  const int ty = blockIdx.x, e = blockIdx.y, b = blockIdx.z;
  const int wave = tid >> 6, lane = tid & 63;
  const int wc = wave & 1, wr = wave >> 1;
  const int f = (wr*64) >> 7;
  const int tx_base = (wr*64) & 127;
  const int col_l = lane & 15, kg = lane >> 4;
  const unsigned short* wsrc = w2 + (long)e*8*16384;

  const int halfV = tid & 1, pxV = (tid >> 1) & 127, rrV = tid >> 8;
  const int iyA = ty + e - 1 + rrV;
  const bool aOk = (iyA >= 0 && iyA < 128);
  const long aBase = ((long)b*128 + (aOk?iyA:0))*16384 + (long)halfV*1024 + pxV*8;
  uint4 pIn = aOk ? *(const uint4*)(xin + aBase) : zero4();     // A(0)

  if (tid < 8) {
    int rr = tid & 1, c = (tid>>1)&1, hf = (tid>>2)&1;
    *(uint4*)&sm.s.In[rr][c?129:0][hf*8] = zero4();
  }
  // W(0) into buffer 0
  #pragma unroll
  for (int j = 0; j < 4; ++j) {
    int blk = wave*4 + j;
    gload_lds16(wsrc + blk*512 + lane*8, &sm.s.W[0][blk*512]);
  }

  f32x4 acc[4][4] = {};
  int cur = 0;
  for (int ch = 0; ch < 8; ++ch) {
    // barrier1: protect In reuse (prev MFMA ds_reads done per-wave)
    asm volatile("s_waitcnt lgkmcnt(0)" ::: "memory");
    __builtin_amdgcn_s_barrier();
    // stage A(ch) (compiler inserts counted vmcnt for pIn dependency)
    *(uint4*)&sm.s.In[rrV][pxV+1][halfV*8] = pIn;
    if (ch < 7) {
      pIn = aOk ? *(const uint4*)(xin + aBase + (ch+1)*2048) : zero4();   // A(ch+1)
      #pragma unroll
      for (int j = 0; j < 4; ++j) {                                       // W(ch+1)
        int blk = wave*4 + j;
        gload_lds16(wsrc + (long)(ch+1)*16384 + blk*512 + lane*8, &sm.s.W[cur^1][blk*512]);
      }
      // retire exactly W(ch)x4; leave A(ch+1)+W(ch+1)x4 = 5 in flight
      asm volatile("s_waitcnt vmcnt(5)" ::: "memory");
    } else {
      asm volatile("s_waitcnt vmcnt(0)" ::: "memory");
    }
    asm volatile("s_waitcnt lgkmcnt(0)" ::: "memory");
    __builtin_amdgcn_s_barrier();            // barrier2: W(ch)+A(ch) visible to all
    __builtin_amdgcn_sched_barrier(0);
    const unsigned short* Wb = &sm.s.W[cur][0];
    #pragma unroll
    for (int kk = 0; kk < 2; ++kk) {
      bf16x8 aF[4];
      const int tap = kk*2 + (kg >> 1), a = tap >> 1, bb = tap & 1;
      #pragma unroll
      for (int mf = 0; mf < 4; ++mf) {
        int tx = tx_base + mf*16 + col_l;
        aF[mf] = *(const bf16x8*)&sm.s.In[1-a][tx + 1 + f - bb][(kg&1)*8];
      }
      const int slot = kk*4 + kg;
      __builtin_amdgcn_s_setprio(1);
      #pragma unroll
      for (int nf = 0; nf < 4; ++nf) {
        int co_l = nf*16 + col_l;
        bf16x8 bF = *(const bf16x8*)(Wb + (f*128 + wc*64 + co_l)*64 + (slot ^ (co_l & 7))*8);
        #pragma unroll
        for (int mf = 0; mf < 4; ++mf)
          acc[mf][nf] = MFMA16(aF[mf], bF, acc[mf][nf]);
      }
      __builtin_amdgcn_s_setprio(0);
    }
    cur ^= 1;
  }

  // epilogue: 2-pass through Out union
  __syncthreads();
  float bv[4];
  #pragma unroll
  for (int nf = 0; nf < 4; ++nf) bv[nf] = bias[wc*64 + nf*16 + col_l];
  const int oy = 2*ty + e;
  const int myp = wr & 1;
  #pragma unroll
  for (int p = 0; p < 2; ++p) {
    if (myp == p) {
      #pragma unroll
      for (int mf = 0; mf < 4; ++mf)
      #pragma unroll
      for (int nf = 0; nf < 4; ++nf) {
        int co = wc*64 + nf*16 + col_l;
        #pragma unroll
        for (int r = 0; r < 4; ++r) {
          int tx = tx_base + mf*16 + kg*4 + r;
          float v = fmaxf(acc[mf][nf][r] + bv[nf], 0.f);
          int ox = 2*tx + f;
          sm.Out[ox & 127][co ^ (((ox>>3)&7)<<3)] = bfbits(v);
        }
      }
    }
    __syncthreads();
    #pragma unroll
    for (int j = 0; j < 4; ++j) {
      int i = tid + j*512;
      int px = i & 127, chn = i >> 7;
      uint4 vv = *(const uint4*)&sm.Out[px][(chn*8) ^ (((px>>3)&7)<<3)];
      int pxg = p*128 + px;
      *(uint4*)(yI + ((((long)b*256 + oy)*16 + chn)*256 + pxg)*8) = vv;
    }
    if (p == 0) __syncthreads();
  }
}

// ---------------- deconv3: MFMA + sigmoid; 2 output rows per block ----------
__global__ __launch_bounds__(512, 4) void deconv3_mfma(
    const unsigned short* __restrict__ g2I,
    const unsigned short* __restrict__ w2,
    const float* __restrict__ bias, float* __restrict__ y) {
  __shared__ __align__(16) unsigned short sA[4][260][8];
  __shared__ __align__(16) unsigned short sB[16*12*16*8];
  const int tid = threadIdx.x;
  const int oy0 = blockIdx.x*2, b = blockIdx.y;
  const int wave = tid >> 6, lane = tid & 63;
  const int col_l = lane & 15, kg = lane >> 4;
  const int r = wave >> 2;
  const int pxb = (wave & 3)*64;
  for (int i = tid; i < 3072; i += 512) {
    int co = i & 15, tap = (i>>4) % 12, ch = i/192;
    *(uint4*)&sB[((ch*12+tap)*16+co)*8] = *(const uint4*)(w2 + (long)co*1536 + ch*96 + tap*8);
  }
  if (tid < 16) {
    int dy = tid >> 2, c = tid & 3;
    *(uint4*)&sA[dy][(c<2)?c:(256+c)][0] = zero4();
  }
  long aBase[2]; int aLdsO[2]; bool aOk[2];
  #pragma unroll
  for (int u = 0; u < 2; ++u) {
    int idx = tid + u*512;
    int px = idx & 255, dy = idx >> 8;
    int iy = oy0 - 1 + dy;
    aOk[u] = (iy >= 0 && iy < 256);
    aBase[u] = ((long)(b*256 + (aOk[u]?iy:0)))*32768 + px*8;
    aLdsO[u] = (dy*260 + px + 2)*8;
  }
  uint4 pA[2];
  #pragma unroll
  for (int u=0;u<2;u++) pA[u] = aOk[u] ? *(const uint4*)(g2I + aBase[u]) : zero4();

  unsigned short* sAf = &sA[0][0][0];
  f32x4 acc[4] = {};
  for (int ch = 0; ch < 16; ++ch) {
    __syncthreads();
    #pragma unroll
    for (int u=0;u<2;u++) *(uint4*)(sAf + aLdsO[u]) = pA[u];
    __syncthreads();
    if (ch < 15) {
      #pragma unroll
      for (int u=0;u<2;u++)
        pA[u] = aOk[u] ? *(const uint4*)(g2I + aBase[u] + (ch+1)*2048) : zero4();
      __builtin_amdgcn_sched_barrier(0);
    }
    #pragma unroll
    for (int s = 0; s < 3; ++s) {
      bf16x8 bF = *(const bf16x8*)&sB[((ch*12 + s*4 + kg)*16 + col_l)*8];
      __builtin_amdgcn_s_setprio(1);
      #pragma unroll
      for (int mf = 0; mf < 4; ++mf) {
        int px = pxb + mf*16 + col_l;
        bf16x8 aF = *(const bf16x8*)&sA[r + 2 - s][px + 3 - kg][0];
        acc[mf] = MFMA16(aF, bF, acc[mf]);
      }
      __builtin_amdgcn_s_setprio(0);
    }
  }
  if (col_l < 3) {
    const int oy = oy0 + r;
    float bv = bias[col_l];
    #pragma unroll
    for (int mf = 0; mf < 4; ++mf) {
      int px = pxb + mf*16 + kg*4;
      float4 o;
      o.x = 1.f/(1.f + expf(-(acc[mf][0] + bv)));
      o.y = 1.f/(1.f + expf(-(acc[mf][1] + bv)));
      o.z = 1.f/(1.f + expf(-(acc[mf][2] + bv)));
      o.w = 1.f/(1.f + expf(-(acc[mf][3] + bv)));
      *(float4*)(y + ((long)(b*3 + col_l)*256 + oy)*256 + px) = o;
    }
  }
}

// ---------------- VQ via MFMA (unchanged) ----------------
__global__ __launch_bounds__(256, 2) void vq_mfma(
    const unsigned short* __restrict__ zeH, const unsigned short* __restrict__ zeM,
    const unsigned short* __restrict__ zeL,
    const float* __restrict__ emb, const float* __restrict__ esq,
    float* __restrict__ out_idx, float* __restrict__ zq) {
  __shared__ __align__(16) unsigned short sA[64*3*8*8];
  __shared__ __align__(16) unsigned short sB[128*3*8*8];
  __shared__ float snb[128];
  __shared__ int sidx[64];
  const int tid = threadIdx.x;
  const long n0 = (long)blockIdx.x*64;
  const int wave = tid >> 6, lane = tid & 63;
  const int col = lane & 15, kg = lane >> 4;

  #pragma unroll
  for (int j = 0; j < 6; ++j) {
    int idx = tid + j*256;
    int pl = idx >> 9, rem = idx & 511;
    int n = rem >> 3, slot = rem & 7;
    const unsigned short* src = (pl==0 ? zeH : (pl==1 ? zeM : zeL)) + (n0+n)*64 + slot*8;
    *(uint4*)&sA[((n*3 + pl)*8 + (slot ^ (n&7)))*8] = *(const uint4*)src;
  }

  const int codeT = tid >> 1, halfT = tid & 1;
  float4 pB[8];
  #pragma unroll
  for (int q = 0; q < 8; ++q)
    pB[q] = *(const float4*)(emb + (long)codeT*64 + halfT*32 + q*4);
  float pSn = (tid < 128) ? esq[tid] : 0.f;

  float best[4] = {3.4e38f,3.4e38f,3.4e38f,3.4e38f};
  int bidx[4] = {0,0,0,0};

  for (int ch = 0; ch < 4; ++ch) {
    __syncthreads();
    #pragma unroll
    for (int s4 = 0; s4 < 4; ++s4) {
      int slot = halfT*4 + s4;
      float4 lo = pB[s4*2], hi = pB[s4*2+1];
      unsigned short th[8], tm[8], tl[8];
      split3(lo.x, th[0], tm[0], tl[0]); split3(lo.y, th[1], tm[1], tl[1]);
      split3(lo.z, th[2], tm[2], tl[2]); split3(lo.w, th[3], tm[3], tl[3]);
      split3(hi.x, th[4], tm[4], tl[4]); split3(hi.y, th[5], tm[5], tl[5]);
      split3(hi.z, th[6], tm[6], tl[6]); split3(hi.w, th[7], tm[7], tl[7]);
      int base = ((codeT*3)*8 + (slot ^ (codeT&7)))*8;
      *(uint4*)&sB[base]       = *(uint4*)th;
      *(uint4*)&sB[base + 64]  = *(uint4*)tm;
      *(uint4*)&sB[base + 128] = *(uint4*)tl;
    }
    if (tid < 128) snb[tid] = pSn;
    if (ch < 3) {
      #pragma unroll
      for (int q = 0; q < 8; ++q)
        pB[q] = *(const float4*)(emb + ((long)(ch+1)*128 + codeT)*64 + halfT*32 + q*4);
      if (tid < 128) pSn = esq[(ch+1)*128 + tid];
    }
    __syncthreads();

    f32x4 acc[8] = {};
    #pragma unroll
    for (int kk = 0; kk < 2; ++kk) {
      const int nloc = wave*16 + col;
      const int slot = kk*4 + kg;
      bf16x8 aF[3];
      #pragma unroll
      for (int pl = 0; pl < 3; ++pl)
        aF[pl] = *(const bf16x8*)&sA[((nloc*3 + pl)*8 + (slot ^ (nloc&7)))*8];
      __builtin_amdgcn_s_setprio(1);
      #pragma unroll
      for (int cf = 0; cf < 8; ++cf) {
        int cl = cf*16 + col;
        int bb = ((cl*3)*8 + (slot ^ (cl&7)))*8;
        bf16x8 b0 = *(const bf16x8*)&sB[bb];
        bf16x8 b1 = *(const bf16x8*)&sB[bb + 64];
        bf16x8 b2 = *(const bf16x8*)&sB[bb + 128];
        f32x4 a = acc[cf];
        a = MFMA16(aF[0], b0, a);
        a = MFMA16(aF[0], b1, a);
        a = MFMA16(aF[1], b0, a);
        a = MFMA16(aF[0], b2, a);
        a = MFMA16(aF[2], b0, a);
        a = MFMA16(aF[1], b1, a);
        acc[cf] = a;
      }
      __builtin_amdgcn_s_setprio(0);
    }
    #pragma unroll
    for (int cf = 0; cf < 8; ++cf) {
      float sv = snb[cf*16 + col];
      int code = ch*128 + cf*16 + col;
      #pragma unroll
      for (int j = 0; j < 4; ++j) {
        float s = sv - 2.f*acc[cf][j];
        if (s < best[j]) { best[j] = s; bidx[j] = code; }
      }
    }
  }

  #pragma unroll
  for (int j = 0; j < 4; ++j) {
    float b = best[j]; int ii = bidx[j];
    #pragma unroll
    for (int off = 1; off < 16; off <<= 1) {
      float ob = __shfl_xor(b, off);
      int oi = __shfl_xor(ii, off);
      if (ob < b || (ob == b && oi < ii)) { b = ob; ii = oi; }
    }
    if (col == 0) sidx[wave*16 + kg*4 + j] = ii;
  }
  __syncthreads();
  if (tid < 64) out_idx[n0 + tid] = (float)sidx[tid];
  #pragma unroll
  for (int j = 0; j < 4; ++j) {
    int t = tid + j*256;
    int row = t >> 4, q = t & 15;
    float4 v = *(const float4*)(emb + (long)sidx[row]*64 + q*4);
    *(float4*)(zq + (n0 + row)*64 + q*4) = v;
  }
}

// ---------------- launch ----------------
extern "C" void kernel_launch(void* const* d_in, const int* in_sizes, int n_in,
                              void* d_out, int out_size, void* d_ws, size_t ws_size,
                              hipStream_t stream) {
  const float* x   = (const float*)d_in[0];
  const float* c1w = (const float*)d_in[1];  const float* c1b = (const float*)d_in[2];
  const float* c2w = (const float*)d_in[3];  const float* c2b = (const float*)d_in[4];
  const float* c3w = (const float*)d_in[5];  const float* c3b = (const float*)d_in[6];
  const float* emb = (const float*)d_in[7];
  const float* d1w = (const float*)d_in[8];  const float* d1b = (const float*)d_in[9];
  const float* d2w = (const float*)d_in[10]; const float* d2b = (const float*)d_in[11];
  const float* d3w = (const float*)d_in[12]; const float* d3b = (const float*)d_in[13];
  float* out = (float*)d_out;

  float* xrec = out;
  float* oidx = out + 3145728;
  float* zq   = out + 3211264;

  const long XB  = 196608;   // 3*256*256
  const long ZEB = 262144;   // ze elems per batch
  const long H2B = 1572864;  // per-batch h2I stride in shorts

  const size_t NEEDED   = 112273408ULL;   // 4-batch tier
  const size_t NEEDED8  = 170994688ULL;   // 8-batch decoder tier
  const size_t NEEDED16 = 288434176ULL;   // 16-batch single-pass encoder tier
  if (ws_size < NEEDED) return;
  const bool use16 = (ws_size >= NEEDED16);
  const bool use8  = (ws_size >= NEEDED8);
  char* wsb = (char*)d_ws;

  unsigned short* zeL = (unsigned short*)out;   // xrec region: dead until deconv3

  if (use16) {
    unsigned short* h1  = (unsigned short*)wsb;                  // 201.3MB, PS1=33554432
    unsigned short* h2I = (unsigned short*)(wsb + 201326592);    // 50.3MB
    unsigned short* zeH = (unsigned short*)(wsb + 251658240);
    unsigned short* zeM = (unsigned short*)(wsb + 268435456);
    char* W = wsb + 285212672;
    float* w2c1          = (float*)(W);
    unsigned short* w2c2 = (unsigned short*)(W + 24576);
    unsigned short* w2c3 = (unsigned short*)(W + 1597440);
    unsigned short* w2d1 = (unsigned short*)(W + 2383872);
    unsigned short* w2d2 = (unsigned short*)(W + 2646016);
    unsigned short* w2d3 = (unsigned short*)(W + 3170304);
    float* esq           = (float*)(W + 3219456);

    wprep_all<<<3066, 256, 0, stream>>>(c1w, w2c1, c2w, w2c2, c3w, w2c3,
                                        d1w, w2d1, d2w, w2d2, d3w, w2d3, emb, esq);
    conv1_split<<<dim3(16,16,32), 256, 0, stream>>>(x, w2c1, c1b, h1, 33554432L);
    conv2_mfma<<<dim3(64,2,16), 256, 0, stream>>>(h1, 33554432L, w2c2, c2b, h2I);
    conv3_mfma<<<dim3(64,1,16), 256, 0, stream>>>(h2I, w2c3, c3b, zeH, zeM, zeL);
    vq_mfma<<<1024, 256, 0, stream>>>(zeH, zeM, zeL, emb, esq, oidx, zq);

    unsigned short* g2g = (unsigned short*)wsb;                 // 134MB
    unsigned short* g1g = (unsigned short*)(wsb + 134217728);   // 34MB
    for (int g = 0; g < 2; ++g) {
      deconv_mfma<64, 64, 0 ><<<dim3(64, 2, 8), 256, 0, stream>>>(
          (const void*)(zq + (long)g*8*ZEB), w2d1, d1b, g1g);
      deconv2_pipe<<<dim3(128,2,8), 512, 0, stream>>>(g1g, w2d2, d2b, g2g);
      deconv3_mfma<<<dim3(128,8), 512, 0, stream>>>(
          g2g, w2d3, d3b, xrec + (long)g*8*XB);
    }
    return;
  }

  // ---- fallback tiers ----
  unsigned short* h1grp = (unsigned short*)wsb;
  unsigned short* h2I   = (unsigned short*)(wsb + 67108864);
  unsigned short* zeH = (unsigned short*)(wsb + 92274688);
  unsigned short* zeM = (unsigned short*)(wsb + 100663296);
  char* W = use8 ? (wsb + 167772160) : (wsb + 109051904);
  float* w2c1          = (float*)(W);
  unsigned short* w2c2 = (unsigned short*)(W + 24576);
  unsigned short* w2c3 = (unsigned short*)(W + 1597440);
  unsigned short* w2d1 = (unsigned short*)(W + 2383872);
  unsigned short* w2d2 = (unsigned short*)(W + 2646016);
  unsigned short* w2d3 = (unsigned short*)(W + 3170304);
  float* esq           = (float*)(W + 3219456);

  wprep_all<<<3066, 256, 0, stream>>>(c1w, w2c1, c2w, w2c2, c3w, w2c3,
                                      d1w, w2d1, d2w, w2d2, d3w, w2d3, emb, esq);

  const long PS1 = 8388608;
  for (int g = 0; g < 4; ++g) {
    conv1_split<<<dim3(16,16,8), 256, 0, stream>>>(
        x + (long)g*4*XB, w2c1, c1b, h1grp, PS1);
    conv2_mfma<<<dim3(64,2,4), 256, 0, stream>>>(
        h1grp, PS1, w2c2, c2b, h2I + (long)(g&1)*4*H2B);
    if (g & 1) {
      long zo = (long)(g>>1)*8*ZEB;
      conv3_mfma<<<dim3(64,1,8), 256, 0, stream>>>(
          h2I, w2c3, c3b, zeH + zo, zeM + zo, zeL + zo);
    }
  }
  vq_mfma<<<1024, 256, 0, stream>>>(zeH, zeM, zeL, emb, esq, oidx, zq);

  if (use8) {
    unsigned short* g2g = (unsigned short*)wsb;
    unsigned short* g1g = (unsigned short*)(wsb + 134217728);
    for (int g = 0; g < 2; ++g) {
      deconv_mfma<64, 64, 0 ><<<dim3(64, 2, 8), 256, 0, stream>>>(
          (const void*)(zq + (long)g*8*ZEB), w2d1, d1b, g1g);
      deconv2_pipe<<<dim3(128,2,8), 512, 0, stream>>>(g1g, w2d2, d2b, g2g);
      deconv3_mfma<<<dim3(128,8), 512, 0, stream>>>(
          g2g, w2d3, d3b, xrec + (long)g*8*XB);
    }
  } else {
    unsigned short* g2g = (unsigned short*)wsb;
    unsigned short* g1g = (unsigned short*)(wsb + 67108864);
    for (int g = 0; g < 4; ++g) {
      deconv_mfma<64, 64, 0 ><<<dim3(64, 2, 4), 256, 0, stream>>>(
          (const void*)(zq + (long)g*4*ZEB), w2d1, d1b, g1g);
      deconv2_pipe<<<dim3(128,2,4), 512, 0, stream>>>(g1g, w2d2, d2b, g2g);
      deconv3_mfma<<<dim3(128,4), 512, 0, stream>>>(
          g2g, w2d3, d3b, xrec + (long)g*4*XB);
    }
  }
}